// Round 1
// baseline (11997.105 us; speedup 1.0000x reference)
//
#include <hip/hip_runtime.h>
#include <hip/hip_bf16.h>

#define D 512
#define H 8
#define DKH 64
#define NLAYER 2

__device__ __forceinline__ float gelu_f(float x) {
    float x3 = x * x * x;
    return 0.5f * x * (1.0f + tanhf(0.7978845608028654f * (x + 0.044715f * x3)));
}

__device__ __forceinline__ void atomicMaxF(float* addr, float val) {
    // works for all finite floats given init = -inf
    if (val >= 0.0f) atomicMax((int*)addr, __float_as_int(val));
    else             atomicMin((unsigned int*)addr, __float_as_uint(val));
}

// ---------------------------------------------------------------------------
// C[M,N] = postact( A[M,512] @ Bw[N,512]^T + bias ), optional gelu on A load.
// 128x128 tile, BK=16, 256 threads, 8x8 microtile.
// ---------------------------------------------------------------------------
template <int PREG, int POSTG>
__global__ __launch_bounds__(256) void gemm_tn(
    const float* __restrict__ A, const float* __restrict__ Bw,
    const float* __restrict__ bias, float* __restrict__ C, int M, int N) {
    __shared__ __align__(16) float As[16][132];
    __shared__ __align__(16) float Bs[16][132];
    const int bm = blockIdx.y * 128;
    const int bn = blockIdx.x * 128;
    const int tid = threadIdx.x;
    const int tm = tid >> 4;       // 0..15
    const int tn = tid & 15;       // 0..15
    const int lr = tid >> 1;       // 0..127 (tile row for loads)
    const int lk = (tid & 1) * 8;  // 0 or 8
    const float* Ap = A + (size_t)(bm + lr) * D + lk;
    const float* Bp = Bw + (size_t)(bn + lr) * D + lk;
    const bool avld = (bm + lr) < M;
    const bool bvld = (bn + lr) < N;

    float acc[8][8];
#pragma unroll
    for (int i = 0; i < 8; ++i)
#pragma unroll
        for (int j = 0; j < 8; ++j) acc[i][j] = 0.0f;

    for (int k0 = 0; k0 < D; k0 += 16) {
        float4 a0 = make_float4(0.f, 0.f, 0.f, 0.f), a1 = a0, b0 = a0, b1 = a0;
        if (avld) {
            a0 = *(const float4*)(Ap + k0);
            a1 = *(const float4*)(Ap + k0 + 4);
        }
        if (bvld) {
            b0 = *(const float4*)(Bp + k0);
            b1 = *(const float4*)(Bp + k0 + 4);
        }
        if (PREG) {
            a0.x = gelu_f(a0.x); a0.y = gelu_f(a0.y); a0.z = gelu_f(a0.z); a0.w = gelu_f(a0.w);
            a1.x = gelu_f(a1.x); a1.y = gelu_f(a1.y); a1.z = gelu_f(a1.z); a1.w = gelu_f(a1.w);
        }
        __syncthreads();
        As[lk + 0][lr] = a0.x; As[lk + 1][lr] = a0.y; As[lk + 2][lr] = a0.z; As[lk + 3][lr] = a0.w;
        As[lk + 4][lr] = a1.x; As[lk + 5][lr] = a1.y; As[lk + 6][lr] = a1.z; As[lk + 7][lr] = a1.w;
        Bs[lk + 0][lr] = b0.x; Bs[lk + 1][lr] = b0.y; Bs[lk + 2][lr] = b0.z; Bs[lk + 3][lr] = b0.w;
        Bs[lk + 4][lr] = b1.x; Bs[lk + 5][lr] = b1.y; Bs[lk + 6][lr] = b1.z; Bs[lk + 7][lr] = b1.w;
        __syncthreads();
#pragma unroll
        for (int kk = 0; kk < 16; ++kk) {
            float a[8], b[8];
            *(float4*)&a[0] = *(const float4*)&As[kk][tm * 8];
            *(float4*)&a[4] = *(const float4*)&As[kk][tm * 8 + 4];
            *(float4*)&b[0] = *(const float4*)&Bs[kk][tn * 4];
            *(float4*)&b[4] = *(const float4*)&Bs[kk][64 + tn * 4];
#pragma unroll
            for (int i = 0; i < 8; ++i)
#pragma unroll
                for (int j = 0; j < 8; ++j) acc[i][j] = fmaf(a[i], b[j], acc[i][j]);
        }
    }
#pragma unroll
    for (int i = 0; i < 8; ++i) {
        int row = bm + tm * 8 + i;
        if (row < M) {
#pragma unroll
            for (int jg = 0; jg < 2; ++jg) {
                int col = bn + jg * 64 + tn * 4;
                if (col < N) {
                    float4 o;
                    float* op = &o.x;
#pragma unroll
                    for (int j = 0; j < 4; ++j) {
                        float v = acc[i][jg * 4 + j];
                        if (bias) v += bias[col + j];
                        if (POSTG) v = gelu_f(v);
                        op[j] = v;
                    }
                    *(float4*)(C + (size_t)row * N + col) = o;
                }
            }
        }
    }
}

// ---------------------------------------------------------------------------
// fold att_r/msg_r into the K/V projection weight:
// fw[h*64+j][d] = sum_i r[h][i][j] * w[h*64+i][d];  fb likewise from bias.
// grid: (8 d-chunks, 8 heads), 256 threads.
// ---------------------------------------------------------------------------
__global__ __launch_bounds__(256) void fuse_w(
    const float* __restrict__ w, const float* __restrict__ bsrc,
    const float* __restrict__ r, float* __restrict__ fw, float* __restrict__ fb) {
    int h = blockIdx.y;
    int dc = blockIdx.x * 64;
    __shared__ float rs[64][64];
    int tid = threadIdx.x;
    for (int i = tid; i < 4096; i += 256) rs[i >> 6][i & 63] = r[h * 4096 + i];
    __syncthreads();
    for (int rep = 0; rep < 16; ++rep) {
        int o = rep * 256 + tid;
        int j = o >> 6;
        int dd = o & 63;
        float s = 0.0f;
#pragma unroll 8
        for (int i = 0; i < 64; ++i)
            s = fmaf(rs[i][j], w[(size_t)(h * 64 + i) * D + dc + dd], s);
        fw[(size_t)(h * 64 + j) * D + dc + dd] = s;
    }
    if (blockIdx.x == 0 && tid < 64) {
        float s = 0.0f;
        for (int i = 0; i < 64; ++i) s += bsrc[h * 64 + i] * rs[i][tid];
        fb[h * 64 + tid] = s;
    }
}

// ---------------------------------------------------------------------------
// pass 1: t[e][h] = dot(k[src],q[dst]) per head * pri[h]/8; atomicMax into mx.
// one wave per edge.
// ---------------------------------------------------------------------------
__global__ __launch_bounds__(256) void edge_qk(
    const float* __restrict__ kbuf, const float* __restrict__ qbuf,
    const int* __restrict__ src, const int* __restrict__ dst,
    const float* __restrict__ pri, float* __restrict__ t,
    float* __restrict__ mx, int E) {
    int e = blockIdx.x * 4 + (threadIdx.x >> 6);
    if (e >= E) return;
    int lane = threadIdx.x & 63;
    int s = src[e], d = dst[e];
    const float4* kp = (const float4*)(kbuf + (size_t)s * D);
    const float4* qp = (const float4*)(qbuf + (size_t)d * D);
    float4 k0 = kp[lane * 2], k1 = kp[lane * 2 + 1];
    float4 q0 = qp[lane * 2], q1 = qp[lane * 2 + 1];
    float sum = k0.x * q0.x + k0.y * q0.y + k0.z * q0.z + k0.w * q0.w +
                k1.x * q1.x + k1.y * q1.y + k1.z * q1.z + k1.w * q1.w;
    sum += __shfl_xor(sum, 1);
    sum += __shfl_xor(sum, 2);
    sum += __shfl_xor(sum, 4);
    int h = lane >> 3;
    if ((lane & 7) == 0) {
        float val = sum * pri[h] * 0.125f;
        t[(size_t)e * 8 + h] = val;
        atomicMaxF(&mx[d * 8 + h], val);
    }
}

// pass 2: e = exp(t - mx[dst]); den[dst] += e
__global__ __launch_bounds__(256) void edge_sm(
    const int* __restrict__ dst, float* __restrict__ t,
    const float* __restrict__ mx, float* __restrict__ den, int E) {
    int idx = blockIdx.x * 256 + threadIdx.x;
    if (idx >= E * 8) return;
    int e = idx >> 3, h = idx & 7;
    int d = dst[e];
    float v = expf(t[idx] - mx[d * 8 + h]);
    t[idx] = v;
    atomicAdd(&den[d * 8 + h], v);
}

// pass 3: agg[dst] += v[src] * att ; one wave per edge, 8 f32 atomics/lane
__global__ __launch_bounds__(256) void edge_msg(
    const float* __restrict__ vbuf, const int* __restrict__ src,
    const int* __restrict__ dst, const float* __restrict__ t,
    const float* __restrict__ den, float* __restrict__ agg, int E) {
    int e = blockIdx.x * 4 + (threadIdx.x >> 6);
    if (e >= E) return;
    int lane = threadIdx.x & 63;
    int s = src[e], d = dst[e];
    int h = lane >> 3;
    float att = t[(size_t)e * 8 + h] / fmaxf(den[d * 8 + h], 1e-9f);
    const float4* vp = (const float4*)(vbuf + (size_t)s * D);
    float4 v0 = vp[lane * 2], v1 = vp[lane * 2 + 1];
    float* ap = agg + (size_t)d * D + lane * 8;
    atomicAdd(ap + 0, v0.x * att);
    atomicAdd(ap + 1, v0.y * att);
    atomicAdd(ap + 2, v0.z * att);
    atomicAdd(ap + 3, v0.w * att);
    atomicAdd(ap + 4, v1.x * att);
    atomicAdd(ap + 5, v1.y * att);
    atomicAdd(ap + 6, v1.z * att);
    atomicAdd(ap + 7, v1.w * att);
}

// out = trans*alpha + h*(1-alpha); layernorm; write to hout. 1 block / node.
__global__ __launch_bounds__(128) void blend_ln(
    const float* __restrict__ trans, const float* __restrict__ hin,
    const float* __restrict__ skip, const float* __restrict__ g,
    const float* __restrict__ b, float* __restrict__ hout) {
    int n = blockIdx.x;
    int tid = threadIdx.x;  // 0..127
    float alpha = 1.0f / (1.0f + expf(-skip[0]));
    size_t base = (size_t)n * D + tid * 4;
    float4 t4 = *(const float4*)(trans + base);
    float4 h4 = *(const float4*)(hin + base);
    float o[4];
    o[0] = t4.x * alpha + h4.x * (1.0f - alpha);
    o[1] = t4.y * alpha + h4.y * (1.0f - alpha);
    o[2] = t4.z * alpha + h4.z * (1.0f - alpha);
    o[3] = t4.w * alpha + h4.w * (1.0f - alpha);
    float s = o[0] + o[1] + o[2] + o[3];
    float ss = o[0] * o[0] + o[1] * o[1] + o[2] * o[2] + o[3] * o[3];
    for (int off = 32; off; off >>= 1) {
        s += __shfl_down(s, off);
        ss += __shfl_down(ss, off);
    }
    __shared__ float red[4];
    if ((tid & 63) == 0) { red[tid >> 6] = s; red[2 + (tid >> 6)] = ss; }
    __syncthreads();
    float S = red[0] + red[1];
    float SS = red[2] + red[3];
    float mu = S * (1.0f / 512.0f);
    float var = SS * (1.0f / 512.0f) - mu * mu;
    float inv = rsqrtf(var + 1e-5f);
    int c = tid * 4;
    float4 o4;
    o4.x = (o[0] - mu) * inv * g[c + 0] + b[c + 0];
    o4.y = (o[1] - mu) * inv * g[c + 1] + b[c + 1];
    o4.z = (o[2] - mu) * inv * g[c + 2] + b[c + 2];
    o4.w = (o[3] - mu) * inv * g[c + 3] + b[c + 3];
    *(float4*)(hout + base) = o4;
}

__global__ void fill_val(float* __restrict__ p, float v, int n) {
    int i = blockIdx.x * 256 + threadIdx.x;
    if (i < n) p[i] = v;
}

__global__ void scale_emb(const float* __restrict__ e, const float* __restrict__ ak,
                          float* __restrict__ o, int n4) {
    int i = blockIdx.x * 256 + threadIdx.x;
    if (i >= n4) return;
    float4 v = ((const float4*)e)[i];
    int d0 = (i * 4) & (D - 1);
    v.x *= ak[d0]; v.y *= ak[d0 + 1]; v.z *= ak[d0 + 2]; v.w *= ak[d0 + 3];
    ((float4*)o)[i] = v;
}

extern "C" void kernel_launch(void* const* d_in, const int* in_sizes, int n_in,
                              void* d_out, int out_size, void* d_ws, size_t ws_size,
                              hipStream_t stream) {
    const float* embeddings = (const float*)d_in[0];
    const float* node_emb   = (const float*)d_in[1];
    const float* adapt_w    = (const float*)d_in[2];
    const float* adapt_b    = (const float*)d_in[3];
    const float* kw   = (const float*)d_in[4];
    const float* kb   = (const float*)d_in[5];
    const float* qw   = (const float*)d_in[6];
    const float* qb   = (const float*)d_in[7];
    const float* vw   = (const float*)d_in[8];
    const float* vb   = (const float*)d_in[9];
    const float* aw   = (const float*)d_in[10];
    const float* ab   = (const float*)d_in[11];
    const float* pri  = (const float*)d_in[12];
    const float* att_r = (const float*)d_in[13];
    const float* msg_r = (const float*)d_in[14];
    const float* skip  = (const float*)d_in[15];
    const float* ln_g  = (const float*)d_in[16];
    const float* ln_b  = (const float*)d_in[17];
    const float* out_w = (const float*)d_in[18];
    const float* out_b = (const float*)d_in[19];
    const float* attn_k = (const float*)d_in[20];
    const int* src = (const int*)d_in[21];
    const int* dst = (const int*)d_in[22];

    const int E  = in_sizes[21];
    const int NB = in_sizes[0] / D;   // 8192
    const int NN = in_sizes[1] / D;   // 20000
    const int NC = out_size / NB;     // 10000

    float* ws = (float*)d_ws;
    size_t big = (size_t)NN * D;
    float* hbuf = ws;
    float* kbuf = hbuf + big;
    float* qbuf = kbuf + big;
    float* vbuf = qbuf + big;
    float* aggb = vbuf + big;
    float* fwk = aggb + big;
    float* fbk = fwk + (size_t)D * D;
    float* fwv = fbk + D;
    float* fbv = fwv + (size_t)D * D;
    float* tbuf = fbv + D;
    float* mx  = tbuf + (size_t)E * 8;
    float* den = mx + (size_t)NN * 8;
    // reuse after layers:
    float* clsb = qbuf;
    float* embs = vbuf;

    auto ggrid = [](int M, int N) { return dim3((N + 127) / 128, (M + 127) / 128); };

    // h = gelu(node_emb @ adapt_w^T + adapt_b)
    gemm_tn<0, 1><<<ggrid(NN, D), 256, 0, stream>>>(node_emb, adapt_w, adapt_b, hbuf, NN, D);

    for (int l = 0; l < NLAYER; ++l) {
        const size_t wo = (size_t)l * D * D;
        fuse_w<<<dim3(8, 8), 256, 0, stream>>>(kw + wo, kb + l * D, att_r + (size_t)l * H * DKH * DKH, fwk, fbk);
        fuse_w<<<dim3(8, 8), 256, 0, stream>>>(vw + wo, vb + l * D, msg_r + (size_t)l * H * DKH * DKH, fwv, fbv);
        gemm_tn<0, 0><<<ggrid(NN, D), 256, 0, stream>>>(hbuf, fwk, fbk, kbuf, NN, D);
        gemm_tn<0, 0><<<ggrid(NN, D), 256, 0, stream>>>(hbuf, qw + wo, qb + l * D, qbuf, NN, D);
        gemm_tn<0, 0><<<ggrid(NN, D), 256, 0, stream>>>(hbuf, fwv, fbv, vbuf, NN, D);

        hipMemsetAsync(den, 0, (size_t)NN * 8 * sizeof(float), stream);
        hipMemsetAsync(aggb, 0, big * sizeof(float), stream);
        fill_val<<<(NN * 8 + 255) / 256, 256, 0, stream>>>(mx, -INFINITY, NN * 8);

        edge_qk<<<(E + 3) / 4, 256, 0, stream>>>(kbuf, qbuf, src, dst, pri + l * H, tbuf, mx, E);
        edge_sm<<<((size_t)E * 8 + 255) / 256, 256, 0, stream>>>(dst, tbuf, mx, den, E);
        edge_msg<<<(E + 3) / 4, 256, 0, stream>>>(vbuf, src, dst, tbuf, den, aggb, E);

        // trans = gelu(agg) @ aw^T + ab   (into kbuf)
        gemm_tn<1, 0><<<ggrid(NN, D), 256, 0, stream>>>(aggb, aw + wo, ab + l * D, kbuf, NN, D);
        blend_ln<<<NN, 128, 0, stream>>>(kbuf, hbuf, skip + l, ln_g + l * D, ln_b + l * D, hbuf);
    }

    // cls_emb = h[:NC] @ out_w^T + out_b
    gemm_tn<0, 0><<<ggrid(NC, D), 256, 0, stream>>>(hbuf, out_w, out_b, clsb, NC, D);
    // embs = embeddings * attn_kernels
    scale_emb<<<((NB * D / 4) + 255) / 256, 256, 0, stream>>>(embeddings, attn_k, embs, NB * D / 4);
    // logits = embs @ cls_emb^T
    gemm_tn<0, 0><<<ggrid(NB, NC), 256, 0, stream>>>(embs, clsb, nullptr, (float*)d_out, NB, NC);
}

// Round 2
// 3343.692 us; speedup vs baseline: 3.5880x; 3.5880x over previous
//
#include <hip/hip_runtime.h>
#include <hip/hip_bf16.h>

#define D 512
#define H 8
#define DKH 64
#define NLAYER 2

__device__ __forceinline__ float gelu_f(float x) {
    float x3 = x * x * x;
    return 0.5f * x * (1.0f + tanhf(0.7978845608028654f * (x + 0.044715f * x3)));
}

// ---------------------------------------------------------------------------
// C[M,N] = postact( A[M,512] @ Bw[N,512]^T + bias ), optional gelu on A load.
// 128x128 tile, BK=16, 256 threads, 8x8 microtile.
// ---------------------------------------------------------------------------
template <int PREG, int POSTG>
__global__ __launch_bounds__(256) void gemm_tn(
    const float* __restrict__ A, const float* __restrict__ Bw,
    const float* __restrict__ bias, float* __restrict__ C, int M, int N) {
    __shared__ __align__(16) float As[16][132];
    __shared__ __align__(16) float Bs[16][132];
    const int bm = blockIdx.y * 128;
    const int bn = blockIdx.x * 128;
    const int tid = threadIdx.x;
    const int tm = tid >> 4;       // 0..15
    const int tn = tid & 15;       // 0..15
    const int lr = tid >> 1;       // 0..127 (tile row for loads)
    const int lk = (tid & 1) * 8;  // 0 or 8
    const float* Ap = A + (size_t)(bm + lr) * D + lk;
    const float* Bp = Bw + (size_t)(bn + lr) * D + lk;
    const bool avld = (bm + lr) < M;
    const bool bvld = (bn + lr) < N;

    float acc[8][8];
#pragma unroll
    for (int i = 0; i < 8; ++i)
#pragma unroll
        for (int j = 0; j < 8; ++j) acc[i][j] = 0.0f;

    for (int k0 = 0; k0 < D; k0 += 16) {
        float4 a0 = make_float4(0.f, 0.f, 0.f, 0.f), a1 = a0, b0 = a0, b1 = a0;
        if (avld) {
            a0 = *(const float4*)(Ap + k0);
            a1 = *(const float4*)(Ap + k0 + 4);
        }
        if (bvld) {
            b0 = *(const float4*)(Bp + k0);
            b1 = *(const float4*)(Bp + k0 + 4);
        }
        if (PREG) {
            a0.x = gelu_f(a0.x); a0.y = gelu_f(a0.y); a0.z = gelu_f(a0.z); a0.w = gelu_f(a0.w);
            a1.x = gelu_f(a1.x); a1.y = gelu_f(a1.y); a1.z = gelu_f(a1.z); a1.w = gelu_f(a1.w);
        }
        __syncthreads();
        As[lk + 0][lr] = a0.x; As[lk + 1][lr] = a0.y; As[lk + 2][lr] = a0.z; As[lk + 3][lr] = a0.w;
        As[lk + 4][lr] = a1.x; As[lk + 5][lr] = a1.y; As[lk + 6][lr] = a1.z; As[lk + 7][lr] = a1.w;
        Bs[lk + 0][lr] = b0.x; Bs[lk + 1][lr] = b0.y; Bs[lk + 2][lr] = b0.z; Bs[lk + 3][lr] = b0.w;
        Bs[lk + 4][lr] = b1.x; Bs[lk + 5][lr] = b1.y; Bs[lk + 6][lr] = b1.z; Bs[lk + 7][lr] = b1.w;
        __syncthreads();
#pragma unroll
        for (int kk = 0; kk < 16; ++kk) {
            float a[8], b[8];
            *(float4*)&a[0] = *(const float4*)&As[kk][tm * 8];
            *(float4*)&a[4] = *(const float4*)&As[kk][tm * 8 + 4];
            *(float4*)&b[0] = *(const float4*)&Bs[kk][tn * 4];
            *(float4*)&b[4] = *(const float4*)&Bs[kk][64 + tn * 4];
#pragma unroll
            for (int i = 0; i < 8; ++i)
#pragma unroll
                for (int j = 0; j < 8; ++j) acc[i][j] = fmaf(a[i], b[j], acc[i][j]);
        }
    }
#pragma unroll
    for (int i = 0; i < 8; ++i) {
        int row = bm + tm * 8 + i;
        if (row < M) {
#pragma unroll
            for (int jg = 0; jg < 2; ++jg) {
                int col = bn + jg * 64 + tn * 4;
                if (col < N) {
                    float4 o;
                    float* op = &o.x;
#pragma unroll
                    for (int j = 0; j < 4; ++j) {
                        float v = acc[i][jg * 4 + j];
                        if (bias) v += bias[col + j];
                        if (POSTG) v = gelu_f(v);
                        op[j] = v;
                    }
                    *(float4*)(C + (size_t)row * N + col) = o;
                }
            }
        }
    }
}

// ---------------------------------------------------------------------------
// fold att_r/msg_r into the K/V projection weight:
// fw[h*64+j][d] = sum_i r[h][i][j] * w[h*64+i][d];  fb likewise from bias.
// ---------------------------------------------------------------------------
__global__ __launch_bounds__(256) void fuse_w(
    const float* __restrict__ w, const float* __restrict__ bsrc,
    const float* __restrict__ r, float* __restrict__ fw, float* __restrict__ fb) {
    int h = blockIdx.y;
    int dc = blockIdx.x * 64;
    __shared__ float rs[64][64];
    int tid = threadIdx.x;
    for (int i = tid; i < 4096; i += 256) rs[i >> 6][i & 63] = r[h * 4096 + i];
    __syncthreads();
    for (int rep = 0; rep < 16; ++rep) {
        int o = rep * 256 + tid;
        int j = o >> 6;
        int dd = o & 63;
        float s = 0.0f;
#pragma unroll 8
        for (int i = 0; i < 64; ++i)
            s = fmaf(rs[i][j], w[(size_t)(h * 64 + i) * D + dc + dd], s);
        fw[(size_t)(h * 64 + j) * D + dc + dd] = s;
    }
    if (blockIdx.x == 0 && tid < 64) {
        float s = 0.0f;
        for (int i = 0; i < 64; ++i) s += bsrc[h * 64 + i] * rs[i][tid];
        fb[h * 64 + tid] = s;
    }
}

// ---------------------------------------------------------------------------
// CSR build by dst:  hist -> scan -> scatter
// ---------------------------------------------------------------------------
__global__ void zero_int(int* __restrict__ p, int n) {
    int i = blockIdx.x * 256 + threadIdx.x;
    if (i < n) p[i] = 0;
}

__global__ void hist_dst(const int* __restrict__ dst, int* __restrict__ cnt, int E) {
    int i = blockIdx.x * 256 + threadIdx.x;
    if (i < E) atomicAdd(&cnt[dst[i]], 1);
}

__global__ __launch_bounds__(1024) void scan_counts(
    const int* __restrict__ cnt, int* __restrict__ offs, int* __restrict__ cursor,
    int n, int E) {
    __shared__ int part[1024];
    int t = threadIdx.x;
    int chunk = (n + 1023) >> 10;
    int lo = t * chunk;
    int hi = min(lo + chunk, n);
    int s = 0;
    for (int i = lo; i < hi; ++i) s += cnt[i];
    part[t] = s;
    __syncthreads();
    for (int off = 1; off < 1024; off <<= 1) {
        int v = (t >= off) ? part[t - off] : 0;
        __syncthreads();
        part[t] += v;
        __syncthreads();
    }
    int base = (t == 0) ? 0 : part[t - 1];
    for (int i = lo; i < hi; ++i) {
        offs[i] = base;
        cursor[i] = base;
        base += cnt[i];
    }
    if (t == 1023) offs[n] = E;
}

__global__ void scatter_edges(const int* __restrict__ dst, int* __restrict__ cursor,
                              int* __restrict__ eidx, int E) {
    int i = blockIdx.x * 256 + threadIdx.x;
    if (i < E) {
        int pos = atomicAdd(&cursor[dst[i]], 1);
        eidx[pos] = i;
    }
}

// ---------------------------------------------------------------------------
// pass 1: t[e][h] = dot(k[src],q[dst]) per head * pri[h]/8. one wave per edge.
// ---------------------------------------------------------------------------
__global__ __launch_bounds__(256) void edge_qk(
    const float* __restrict__ kbuf, const float* __restrict__ qbuf,
    const int* __restrict__ src, const int* __restrict__ dst,
    const float* __restrict__ pri, float* __restrict__ t, int E) {
    int e = blockIdx.x * 4 + (threadIdx.x >> 6);
    if (e >= E) return;
    int lane = threadIdx.x & 63;
    int s = src[e], d = dst[e];
    const float4* kp = (const float4*)(kbuf + (size_t)s * D);
    const float4* qp = (const float4*)(qbuf + (size_t)d * D);
    float4 k0 = kp[lane * 2], k1 = kp[lane * 2 + 1];
    float4 q0 = qp[lane * 2], q1 = qp[lane * 2 + 1];
    float sum = k0.x * q0.x + k0.y * q0.y + k0.z * q0.z + k0.w * q0.w +
                k1.x * q1.x + k1.y * q1.y + k1.z * q1.z + k1.w * q1.w;
    sum += __shfl_xor(sum, 1);
    sum += __shfl_xor(sum, 2);
    sum += __shfl_xor(sum, 4);
    int h = lane >> 3;
    if ((lane & 7) == 0) t[(size_t)e * 8 + h] = sum * pri[h] * 0.125f;
}

// ---------------------------------------------------------------------------
// Per-dst-node softmax + aggregation, gather-based, zero atomics.
// One 256-thread block per node. Phase 1: per-head max & denom over incoming
// edges (LDS tree reduce). Phase 2: acc += v[src] * att, one float2/thread.
// ---------------------------------------------------------------------------
__global__ __launch_bounds__(256) void node_attn_agg(
    const float* __restrict__ vbuf, const int* __restrict__ src,
    const float* __restrict__ t, const int* __restrict__ offs,
    const int* __restrict__ eidx, float* __restrict__ agg) {
    int n = blockIdx.x;
    int tid = threadIdx.x;
    int start = offs[n], end = offs[n + 1];
    __shared__ float red[32][8];
    __shared__ float smx[8], sinv[8];
    int h = tid & 7, sub = tid >> 3;

    float m = -INFINITY;
    for (int i = start + sub; i < end; i += 32)
        m = fmaxf(m, t[(size_t)eidx[i] * 8 + h]);
    red[sub][h] = m;
    __syncthreads();
    if (tid < 8) {
        float mm = -INFINITY;
#pragma unroll
        for (int s2 = 0; s2 < 32; ++s2) mm = fmaxf(mm, red[s2][tid]);
        smx[tid] = mm;
    }
    __syncthreads();
    float mh = smx[h];
    float s = 0.0f;
    for (int i = start + sub; i < end; i += 32)
        s += expf(t[(size_t)eidx[i] * 8 + h] - mh);
    red[sub][h] = s;
    __syncthreads();
    if (tid < 8) {
        float ss = 0.0f;
#pragma unroll
        for (int s2 = 0; s2 < 32; ++s2) ss += red[s2][tid];
        sinv[tid] = 1.0f / fmaxf(ss, 1e-9f);
    }
    __syncthreads();

    int h2 = tid >> 5;  // head for cols [2*tid, 2*tid+1]
    float mx2 = smx[h2], inv2 = sinv[h2];
    float ax = 0.0f, ay = 0.0f;
    for (int i = start; i < end; ++i) {
        int e = eidx[i];
        int sn = src[e];
        float a = expf(t[(size_t)e * 8 + h2] - mx2) * inv2;
        float2 v = *(const float2*)(vbuf + (size_t)sn * D + tid * 2);
        ax = fmaf(v.x, a, ax);
        ay = fmaf(v.y, a, ay);
    }
    float2 o = make_float2(ax, ay);
    *(float2*)(agg + (size_t)n * D + tid * 2) = o;
}

// out = trans*alpha + h*(1-alpha); layernorm; write to hout. 1 block / node.
__global__ __launch_bounds__(128) void blend_ln(
    const float* __restrict__ trans, const float* __restrict__ hin,
    const float* __restrict__ skip, const float* __restrict__ g,
    const float* __restrict__ b, float* __restrict__ hout) {
    int n = blockIdx.x;
    int tid = threadIdx.x;  // 0..127
    float alpha = 1.0f / (1.0f + expf(-skip[0]));
    size_t base = (size_t)n * D + tid * 4;
    float4 t4 = *(const float4*)(trans + base);
    float4 h4 = *(const float4*)(hin + base);
    float o[4];
    o[0] = t4.x * alpha + h4.x * (1.0f - alpha);
    o[1] = t4.y * alpha + h4.y * (1.0f - alpha);
    o[2] = t4.z * alpha + h4.z * (1.0f - alpha);
    o[3] = t4.w * alpha + h4.w * (1.0f - alpha);
    float s = o[0] + o[1] + o[2] + o[3];
    float ss = o[0] * o[0] + o[1] * o[1] + o[2] * o[2] + o[3] * o[3];
    for (int off = 32; off; off >>= 1) {
        s += __shfl_down(s, off);
        ss += __shfl_down(ss, off);
    }
    __shared__ float red[4];
    if ((tid & 63) == 0) { red[tid >> 6] = s; red[2 + (tid >> 6)] = ss; }
    __syncthreads();
    float S = red[0] + red[1];
    float SS = red[2] + red[3];
    float mu = S * (1.0f / 512.0f);
    float var = SS * (1.0f / 512.0f) - mu * mu;
    float inv = rsqrtf(var + 1e-5f);
    int c = tid * 4;
    float4 o4;
    o4.x = (o[0] - mu) * inv * g[c + 0] + b[c + 0];
    o4.y = (o[1] - mu) * inv * g[c + 1] + b[c + 1];
    o4.z = (o[2] - mu) * inv * g[c + 2] + b[c + 2];
    o4.w = (o[3] - mu) * inv * g[c + 3] + b[c + 3];
    *(float4*)(hout + base) = o4;
}

__global__ void scale_emb(const float* __restrict__ e, const float* __restrict__ ak,
                          float* __restrict__ o, int n4) {
    int i = blockIdx.x * 256 + threadIdx.x;
    if (i >= n4) return;
    float4 v = ((const float4*)e)[i];
    int d0 = (i * 4) & (D - 1);
    v.x *= ak[d0]; v.y *= ak[d0 + 1]; v.z *= ak[d0 + 2]; v.w *= ak[d0 + 3];
    ((float4*)o)[i] = v;
}

extern "C" void kernel_launch(void* const* d_in, const int* in_sizes, int n_in,
                              void* d_out, int out_size, void* d_ws, size_t ws_size,
                              hipStream_t stream) {
    const float* embeddings = (const float*)d_in[0];
    const float* node_emb   = (const float*)d_in[1];
    const float* adapt_w    = (const float*)d_in[2];
    const float* adapt_b    = (const float*)d_in[3];
    const float* kw   = (const float*)d_in[4];
    const float* kb   = (const float*)d_in[5];
    const float* qw   = (const float*)d_in[6];
    const float* qb   = (const float*)d_in[7];
    const float* vw   = (const float*)d_in[8];
    const float* vb   = (const float*)d_in[9];
    const float* aw   = (const float*)d_in[10];
    const float* ab   = (const float*)d_in[11];
    const float* pri  = (const float*)d_in[12];
    const float* att_r = (const float*)d_in[13];
    const float* msg_r = (const float*)d_in[14];
    const float* skip  = (const float*)d_in[15];
    const float* ln_g  = (const float*)d_in[16];
    const float* ln_b  = (const float*)d_in[17];
    const float* out_w = (const float*)d_in[18];
    const float* out_b = (const float*)d_in[19];
    const float* attn_k = (const float*)d_in[20];
    const int* src = (const int*)d_in[21];
    const int* dst = (const int*)d_in[22];

    const int E  = in_sizes[21];
    const int NB = in_sizes[0] / D;   // 8192
    const int NN = in_sizes[1] / D;   // 20000
    const int NC = out_size / NB;     // 10000

    float* ws = (float*)d_ws;
    size_t big = (size_t)NN * D;
    float* hbuf = ws;
    float* kbuf = hbuf + big;
    float* qbuf = kbuf + big;
    float* vbuf = qbuf + big;
    float* aggb = vbuf + big;
    float* fwk = aggb + big;
    float* fbk = fwk + (size_t)D * D;
    float* fwv = fbk + D;
    float* fbv = fwv + (size_t)D * D;
    float* tbuf = fbv + D;
    int* offs   = (int*)(tbuf + (size_t)E * 8);  // NN+1
    int* cursor = offs + NN + 1;                 // NN  (also used as counts)
    int* eidx   = cursor + NN;                   // E
    // reuse after layers:
    float* clsb = qbuf;
    float* embs = vbuf;

    auto ggrid = [](int M, int N) { return dim3((N + 127) / 128, (M + 127) / 128); };

    // ---- CSR by dst (src/dst are layer-invariant) ----
    zero_int<<<(NN + 255) / 256, 256, 0, stream>>>(cursor, NN);
    hist_dst<<<(E + 255) / 256, 256, 0, stream>>>(dst, cursor, E);
    // scan reads counts from cursor's final state? No: counts are in cursor now.
    // Use eidx as temp counts copy target? Simpler: scan takes cnt=cursor, then
    // rewrites cursor with offsets (reads all cnt first within same thread chunk).
    // But Hillis-Steele phase only touches LDS; per-thread chunk reads cnt[i]
    // then later writes cursor[i]=offs — same array, same thread, read-before-
    // write within the thread's sequential loop. Safe: each element read once
    // (prefix pass) before being overwritten (write pass) by the SAME thread.
    scan_counts<<<1, 1024, 0, stream>>>(cursor, offs, cursor, NN, E);
    scatter_edges<<<(E + 255) / 256, 256, 0, stream>>>(dst, cursor, eidx, E);

    // h = gelu(node_emb @ adapt_w^T + adapt_b)
    gemm_tn<0, 1><<<ggrid(NN, D), 256, 0, stream>>>(node_emb, adapt_w, adapt_b, hbuf, NN, D);

    for (int l = 0; l < NLAYER; ++l) {
        const size_t wo = (size_t)l * D * D;
        fuse_w<<<dim3(8, 8), 256, 0, stream>>>(kw + wo, kb + l * D, att_r + (size_t)l * H * DKH * DKH, fwk, fbk);
        fuse_w<<<dim3(8, 8), 256, 0, stream>>>(vw + wo, vb + l * D, msg_r + (size_t)l * H * DKH * DKH, fwv, fbv);
        gemm_tn<0, 0><<<ggrid(NN, D), 256, 0, stream>>>(hbuf, fwk, fbk, kbuf, NN, D);
        gemm_tn<0, 0><<<ggrid(NN, D), 256, 0, stream>>>(hbuf, qw + wo, qb + l * D, qbuf, NN, D);
        gemm_tn<0, 0><<<ggrid(NN, D), 256, 0, stream>>>(hbuf, fwv, fbv, vbuf, NN, D);

        edge_qk<<<(E + 3) / 4, 256, 0, stream>>>(kbuf, qbuf, src, dst, pri + l * H, tbuf, E);
        node_attn_agg<<<NN, 256, 0, stream>>>(vbuf, src, tbuf, offs, eidx, aggb);

        // trans = gelu(agg) @ aw^T + ab   (into kbuf)
        gemm_tn<1, 0><<<ggrid(NN, D), 256, 0, stream>>>(aggb, aw + wo, ab + l * D, kbuf, NN, D);
        blend_ln<<<NN, 128, 0, stream>>>(kbuf, hbuf, skip + l, ln_g + l * D, ln_b + l * D, hbuf);
    }

    // cls_emb = h[:NC] @ out_w^T + out_b
    gemm_tn<0, 0><<<ggrid(NC, D), 256, 0, stream>>>(hbuf, out_w, out_b, clsb, NC, D);
    // embs = embeddings * attn_kernels
    scale_emb<<<((NB * D / 4) + 255) / 256, 256, 0, stream>>>(embeddings, attn_k, embs, NB * D / 4);
    // logits = embs @ cls_emb^T
    gemm_tn<0, 0><<<ggrid(NB, NC), 256, 0, stream>>>(embs, clsb, nullptr, (float*)d_out, NB, NC);
}

// Round 3
// 1564.673 us; speedup vs baseline: 7.6675x; 2.1370x over previous
//
#include <hip/hip_runtime.h>
#include <hip/hip_bf16.h>

#define D 512
#define H 8
#define DKH 64
#define NLAYER 2

typedef __attribute__((ext_vector_type(8))) short short8;
typedef __attribute__((ext_vector_type(4))) float f32x4;

__device__ __forceinline__ float gelu_f(float x) {
    float x3 = x * x * x;
    return 0.5f * x * (1.0f + tanhf(0.7978845608028654f * (x + 0.044715f * x3)));
}

// fp32 -> bf16 bits, round-to-nearest-even
__device__ __forceinline__ short f2b(float x) {
    unsigned u = __float_as_uint(x);
    u += 0x7FFF + ((u >> 16) & 1);
    return (short)(u >> 16);
}

// ---------------------------------------------------------------------------
// C[M,N] = postact( A[M,K] @ Bw[N,K]^T + bias ) via bf16 MFMA, fp32 accum.
// 128x128 tile, BK=32, 256 threads = 4 waves (2x2 of 64x64), 4x4 16x16 frags.
// A,Bw fp32 in HBM; converted to bf16 during LDS staging. PREG: gelu on A.
// ---------------------------------------------------------------------------
template <int PREG, int POSTG>
__global__ __launch_bounds__(256) void gemm_mfma(
    const float* __restrict__ A, const float* __restrict__ Bw,
    const float* __restrict__ bias, float* __restrict__ C,
    int M, int N, int K) {
    // bf16 tiles, row stride 40 shorts (80 B): 16B-aligned rows, 2-way-free banks
    __shared__ __align__(16) short As[128 * 40];
    __shared__ __align__(16) short Bs[128 * 40];
    const int bm = blockIdx.y * 128, bn = blockIdx.x * 128;
    const int tid = threadIdx.x;
    const int lane = tid & 63;
    const int wave = tid >> 6;
    const int wm = (wave >> 1) * 64, wn = (wave & 1) * 64;
    const int lr16 = lane & 15;          // fragment row (A) / col (B)
    const int lk8 = (lane >> 4) * 8;     // k-offset within BK=32

    // staging: thread t loads row t>>1, k-chunk (t&1)*16 (16 floats)
    const int srow = tid >> 1;
    const int skb = (tid & 1) * 16;
    const float* Ap = A + (size_t)(bm + srow) * K + skb;
    const float* Bp = Bw + (size_t)(bn + srow) * K + skb;
    const bool avld = (bm + srow) < M;
    const bool bvld = (bn + srow) < N;

    f32x4 acc[4][4];
#pragma unroll
    for (int i = 0; i < 4; ++i)
#pragma unroll
        for (int j = 0; j < 4; ++j) acc[i][j] = (f32x4){0.f, 0.f, 0.f, 0.f};

    float ar[16], br[16];
    auto load_ab = [&](int k0) {
        if (avld) {
            *(float4*)&ar[0]  = *(const float4*)(Ap + k0);
            *(float4*)&ar[4]  = *(const float4*)(Ap + k0 + 4);
            *(float4*)&ar[8]  = *(const float4*)(Ap + k0 + 8);
            *(float4*)&ar[12] = *(const float4*)(Ap + k0 + 12);
        } else {
#pragma unroll
            for (int j = 0; j < 16; ++j) ar[j] = 0.f;
        }
        if (bvld) {
            *(float4*)&br[0]  = *(const float4*)(Bp + k0);
            *(float4*)&br[4]  = *(const float4*)(Bp + k0 + 4);
            *(float4*)&br[8]  = *(const float4*)(Bp + k0 + 8);
            *(float4*)&br[12] = *(const float4*)(Bp + k0 + 12);
        } else {
#pragma unroll
            for (int j = 0; j < 16; ++j) br[j] = 0.f;
        }
    };

    load_ab(0);
    for (int k0 = 0; k0 < K; k0 += 32) {
        __syncthreads();  // prev compute done before overwriting LDS
        short8 aw0, aw1, bw0, bw1;
#pragma unroll
        for (int j = 0; j < 8; ++j) {
            float a0 = PREG ? gelu_f(ar[j]) : ar[j];
            float a1 = PREG ? gelu_f(ar[j + 8]) : ar[j + 8];
            aw0[j] = f2b(a0);
            aw1[j] = f2b(a1);
            bw0[j] = f2b(br[j]);
            bw1[j] = f2b(br[j + 8]);
        }
        *(short8*)&As[srow * 40 + skb]     = aw0;
        *(short8*)&As[srow * 40 + skb + 8] = aw1;
        *(short8*)&Bs[srow * 40 + skb]     = bw0;
        *(short8*)&Bs[srow * 40 + skb + 8] = bw1;
        __syncthreads();
        if (k0 + 32 < K) load_ab(k0 + 32);  // prefetch next tile (overlaps MFMA)

        short8 af[4], bfr[4];
#pragma unroll
        for (int mi = 0; mi < 4; ++mi)
            af[mi] = *(const short8*)&As[(wm + mi * 16 + lr16) * 40 + lk8];
#pragma unroll
        for (int ni = 0; ni < 4; ++ni)
            bfr[ni] = *(const short8*)&Bs[(wn + ni * 16 + lr16) * 40 + lk8];
#pragma unroll
        for (int mi = 0; mi < 4; ++mi)
#pragma unroll
            for (int ni = 0; ni < 4; ++ni)
                acc[mi][ni] = __builtin_amdgcn_mfma_f32_16x16x32_bf16(
                    af[mi], bfr[ni], acc[mi][ni], 0, 0, 0);
    }

    // epilogue: C/D layout col=lane&15, row=(lane>>4)*4+reg  [m89 verified]
#pragma unroll
    for (int mi = 0; mi < 4; ++mi) {
        int row0 = bm + wm + mi * 16 + (lane >> 4) * 4;
#pragma unroll
        for (int ni = 0; ni < 4; ++ni) {
            int col = bn + wn + ni * 16 + lr16;
            if (col < N) {
                float bsv = bias ? bias[col] : 0.0f;
#pragma unroll
                for (int r = 0; r < 4; ++r) {
                    int row = row0 + r;
                    if (row < M) {
                        float v = acc[mi][ni][r] + bsv;
                        if (POSTG) v = gelu_f(v);
                        C[(size_t)row * N + col] = v;
                    }
                }
            }
        }
    }
}

// ---------------------------------------------------------------------------
// fold att_r/msg_r into the K/V projection weight:
// fw[h*64+j][d] = sum_i r[h][i][j] * w[h*64+i][d];  fb likewise from bias.
// ---------------------------------------------------------------------------
__global__ __launch_bounds__(256) void fuse_w(
    const float* __restrict__ w, const float* __restrict__ bsrc,
    const float* __restrict__ r, float* __restrict__ fw, float* __restrict__ fb) {
    int h = blockIdx.y;
    int dc = blockIdx.x * 64;
    __shared__ float rs[64][64];
    int tid = threadIdx.x;
    for (int i = tid; i < 4096; i += 256) rs[i >> 6][i & 63] = r[h * 4096 + i];
    __syncthreads();
    for (int rep = 0; rep < 16; ++rep) {
        int o = rep * 256 + tid;
        int j = o >> 6;
        int dd = o & 63;
        float s = 0.0f;
#pragma unroll 8
        for (int i = 0; i < 64; ++i)
            s = fmaf(rs[i][j], w[(size_t)(h * 64 + i) * D + dc + dd], s);
        fw[(size_t)(h * 64 + j) * D + dc + dd] = s;
    }
    if (blockIdx.x == 0 && tid < 64) {
        float s = 0.0f;
        for (int i = 0; i < 64; ++i) s += bsrc[h * 64 + i] * rs[i][tid];
        fb[h * 64 + tid] = s;
    }
}

// ---------------------------------------------------------------------------
// CSR build by dst:  hist -> scan -> scatter
// ---------------------------------------------------------------------------
__global__ void zero_int(int* __restrict__ p, int n) {
    int i = blockIdx.x * 256 + threadIdx.x;
    if (i < n) p[i] = 0;
}

__global__ void hist_dst(const int* __restrict__ dst, int* __restrict__ cnt, int E) {
    int i = blockIdx.x * 256 + threadIdx.x;
    if (i < E) atomicAdd(&cnt[dst[i]], 1);
}

__global__ __launch_bounds__(1024) void scan_counts(
    const int* __restrict__ cnt, int* __restrict__ offs, int* __restrict__ cursor,
    int n, int E) {
    __shared__ int part[1024];
    int t = threadIdx.x;
    int chunk = (n + 1023) >> 10;
    int lo = t * chunk;
    int hi = min(lo + chunk, n);
    int s = 0;
    for (int i = lo; i < hi; ++i) s += cnt[i];
    part[t] = s;
    __syncthreads();
    for (int off = 1; off < 1024; off <<= 1) {
        int v = (t >= off) ? part[t - off] : 0;
        __syncthreads();
        part[t] += v;
        __syncthreads();
    }
    int base = (t == 0) ? 0 : part[t - 1];
    for (int i = lo; i < hi; ++i) {
        offs[i] = base;
        cursor[i] = base;
        base += cnt[i];
    }
    if (t == 1023) offs[n] = E;
}

__global__ void scatter_edges(const int* __restrict__ dst, int* __restrict__ cursor,
                              int* __restrict__ eidx, int E) {
    int i = blockIdx.x * 256 + threadIdx.x;
    if (i < E) {
        int pos = atomicAdd(&cursor[dst[i]], 1);
        eidx[pos] = i;
    }
}

// ---------------------------------------------------------------------------
// pass 1: t[e][h] = dot(k[src],q[dst]) per head * pri[h]/8. one wave per edge.
// ---------------------------------------------------------------------------
__global__ __launch_bounds__(256) void edge_qk(
    const float* __restrict__ kbuf, const float* __restrict__ qbuf,
    const int* __restrict__ src, const int* __restrict__ dst,
    const float* __restrict__ pri, float* __restrict__ t, int E) {
    int e = blockIdx.x * 4 + (threadIdx.x >> 6);
    if (e >= E) return;
    int lane = threadIdx.x & 63;
    int s = src[e], d = dst[e];
    const float4* kp = (const float4*)(kbuf + (size_t)s * D);
    const float4* qp = (const float4*)(qbuf + (size_t)d * D);
    float4 k0 = kp[lane * 2], k1 = kp[lane * 2 + 1];
    float4 q0 = qp[lane * 2], q1 = qp[lane * 2 + 1];
    float sum = k0.x * q0.x + k0.y * q0.y + k0.z * q0.z + k0.w * q0.w +
                k1.x * q1.x + k1.y * q1.y + k1.z * q1.z + k1.w * q1.w;
    sum += __shfl_xor(sum, 1);
    sum += __shfl_xor(sum, 2);
    sum += __shfl_xor(sum, 4);
    int h = lane >> 3;
    if ((lane & 7) == 0) t[(size_t)e * 8 + h] = sum * pri[h] * 0.125f;
}

// ---------------------------------------------------------------------------
// Per-dst-node softmax + aggregation, gather-based, zero atomics.
// ---------------------------------------------------------------------------
__global__ __launch_bounds__(256) void node_attn_agg(
    const float* __restrict__ vbuf, const int* __restrict__ src,
    const float* __restrict__ t, const int* __restrict__ offs,
    const int* __restrict__ eidx, float* __restrict__ agg) {
    int n = blockIdx.x;
    int tid = threadIdx.x;
    int start = offs[n], end = offs[n + 1];
    __shared__ float red[32][8];
    __shared__ float smx[8], sinv[8];
    int h = tid & 7, sub = tid >> 3;

    float m = -INFINITY;
    for (int i = start + sub; i < end; i += 32)
        m = fmaxf(m, t[(size_t)eidx[i] * 8 + h]);
    red[sub][h] = m;
    __syncthreads();
    if (tid < 8) {
        float mm = -INFINITY;
#pragma unroll
        for (int s2 = 0; s2 < 32; ++s2) mm = fmaxf(mm, red[s2][tid]);
        smx[tid] = mm;
    }
    __syncthreads();
    float mh = smx[h];
    float s = 0.0f;
    for (int i = start + sub; i < end; i += 32)
        s += expf(t[(size_t)eidx[i] * 8 + h] - mh);
    red[sub][h] = s;
    __syncthreads();
    if (tid < 8) {
        float ss = 0.0f;
#pragma unroll
        for (int s2 = 0; s2 < 32; ++s2) ss += red[s2][tid];
        sinv[tid] = 1.0f / fmaxf(ss, 1e-9f);
    }
    __syncthreads();

    int h2 = tid >> 5;  // head for cols [2*tid, 2*tid+1]
    float mx2 = smx[h2], inv2 = sinv[h2];
    float ax = 0.0f, ay = 0.0f;
    for (int i = start; i < end; ++i) {
        int e = eidx[i];
        int sn = src[e];
        float a = expf(t[(size_t)e * 8 + h2] - mx2) * inv2;
        float2 v = *(const float2*)(vbuf + (size_t)sn * D + tid * 2);
        ax = fmaf(v.x, a, ax);
        ay = fmaf(v.y, a, ay);
    }
    *(float2*)(agg + (size_t)n * D + tid * 2) = make_float2(ax, ay);
}

// out = trans*alpha + h*(1-alpha); layernorm; write to hout. 1 block / node.
__global__ __launch_bounds__(128) void blend_ln(
    const float* __restrict__ trans, const float* __restrict__ hin,
    const float* __restrict__ skip, const float* __restrict__ g,
    const float* __restrict__ b, float* __restrict__ hout) {
    int n = blockIdx.x;
    int tid = threadIdx.x;  // 0..127
    float alpha = 1.0f / (1.0f + expf(-skip[0]));
    size_t base = (size_t)n * D + tid * 4;
    float4 t4 = *(const float4*)(trans + base);
    float4 h4 = *(const float4*)(hin + base);
    float o[4];
    o[0] = t4.x * alpha + h4.x * (1.0f - alpha);
    o[1] = t4.y * alpha + h4.y * (1.0f - alpha);
    o[2] = t4.z * alpha + h4.z * (1.0f - alpha);
    o[3] = t4.w * alpha + h4.w * (1.0f - alpha);
    float s = o[0] + o[1] + o[2] + o[3];
    float ss = o[0] * o[0] + o[1] * o[1] + o[2] * o[2] + o[3] * o[3];
    for (int off = 32; off; off >>= 1) {
        s += __shfl_down(s, off);
        ss += __shfl_down(ss, off);
    }
    __shared__ float red[4];
    if ((tid & 63) == 0) { red[tid >> 6] = s; red[2 + (tid >> 6)] = ss; }
    __syncthreads();
    float S = red[0] + red[1];
    float SS = red[2] + red[3];
    float mu = S * (1.0f / 512.0f);
    float var = SS * (1.0f / 512.0f) - mu * mu;
    float inv = rsqrtf(var + 1e-5f);
    int c = tid * 4;
    float4 o4;
    o4.x = (o[0] - mu) * inv * g[c + 0] + b[c + 0];
    o4.y = (o[1] - mu) * inv * g[c + 1] + b[c + 1];
    o4.z = (o[2] - mu) * inv * g[c + 2] + b[c + 2];
    o4.w = (o[3] - mu) * inv * g[c + 3] + b[c + 3];
    *(float4*)(hout + base) = o4;
}

__global__ void scale_emb(const float* __restrict__ e, const float* __restrict__ ak,
                          float* __restrict__ o, int n4) {
    int i = blockIdx.x * 256 + threadIdx.x;
    if (i >= n4) return;
    float4 v = ((const float4*)e)[i];
    int d0 = (i * 4) & (D - 1);
    v.x *= ak[d0]; v.y *= ak[d0 + 1]; v.z *= ak[d0 + 2]; v.w *= ak[d0 + 3];
    ((float4*)o)[i] = v;
}

extern "C" void kernel_launch(void* const* d_in, const int* in_sizes, int n_in,
                              void* d_out, int out_size, void* d_ws, size_t ws_size,
                              hipStream_t stream) {
    const float* embeddings = (const float*)d_in[0];
    const float* node_emb   = (const float*)d_in[1];
    const float* adapt_w    = (const float*)d_in[2];
    const float* adapt_b    = (const float*)d_in[3];
    const float* kw   = (const float*)d_in[4];
    const float* kb   = (const float*)d_in[5];
    const float* qw   = (const float*)d_in[6];
    const float* qb   = (const float*)d_in[7];
    const float* vw   = (const float*)d_in[8];
    const float* vb   = (const float*)d_in[9];
    const float* aw   = (const float*)d_in[10];
    const float* ab   = (const float*)d_in[11];
    const float* pri  = (const float*)d_in[12];
    const float* att_r = (const float*)d_in[13];
    const float* msg_r = (const float*)d_in[14];
    const float* skip  = (const float*)d_in[15];
    const float* ln_g  = (const float*)d_in[16];
    const float* ln_b  = (const float*)d_in[17];
    const float* out_w = (const float*)d_in[18];
    const float* out_b = (const float*)d_in[19];
    const float* attn_k = (const float*)d_in[20];
    const int* src = (const int*)d_in[21];
    const int* dst = (const int*)d_in[22];

    const int E  = in_sizes[21];
    const int NB = in_sizes[0] / D;   // 8192
    const int NN = in_sizes[1] / D;   // 20000
    const int NC = out_size / NB;     // 10000

    float* ws = (float*)d_ws;
    size_t big = (size_t)NN * D;
    float* hbuf = ws;
    float* kbuf = hbuf + big;
    float* qbuf = kbuf + big;
    float* vbuf = qbuf + big;
    float* aggb = vbuf + big;
    float* fwk = aggb + big;
    float* fbk = fwk + (size_t)D * D;
    float* fwv = fbk + D;
    float* fbv = fwv + (size_t)D * D;
    float* tbuf = fbv + D;
    int* offs   = (int*)(tbuf + (size_t)E * 8);  // NN+1
    int* cursor = offs + NN + 1;                 // NN  (also counts)
    int* eidx   = cursor + NN;                   // E
    // reuse after layers:
    float* clsb = qbuf;
    float* embs = vbuf;

    auto ggrid = [](int M, int N) { return dim3((N + 127) / 128, (M + 127) / 128); };

    // ---- CSR by dst (src/dst are layer-invariant) ----
    zero_int<<<(NN + 255) / 256, 256, 0, stream>>>(cursor, NN);
    hist_dst<<<(E + 255) / 256, 256, 0, stream>>>(dst, cursor, E);
    scan_counts<<<1, 1024, 0, stream>>>(cursor, offs, cursor, NN, E);
    scatter_edges<<<(E + 255) / 256, 256, 0, stream>>>(dst, cursor, eidx, E);

    // h = gelu(node_emb @ adapt_w^T + adapt_b)
    gemm_mfma<0, 1><<<ggrid(NN, D), 256, 0, stream>>>(node_emb, adapt_w, adapt_b, hbuf, NN, D, D);

    for (int l = 0; l < NLAYER; ++l) {
        const size_t wo = (size_t)l * D * D;
        fuse_w<<<dim3(8, 8), 256, 0, stream>>>(kw + wo, kb + l * D, att_r + (size_t)l * H * DKH * DKH, fwk, fbk);
        fuse_w<<<dim3(8, 8), 256, 0, stream>>>(vw + wo, vb + l * D, msg_r + (size_t)l * H * DKH * DKH, fwv, fbv);
        gemm_mfma<0, 0><<<ggrid(NN, D), 256, 0, stream>>>(hbuf, fwk, fbk, kbuf, NN, D, D);
        gemm_mfma<0, 0><<<ggrid(NN, D), 256, 0, stream>>>(hbuf, qw + wo, qb + l * D, qbuf, NN, D, D);
        gemm_mfma<0, 0><<<ggrid(NN, D), 256, 0, stream>>>(hbuf, fwv, fbv, vbuf, NN, D, D);

        edge_qk<<<(E + 3) / 4, 256, 0, stream>>>(kbuf, qbuf, src, dst, pri + l * H, tbuf, E);
        node_attn_agg<<<NN, 256, 0, stream>>>(vbuf, src, tbuf, offs, eidx, aggb);

        // trans = gelu(agg) @ aw^T + ab   (into kbuf)
        gemm_mfma<1, 0><<<ggrid(NN, D), 256, 0, stream>>>(aggb, aw + wo, ab + l * D, kbuf, NN, D, D);
        blend_ln<<<NN, 128, 0, stream>>>(kbuf, hbuf, skip + l, ln_g + l * D, ln_b + l * D, hbuf);
    }

    // cls_emb = h[:NC] @ out_w^T + out_b
    gemm_mfma<0, 0><<<ggrid(NC, D), 256, 0, stream>>>(hbuf, out_w, out_b, clsb, NC, D, D);
    // embs = embeddings * attn_kernels
    scale_emb<<<((NB * D / 4) + 255) / 256, 256, 0, stream>>>(embeddings, attn_k, embs, NB * D / 4);
    // logits = embs @ cls_emb^T
    gemm_mfma<0, 0><<<ggrid(NB, NC), 256, 0, stream>>>(embs, clsb, nullptr, (float*)d_out, NB, NC, D);
}

// Round 4
// 1154.028 us; speedup vs baseline: 10.3958x; 1.3558x over previous
//
#include <hip/hip_runtime.h>
#include <hip/hip_bf16.h>

#define D 512
#define H 8
#define NLAYER 2

typedef __attribute__((ext_vector_type(8))) short short8;
typedef __attribute__((ext_vector_type(4))) short short4v;
typedef __attribute__((ext_vector_type(4))) float f32x4;

__device__ __forceinline__ float gelu_f(float x) {
    float x3 = x * x * x;
    return 0.5f * x * (1.0f + tanhf(0.7978845608028654f * (x + 0.044715f * x3)));
}

// fp32 -> bf16 bits, round-to-nearest-even
__device__ __forceinline__ unsigned short f2b(float x) {
    unsigned u = __float_as_uint(x);
    u += 0x7FFF + ((u >> 16) & 1);
    return (unsigned short)(u >> 16);
}
__device__ __forceinline__ float b2f(unsigned short u) {
    return __uint_as_float(((unsigned)u) << 16);
}

// ---------------------------------------------------------------------------
// C[M,N] = postact( A[M,K] @ B[N,K]^T + bias ), A/B bf16-resident, fp32 accum.
// 128x128 tile, BK=32, 256 threads = 4 waves (2x2 of 64x64), 4x4 16x16x32.
// OUTMODE: 0 = f32 out, 1 = bf16 out, 2 = both. XCD-bijective block swizzle.
// ---------------------------------------------------------------------------
template <int POSTG, int OUTMODE>
__global__ __launch_bounds__(256) void gemm_bf(
    const short* __restrict__ A, const short* __restrict__ B,
    const float* __restrict__ bias, float* __restrict__ Cf,
    short* __restrict__ Cb, int M, int N, int K) {
    __shared__ __align__(16) short As[128 * 40];
    __shared__ __align__(16) short Bs[128 * 40];
    // bijective XCD swizzle (m204)
    unsigned nwg = gridDim.x * gridDim.y;
    unsigned orig = blockIdx.y * gridDim.x + blockIdx.x;
    unsigned qq = nwg >> 3, rr = nwg & 7;
    unsigned xcd = orig & 7, sidx = orig >> 3;
    unsigned swz = (xcd < rr ? xcd * (qq + 1) : rr * (qq + 1) + (xcd - rr) * qq) + sidx;
    const int bn = (int)(swz % gridDim.x) * 128;
    const int bm = (int)(swz / gridDim.x) * 128;

    const int tid = threadIdx.x;
    const int lane = tid & 63;
    const int wave = tid >> 6;
    const int wm = (wave >> 1) * 64, wn = (wave & 1) * 64;
    const int lr16 = lane & 15;
    const int lk8 = (lane >> 4) * 8;

    // staging: thread t -> row t>>1, k-chunk (t&1)*16 (16 bf16 = 32 B)
    const int srow = tid >> 1;
    const int skb = (tid & 1) * 16;
    const int arow = min(bm + srow, M - 1);  // clamp: garbage rows discarded at write
    const int brow = min(bn + srow, N - 1);
    const short* Ap = A + (size_t)arow * K + skb;
    const short* Bp = B + (size_t)brow * K + skb;

    f32x4 acc[4][4];
#pragma unroll
    for (int i = 0; i < 4; ++i)
#pragma unroll
        for (int j = 0; j < 4; ++j) acc[i][j] = (f32x4){0.f, 0.f, 0.f, 0.f};

    short8 ra0, ra1, rb0, rb1;
    auto load_ab = [&](int k0) {
        ra0 = *(const short8*)(Ap + k0);
        ra1 = *(const short8*)(Ap + k0 + 8);
        rb0 = *(const short8*)(Bp + k0);
        rb1 = *(const short8*)(Bp + k0 + 8);
    };

    load_ab(0);
    for (int k0 = 0; k0 < K; k0 += 32) {
        __syncthreads();
        *(short8*)&As[srow * 40 + skb]     = ra0;
        *(short8*)&As[srow * 40 + skb + 8] = ra1;
        *(short8*)&Bs[srow * 40 + skb]     = rb0;
        *(short8*)&Bs[srow * 40 + skb + 8] = rb1;
        __syncthreads();
        if (k0 + 32 < K) load_ab(k0 + 32);  // prefetch next tile under MFMA

        short8 af[4], bfr[4];
#pragma unroll
        for (int mi = 0; mi < 4; ++mi)
            af[mi] = *(const short8*)&As[(wm + mi * 16 + lr16) * 40 + lk8];
#pragma unroll
        for (int ni = 0; ni < 4; ++ni)
            bfr[ni] = *(const short8*)&Bs[(wn + ni * 16 + lr16) * 40 + lk8];
#pragma unroll
        for (int mi = 0; mi < 4; ++mi)
#pragma unroll
            for (int ni = 0; ni < 4; ++ni)
                acc[mi][ni] = __builtin_amdgcn_mfma_f32_16x16x32_bf16(
                    af[mi], bfr[ni], acc[mi][ni], 0, 0, 0);
    }

    // epilogue: C/D layout col=lane&15, row=(lane>>4)*4+reg  [m89 verified]
#pragma unroll
    for (int mi = 0; mi < 4; ++mi) {
        int row0 = bm + wm + mi * 16 + (lane >> 4) * 4;
#pragma unroll
        for (int ni = 0; ni < 4; ++ni) {
            int col = bn + wn + ni * 16 + lr16;
            if (col < N) {
                float bsv = bias ? bias[col] : 0.0f;
#pragma unroll
                for (int r = 0; r < 4; ++r) {
                    int row = row0 + r;
                    if (row < M) {
                        float v = acc[mi][ni][r] + bsv;
                        if (POSTG) v = gelu_f(v);
                        if (OUTMODE != 1) Cf[(size_t)row * N + col] = v;
                        if (OUTMODE != 0) Cb[(size_t)row * N + col] = (short)f2b(v);
                    }
                }
            }
        }
    }
}

// fp32 -> bf16 bulk convert, 8 elems/thread
__global__ void cvt_b16(const float* __restrict__ in, short* __restrict__ out, int n8) {
    int i = blockIdx.x * 256 + threadIdx.x;
    if (i >= n8) return;
    float4 a = ((const float4*)in)[i * 2];
    float4 b = ((const float4*)in)[i * 2 + 1];
    short8 o;
    o[0] = f2b(a.x); o[1] = f2b(a.y); o[2] = f2b(a.z); o[3] = f2b(a.w);
    o[4] = f2b(b.x); o[5] = f2b(b.y); o[6] = f2b(b.z); o[7] = f2b(b.w);
    *(short8*)(out + (size_t)i * 8) = o;
}

// ---------------------------------------------------------------------------
// fold att_r/msg_r into the K/V projection weight; write bf16 weight.
// ---------------------------------------------------------------------------
__global__ __launch_bounds__(256) void fuse_w(
    const float* __restrict__ w, const float* __restrict__ bsrc,
    const float* __restrict__ r, short* __restrict__ fw, float* __restrict__ fb) {
    int h = blockIdx.y;
    int dc = blockIdx.x * 64;
    __shared__ float rs[64][64];
    int tid = threadIdx.x;
    for (int i = tid; i < 4096; i += 256) rs[i >> 6][i & 63] = r[h * 4096 + i];
    __syncthreads();
    for (int rep = 0; rep < 16; ++rep) {
        int o = rep * 256 + tid;
        int j = o >> 6;
        int dd = o & 63;
        float s = 0.0f;
#pragma unroll 8
        for (int i = 0; i < 64; ++i)
            s = fmaf(rs[i][j], w[(size_t)(h * 64 + i) * D + dc + dd], s);
        fw[(size_t)(h * 64 + j) * D + dc + dd] = (short)f2b(s);
    }
    if (blockIdx.x == 0 && tid < 64) {
        float s = 0.0f;
        for (int i = 0; i < 64; ++i) s += bsrc[h * 64 + i] * rs[i][tid];
        fb[h * 64 + tid] = s;
    }
}

// ---------------------------------------------------------------------------
// CSR build by dst:  hist -> scan -> scatter
// ---------------------------------------------------------------------------
__global__ void zero_int(int* __restrict__ p, int n) {
    int i = blockIdx.x * 256 + threadIdx.x;
    if (i < n) p[i] = 0;
}

__global__ void hist_dst(const int* __restrict__ dst, int* __restrict__ cnt, int E) {
    int i = blockIdx.x * 256 + threadIdx.x;
    if (i < E) atomicAdd(&cnt[dst[i]], 1);
}

__global__ __launch_bounds__(1024) void scan_counts(
    const int* __restrict__ cnt, int* __restrict__ offs, int* __restrict__ cursor,
    int n, int E) {
    __shared__ int part[1024];
    int t = threadIdx.x;
    int chunk = (n + 1023) >> 10;
    int lo = t * chunk;
    int hi = min(lo + chunk, n);
    int s = 0;
    for (int i = lo; i < hi; ++i) s += cnt[i];
    part[t] = s;
    __syncthreads();
    for (int off = 1; off < 1024; off <<= 1) {
        int v = (t >= off) ? part[t - off] : 0;
        __syncthreads();
        part[t] += v;
        __syncthreads();
    }
    int base = (t == 0) ? 0 : part[t - 1];
    for (int i = lo; i < hi; ++i) {
        offs[i] = base;
        cursor[i] = base;
        base += cnt[i];
    }
    if (t == 1023) offs[n] = E;
}

__global__ void scatter_edges(const int* __restrict__ dst, int* __restrict__ cursor,
                              int* __restrict__ eidx, int E) {
    int i = blockIdx.x * 256 + threadIdx.x;
    if (i < E) {
        int pos = atomicAdd(&cursor[dst[i]], 1);
        eidx[pos] = i;
    }
}

// ---------------------------------------------------------------------------
// t[e][h] = dot(k[src],q[dst]) per head * pri[h]/8. one wave per edge, bf16 in.
// ---------------------------------------------------------------------------
__global__ __launch_bounds__(256) void edge_qk(
    const short* __restrict__ kbuf, const short* __restrict__ qbuf,
    const int* __restrict__ src, const int* __restrict__ dst,
    const float* __restrict__ pri, float* __restrict__ t, int E) {
    int e = blockIdx.x * 4 + (threadIdx.x >> 6);
    if (e >= E) return;
    int lane = threadIdx.x & 63;
    int s = src[e], d = dst[e];
    short8 kv = *(const short8*)(kbuf + (size_t)s * D + lane * 8);
    short8 qv = *(const short8*)(qbuf + (size_t)d * D + lane * 8);
    float sum = 0.0f;
#pragma unroll
    for (int j = 0; j < 8; ++j)
        sum = fmaf(b2f((unsigned short)kv[j]), b2f((unsigned short)qv[j]), sum);
    sum += __shfl_xor(sum, 1);
    sum += __shfl_xor(sum, 2);
    sum += __shfl_xor(sum, 4);
    int h = lane >> 3;
    if ((lane & 7) == 0) t[(size_t)e * 8 + h] = sum * pri[h] * 0.125f;
}

// ---------------------------------------------------------------------------
// Per-dst-node softmax + aggregation (gather, no atomics), bf16 v in,
// writes gelu(agg) as bf16 (A-operand of the trans GEMM).
// ---------------------------------------------------------------------------
__global__ __launch_bounds__(256) void node_attn_agg(
    const short* __restrict__ vbuf, const int* __restrict__ src,
    const float* __restrict__ t, const int* __restrict__ offs,
    const int* __restrict__ eidx, short* __restrict__ gg) {
    int n = blockIdx.x;
    int tid = threadIdx.x;
    int start = offs[n], end = offs[n + 1];
    __shared__ float red[32][8];
    __shared__ float smx[8], sinv[8];
    int h = tid & 7, sub = tid >> 3;

    float m = -INFINITY;
    for (int i = start + sub; i < end; i += 32)
        m = fmaxf(m, t[(size_t)eidx[i] * 8 + h]);
    red[sub][h] = m;
    __syncthreads();
    if (tid < 8) {
        float mm = -INFINITY;
#pragma unroll
        for (int s2 = 0; s2 < 32; ++s2) mm = fmaxf(mm, red[s2][tid]);
        smx[tid] = mm;
    }
    __syncthreads();
    float mh = smx[h];
    float s = 0.0f;
    for (int i = start + sub; i < end; i += 32)
        s += expf(t[(size_t)eidx[i] * 8 + h] - mh);
    red[sub][h] = s;
    __syncthreads();
    if (tid < 8) {
        float ss = 0.0f;
#pragma unroll
        for (int s2 = 0; s2 < 32; ++s2) ss += red[s2][tid];
        sinv[tid] = 1.0f / fmaxf(ss, 1e-9f);
    }
    __syncthreads();

    int h2 = tid >> 5;  // head for elems [2*tid, 2*tid+1]
    float mx2 = smx[h2], inv2 = sinv[h2];
    float ax = 0.0f, ay = 0.0f;
    for (int i = start; i < end; ++i) {
        int e = eidx[i];
        int sn = src[e];
        float a = expf(t[(size_t)e * 8 + h2] - mx2) * inv2;
        unsigned vv = ((const unsigned*)(vbuf + (size_t)sn * D))[tid];
        ax = fmaf(b2f((unsigned short)vv), a, ax);
        ay = fmaf(b2f((unsigned short)(vv >> 16)), a, ay);
    }
    unsigned pack = (unsigned)(unsigned short)f2b(gelu_f(ax)) |
                    ((unsigned)(unsigned short)f2b(gelu_f(ay)) << 16);
    ((unsigned*)(gg + (size_t)n * D))[tid] = pack;
}

// out = trans*alpha + h*(1-alpha); layernorm; write fp32 h + bf16 h.
__global__ __launch_bounds__(128) void blend_ln(
    const float* __restrict__ trans, const float* __restrict__ hin,
    const float* __restrict__ skip, const float* __restrict__ g,
    const float* __restrict__ b, float* __restrict__ hout,
    short* __restrict__ hb16) {
    int n = blockIdx.x;
    int tid = threadIdx.x;  // 0..127
    float alpha = 1.0f / (1.0f + expf(-skip[0]));
    size_t base = (size_t)n * D + tid * 4;
    float4 t4 = *(const float4*)(trans + base);
    float4 h4 = *(const float4*)(hin + base);
    float o[4];
    o[0] = t4.x * alpha + h4.x * (1.0f - alpha);
    o[1] = t4.y * alpha + h4.y * (1.0f - alpha);
    o[2] = t4.z * alpha + h4.z * (1.0f - alpha);
    o[3] = t4.w * alpha + h4.w * (1.0f - alpha);
    float s = o[0] + o[1] + o[2] + o[3];
    float ss = o[0] * o[0] + o[1] * o[1] + o[2] * o[2] + o[3] * o[3];
    for (int off = 32; off; off >>= 1) {
        s += __shfl_down(s, off);
        ss += __shfl_down(ss, off);
    }
    __shared__ float red[4];
    if ((tid & 63) == 0) { red[tid >> 6] = s; red[2 + (tid >> 6)] = ss; }
    __syncthreads();
    float S = red[0] + red[1];
    float SS = red[2] + red[3];
    float mu = S * (1.0f / 512.0f);
    float var = SS * (1.0f / 512.0f) - mu * mu;
    float inv = rsqrtf(var + 1e-5f);
    int c = tid * 4;
    float4 o4;
    o4.x = (o[0] - mu) * inv * g[c + 0] + b[c + 0];
    o4.y = (o[1] - mu) * inv * g[c + 1] + b[c + 1];
    o4.z = (o[2] - mu) * inv * g[c + 2] + b[c + 2];
    o4.w = (o[3] - mu) * inv * g[c + 3] + b[c + 3];
    *(float4*)(hout + base) = o4;
    short4v hb;
    hb[0] = f2b(o4.x); hb[1] = f2b(o4.y); hb[2] = f2b(o4.z); hb[3] = f2b(o4.w);
    *(short4v*)(hb16 + base) = hb;
}

// embs16 = bf16(embeddings * attn_kernels), 8 elems/thread
__global__ void scale_emb_b16(const float* __restrict__ e, const float* __restrict__ ak,
                              short* __restrict__ o, int n8) {
    int i = blockIdx.x * 256 + threadIdx.x;
    if (i >= n8) return;
    float4 a = ((const float4*)e)[i * 2];
    float4 b = ((const float4*)e)[i * 2 + 1];
    int d0 = (i * 8) & (D - 1);
    short8 v;
    v[0] = f2b(a.x * ak[d0 + 0]); v[1] = f2b(a.y * ak[d0 + 1]);
    v[2] = f2b(a.z * ak[d0 + 2]); v[3] = f2b(a.w * ak[d0 + 3]);
    v[4] = f2b(b.x * ak[d0 + 4]); v[5] = f2b(b.y * ak[d0 + 5]);
    v[6] = f2b(b.z * ak[d0 + 6]); v[7] = f2b(b.w * ak[d0 + 7]);
    *(short8*)(o + (size_t)i * 8) = v;
}

extern "C" void kernel_launch(void* const* d_in, const int* in_sizes, int n_in,
                              void* d_out, int out_size, void* d_ws, size_t ws_size,
                              hipStream_t stream) {
    const float* embeddings = (const float*)d_in[0];
    const float* node_emb   = (const float*)d_in[1];
    const float* adapt_w    = (const float*)d_in[2];
    const float* adapt_b    = (const float*)d_in[3];
    const float* kw   = (const float*)d_in[4];
    const float* kb   = (const float*)d_in[5];
    const float* qw   = (const float*)d_in[6];
    const float* qb   = (const float*)d_in[7];
    const float* vw   = (const float*)d_in[8];
    const float* vb   = (const float*)d_in[9];
    const float* aw   = (const float*)d_in[10];
    const float* ab   = (const float*)d_in[11];
    const float* pri  = (const float*)d_in[12];
    const float* att_r = (const float*)d_in[13];
    const float* msg_r = (const float*)d_in[14];
    const float* skip  = (const float*)d_in[15];
    const float* ln_g  = (const float*)d_in[16];
    const float* ln_b  = (const float*)d_in[17];
    const float* out_w = (const float*)d_in[18];
    const float* out_b = (const float*)d_in[19];
    const float* attn_k = (const float*)d_in[20];
    const int* src = (const int*)d_in[21];
    const int* dst = (const int*)d_in[22];

    const int E  = in_sizes[21];
    const int NB = in_sizes[0] / D;   // 8192
    const int NN = in_sizes[1] / D;   // 20000
    const int NC = out_size / NB;     // 10000

    size_t big = (size_t)NN * D;
    float* hbuf = (float*)d_ws;                  // fp32 h (residual/LN)
    float* fb32 = hbuf + big;                    // trans out; also tbuf scores
    short* hb16 = (short*)(fb32 + big);          // bf16 h (GEMM A operand)
    short* kb16 = hb16 + big;
    short* qb16 = kb16 + big;
    short* vb16 = qb16 + big;
    short* gg16 = vb16 + big;                    // node_emb bf16 pre-loop; gelu(agg) in loop
    short* w16a = gg16 + big;                    // adapt_w bf16
    short* w16q = w16a + (size_t)D * D;          // qw[l]
    short* w16w = w16q + (size_t)D * D;          // aw[l]
    short* w16o = w16w + (size_t)D * D;          // out_w
    short* fwk16 = w16o + (size_t)D * D;         // fused kw
    short* fwv16 = fwk16 + (size_t)D * D;        // fused vw
    float* fbk = (float*)(fwv16 + (size_t)D * D);
    float* fbv = fbk + D;
    float* tbuf = fb32;                          // scores alias (E*8 <= big)
    int* offs   = (int*)(fbv + D);               // NN+1
    int* cursor = offs + NN + 1;                 // NN
    int* eidx   = cursor + NN;                   // E
    short* cls16 = kb16;                         // reuse after layers
    short* embs16 = qb16;

    auto ggrid = [](int M, int N) { return dim3((N + 127) / 128, (M + 127) / 128); };
    const int WB = D * D / 8;

    // ---- CSR by dst (src/dst are layer-invariant) ----
    zero_int<<<(NN + 255) / 256, 256, 0, stream>>>(cursor, NN);
    hist_dst<<<(E + 255) / 256, 256, 0, stream>>>(dst, cursor, E);
    scan_counts<<<1, 1024, 0, stream>>>(cursor, offs, cursor, NN, E);
    scatter_edges<<<(E + 255) / 256, 256, 0, stream>>>(dst, cursor, eidx, E);

    // ---- one-shot bf16 conversions ----
    cvt_b16<<<((int)(big / 8) + 255) / 256, 256, 0, stream>>>(node_emb, gg16, (int)(big / 8));
    cvt_b16<<<(WB + 255) / 256, 256, 0, stream>>>(adapt_w, w16a, WB);
    cvt_b16<<<(WB + 255) / 256, 256, 0, stream>>>(out_w, w16o, WB);

    // h = gelu(node_emb @ adapt_w^T + adapt_b)  -> fp32 + bf16
    gemm_bf<1, 2><<<ggrid(NN, D), 256, 0, stream>>>(gg16, w16a, adapt_b, hbuf, hb16, NN, D, D);

    for (int l = 0; l < NLAYER; ++l) {
        const size_t wo = (size_t)l * D * D;
        cvt_b16<<<(WB + 255) / 256, 256, 0, stream>>>(qw + wo, w16q, WB);
        cvt_b16<<<(WB + 255) / 256, 256, 0, stream>>>(aw + wo, w16w, WB);
        fuse_w<<<dim3(8, 8), 256, 0, stream>>>(kw + wo, kb + l * D, att_r + (size_t)l * H * 64 * 64, fwk16, fbk);
        fuse_w<<<dim3(8, 8), 256, 0, stream>>>(vw + wo, vb + l * D, msg_r + (size_t)l * H * 64 * 64, fwv16, fbv);

        gemm_bf<0, 1><<<ggrid(NN, D), 256, 0, stream>>>(hb16, fwk16, fbk, nullptr, kb16, NN, D, D);
        gemm_bf<0, 1><<<ggrid(NN, D), 256, 0, stream>>>(hb16, w16q, qb + l * D, nullptr, qb16, NN, D, D);
        gemm_bf<0, 1><<<ggrid(NN, D), 256, 0, stream>>>(hb16, fwv16, fbv, nullptr, vb16, NN, D, D);

        edge_qk<<<(E + 3) / 4, 256, 0, stream>>>(kb16, qb16, src, dst, pri + l * H, tbuf, E);
        node_attn_agg<<<NN, 256, 0, stream>>>(vb16, src, tbuf, offs, eidx, gg16);

        // trans = gelu(agg) @ aw^T + ab  (gelu pre-applied in gg16) -> fp32
        gemm_bf<0, 0><<<ggrid(NN, D), 256, 0, stream>>>(gg16, w16w, ab + l * D, fb32, nullptr, NN, D, D);
        blend_ln<<<NN, 128, 0, stream>>>(fb32, hbuf, skip + l, ln_g + l * D, ln_b + l * D, hbuf, hb16);
    }

    // cls_emb = h[:NC] @ out_w^T + out_b  -> bf16
    gemm_bf<0, 1><<<ggrid(NC, D), 256, 0, stream>>>(hb16, w16o, out_b, nullptr, cls16, NC, D, D);
    // embs = bf16(embeddings * attn_kernels)
    scale_emb_b16<<<((NB * D / 8) + 255) / 256, 256, 0, stream>>>(embeddings, attn_k, embs16, NB * D / 8);
    // logits = embs @ cls_emb^T  -> fp32 d_out
    gemm_bf<0, 0><<<ggrid(NB, NC), 256, 0, stream>>>(embs16, cls16, nullptr, (float*)d_out, nullptr, NB, NC, D);
}

// Round 5
// 963.069 us; speedup vs baseline: 12.4572x; 1.1983x over previous
//
#include <hip/hip_runtime.h>
#include <hip/hip_bf16.h>

#define D 512
#define H 8
#define NLAYER 2

typedef __attribute__((ext_vector_type(8))) short short8;
typedef __attribute__((ext_vector_type(4))) short short4v;
typedef __attribute__((ext_vector_type(4))) float f32x4;

__device__ __forceinline__ float gelu_f(float x) {
    float x3 = x * x * x;
    return 0.5f * x * (1.0f + tanhf(0.7978845608028654f * (x + 0.044715f * x3)));
}

// fp32 -> bf16 bits, round-to-nearest-even
__device__ __forceinline__ unsigned short f2b(float x) {
    unsigned u = __float_as_uint(x);
    u += 0x7FFF + ((u >> 16) & 1);
    return (unsigned short)(u >> 16);
}
__device__ __forceinline__ float b2f(unsigned short u) {
    return __uint_as_float(((unsigned)u) << 16);
}

// ---------------------------------------------------------------------------
// C[M,N] = postact( A[M,K] @ B[N,K]^T + bias ), A/B bf16-resident, fp32 accum.
// 128x128 tile, BK=32, 256 threads = 4 waves (2x2 of 64x64), 4x4 16x16x32.
// OUTMODE: 0 = f32 out, 1 = bf16 out, 2 = both.
// Tile order: bijective XCD split (m204) + 8-row chunks iterated bn-major
// within each XCD so 8 A-panels (1 MB) stay L2-resident and each B panel is
// fetched once per XCD (fixes 640 MB B re-stream seen in round 4).
// ---------------------------------------------------------------------------
template <int POSTG, int OUTMODE>
__global__ __launch_bounds__(256) void gemm_bf(
    const short* __restrict__ A, const short* __restrict__ B,
    const float* __restrict__ bias, float* __restrict__ Cf,
    short* __restrict__ Cb, int M, int N, int K) {
    __shared__ __align__(16) short As[128 * 40];
    __shared__ __align__(16) short Bs[128 * 40];
    const unsigned gx = gridDim.x, gy = gridDim.y;
    const unsigned nwg = gx * gy;
    const unsigned orig = blockIdx.y * gx + blockIdx.x;
    // XCD-contiguous bijective remap
    const unsigned q = nwg >> 3, r = nwg & 7;
    const unsigned xcd = orig & 7, sidx = orig >> 3;
    const unsigned swz = (xcd < r ? xcd * (q + 1) : r * (q + 1) + (xcd - r) * q) + sidx;
    // 8-row chunks, bn-major within chunk (bijective incl. ragged last chunk)
    const unsigned CH = 8;
    const unsigned chunk = swz / (CH * gx);
    const unsigned rem = swz - chunk * (CH * gx);
    const unsigned nr = min(CH, gy - chunk * CH);
    const unsigned col = rem / nr;
    const unsigned rowin = rem - col * nr;
    const int bm = (int)(chunk * CH + rowin) * 128;
    const int bn = (int)col * 128;

    const int tid = threadIdx.x;
    const int lane = tid & 63;
    const int wave = tid >> 6;
    const int wm = (wave >> 1) * 64, wn = (wave & 1) * 64;
    const int lr16 = lane & 15;
    const int lk8 = (lane >> 4) * 8;

    // staging: thread t -> row t>>1, k-chunk (t&1)*16 (16 bf16 = 32 B)
    const int srow = tid >> 1;
    const int skb = (tid & 1) * 16;
    const int arow = min(bm + srow, M - 1);  // clamp: garbage rows discarded at write
    const int brow = min(bn + srow, N - 1);
    const short* Ap = A + (size_t)arow * K + skb;
    const short* Bp = B + (size_t)brow * K + skb;

    f32x4 acc[4][4];
#pragma unroll
    for (int i = 0; i < 4; ++i)
#pragma unroll
        for (int j = 0; j < 4; ++j) acc[i][j] = (f32x4){0.f, 0.f, 0.f, 0.f};

    short8 ra0, ra1, rb0, rb1;
    auto load_ab = [&](int k0) {
        ra0 = *(const short8*)(Ap + k0);
        ra1 = *(const short8*)(Ap + k0 + 8);
        rb0 = *(const short8*)(Bp + k0);
        rb1 = *(const short8*)(Bp + k0 + 8);
    };

    load_ab(0);
    for (int k0 = 0; k0 < K; k0 += 32) {
        __syncthreads();
        *(short8*)&As[srow * 40 + skb]     = ra0;
        *(short8*)&As[srow * 40 + skb + 8] = ra1;
        *(short8*)&Bs[srow * 40 + skb]     = rb0;
        *(short8*)&Bs[srow * 40 + skb + 8] = rb1;
        __syncthreads();
        if (k0 + 32 < K) load_ab(k0 + 32);  // prefetch next tile under MFMA

        short8 af[4], bfr[4];
#pragma unroll
        for (int mi = 0; mi < 4; ++mi)
            af[mi] = *(const short8*)&As[(wm + mi * 16 + lr16) * 40 + lk8];
#pragma unroll
        for (int ni = 0; ni < 4; ++ni)
            bfr[ni] = *(const short8*)&Bs[(wn + ni * 16 + lr16) * 40 + lk8];
#pragma unroll
        for (int mi = 0; mi < 4; ++mi)
#pragma unroll
            for (int ni = 0; ni < 4; ++ni)
                acc[mi][ni] = __builtin_amdgcn_mfma_f32_16x16x32_bf16(
                    af[mi], bfr[ni], acc[mi][ni], 0, 0, 0);
    }

    // epilogue: C/D layout col=lane&15, row=(lane>>4)*4+reg  [m89 verified]
#pragma unroll
    for (int mi = 0; mi < 4; ++mi) {
        int row0 = bm + wm + mi * 16 + (lane >> 4) * 4;
#pragma unroll
        for (int ni = 0; ni < 4; ++ni) {
            int col2 = bn + wn + ni * 16 + lr16;
            if (col2 < N) {
                float bsv = bias ? bias[col2] : 0.0f;
#pragma unroll
                for (int rr2 = 0; rr2 < 4; ++rr2) {
                    int row = row0 + rr2;
                    if (row < M) {
                        float v = acc[mi][ni][rr2] + bsv;
                        if (POSTG) v = gelu_f(v);
                        if (OUTMODE != 1) Cf[(size_t)row * N + col2] = v;
                        if (OUTMODE != 0) Cb[(size_t)row * N + col2] = (short)f2b(v);
                    }
                }
            }
        }
    }
}

// fp32 -> bf16 bulk convert, 8 elems/thread
__global__ void cvt_b16(const float* __restrict__ in, short* __restrict__ out, int n8) {
    int i = blockIdx.x * 256 + threadIdx.x;
    if (i >= n8) return;
    float4 a = ((const float4*)in)[i * 2];
    float4 b = ((const float4*)in)[i * 2 + 1];
    short8 o;
    o[0] = f2b(a.x); o[1] = f2b(a.y); o[2] = f2b(a.z); o[3] = f2b(a.w);
    o[4] = f2b(b.x); o[5] = f2b(b.y); o[6] = f2b(b.z); o[7] = f2b(b.w);
    *(short8*)(out + (size_t)i * 8) = o;
}

// ---------------------------------------------------------------------------
// fold att_r/msg_r into the K/V projection weight; write bf16 weight.
// ---------------------------------------------------------------------------
__global__ __launch_bounds__(256) void fuse_w(
    const float* __restrict__ w, const float* __restrict__ bsrc,
    const float* __restrict__ r, short* __restrict__ fw, float* __restrict__ fb) {
    int h = blockIdx.y;
    int dc = blockIdx.x * 64;
    __shared__ float rs[64][64];
    int tid = threadIdx.x;
    for (int i = tid; i < 4096; i += 256) rs[i >> 6][i & 63] = r[h * 4096 + i];
    __syncthreads();
    for (int rep = 0; rep < 16; ++rep) {
        int o = rep * 256 + tid;
        int j = o >> 6;
        int dd = o & 63;
        float s = 0.0f;
#pragma unroll 8
        for (int i = 0; i < 64; ++i)
            s = fmaf(rs[i][j], w[(size_t)(h * 64 + i) * D + dc + dd], s);
        fw[(size_t)(h * 64 + j) * D + dc + dd] = (short)f2b(s);
    }
    if (blockIdx.x == 0 && tid < 64) {
        float s = 0.0f;
        for (int i = 0; i < 64; ++i) s += bsrc[h * 64 + i] * rs[i][tid];
        fb[h * 64 + tid] = s;
    }
}

// ---------------------------------------------------------------------------
// CSR build by dst:  hist -> scan -> scatter (emits CSR-ordered src/dst lists)
// ---------------------------------------------------------------------------
__global__ void zero_int(int* __restrict__ p, int n) {
    int i = blockIdx.x * 256 + threadIdx.x;
    if (i < n) p[i] = 0;
}

__global__ void hist_dst(const int* __restrict__ dst, int* __restrict__ cnt, int E) {
    int i = blockIdx.x * 256 + threadIdx.x;
    if (i < E) atomicAdd(&cnt[dst[i]], 1);
}

__global__ __launch_bounds__(1024) void scan_counts(
    const int* __restrict__ cnt, int* __restrict__ offs, int* __restrict__ cursor,
    int n, int E) {
    __shared__ int part[1024];
    int t = threadIdx.x;
    int chunk = (n + 1023) >> 10;
    int lo = t * chunk;
    int hi = min(lo + chunk, n);
    int s = 0;
    for (int i = lo; i < hi; ++i) s += cnt[i];
    part[t] = s;
    __syncthreads();
    for (int off = 1; off < 1024; off <<= 1) {
        int v = (t >= off) ? part[t - off] : 0;
        __syncthreads();
        part[t] += v;
        __syncthreads();
    }
    int base = (t == 0) ? 0 : part[t - 1];
    for (int i = lo; i < hi; ++i) {
        offs[i] = base;
        cursor[i] = base;
        base += cnt[i];
    }
    if (t == 1023) offs[n] = E;
}

__global__ void scatter_edges(const int* __restrict__ src, const int* __restrict__ dst,
                              int* __restrict__ cursor, int* __restrict__ srcs,
                              int* __restrict__ dsts, int E) {
    int i = blockIdx.x * 256 + threadIdx.x;
    if (i < E) {
        int d = dst[i];
        int pos = atomicAdd(&cursor[d], 1);
        srcs[pos] = src[i];
        dsts[pos] = d;
    }
}

// ---------------------------------------------------------------------------
// t[pos][h] = dot(k[srcs[pos]], q[dsts[pos]]) * pri[h]/8, CSR slot order.
// One wave per slot; consecutive slots share dst -> q row L1 reuse; t write
// contiguous.
// ---------------------------------------------------------------------------
__global__ __launch_bounds__(256) void edge_qk(
    const short* __restrict__ kbuf, const short* __restrict__ qbuf,
    const int* __restrict__ srcs, const int* __restrict__ dsts,
    const float* __restrict__ pri, float* __restrict__ t, int E) {
    int e = blockIdx.x * 4 + (threadIdx.x >> 6);
    if (e >= E) return;
    int lane = threadIdx.x & 63;
    int s = srcs[e], d = dsts[e];
    short8 kv = *(const short8*)(kbuf + (size_t)s * D + lane * 8);
    short8 qv = *(const short8*)(qbuf + (size_t)d * D + lane * 8);
    float sum = 0.0f;
#pragma unroll
    for (int j = 0; j < 8; ++j)
        sum = fmaf(b2f((unsigned short)kv[j]), b2f((unsigned short)qv[j]), sum);
    sum += __shfl_xor(sum, 1);
    sum += __shfl_xor(sum, 2);
    sum += __shfl_xor(sum, 4);
    int h = lane >> 3;
    if ((lane & 7) == 0) t[(size_t)e * 8 + h] = sum * pri[h] * 0.125f;
}

// ---------------------------------------------------------------------------
// Per-dst-node softmax + aggregation. CSR-contiguous t/srcs reads.
// Phases 1-2: coalesced max/denom. Phase 3: 4 edge-groups x 64 lanes,
// 8 f32 partials/lane, LDS cross-group reduce. Writes bf16 gelu(agg).
// ---------------------------------------------------------------------------
__global__ __launch_bounds__(256) void node_attn_agg(
    const short* __restrict__ vbuf, const int* __restrict__ srcs,
    const float* __restrict__ t, const int* __restrict__ offs,
    short* __restrict__ gg) {
    int n = blockIdx.x;
    int tid = threadIdx.x;
    int start = offs[n], end = offs[n + 1];
    __shared__ float red[32][8];
    __shared__ float smx[8], sinv[8];
    __shared__ float part[4][512];
    int h = tid & 7, sub = tid >> 3;

    // phase 1: per-head max, coalesced over t[start*8 .. end*8)
    float m = -INFINITY;
    for (int idx = start * 8 + tid; idx < end * 8; idx += 256)
        m = fmaxf(m, t[idx]);
    red[sub][h] = m;
    __syncthreads();
    if (tid < 8) {
        float mm = -INFINITY;
#pragma unroll
        for (int s2 = 0; s2 < 32; ++s2) mm = fmaxf(mm, red[s2][tid]);
        smx[tid] = mm;
    }
    __syncthreads();
    // phase 2: per-head denom
    float mh = smx[h];
    float s = 0.0f;
    for (int idx = start * 8 + tid; idx < end * 8; idx += 256)
        s += expf(t[idx] - mh);
    red[sub][h] = s;
    __syncthreads();
    if (tid < 8) {
        float ss = 0.0f;
#pragma unroll
        for (int s2 = 0; s2 < 32; ++s2) ss += red[s2][tid];
        sinv[tid] = 1.0f / fmaxf(ss, 1e-9f);
    }
    __syncthreads();

    // phase 3: agg, 4 groups over edge subsets
    int g = tid >> 6, lane = tid & 63;
    int hh = lane >> 3;  // head for elems lane*8 .. lane*8+7
    float mxh = smx[hh], invh = sinv[hh];
    float vacc[8];
#pragma unroll
    for (int j = 0; j < 8; ++j) vacc[j] = 0.0f;
    for (int i = start + g; i < end; i += 4) {
        int sn = srcs[i];
        float a = expf(t[(size_t)i * 8 + hh] - mxh) * invh;
        short8 v = *(const short8*)(vbuf + (size_t)sn * D + lane * 8);
#pragma unroll
        for (int j = 0; j < 8; ++j) vacc[j] = fmaf(b2f((unsigned short)v[j]), a, vacc[j]);
    }
#pragma unroll
    for (int j = 0; j < 8; ++j) part[g][lane * 8 + j] = vacc[j];
    __syncthreads();
    int c0 = tid * 2;
    float s0 = part[0][c0] + part[1][c0] + part[2][c0] + part[3][c0];
    float s1 = part[0][c0 + 1] + part[1][c0 + 1] + part[2][c0 + 1] + part[3][c0 + 1];
    unsigned pack = (unsigned)(unsigned short)f2b(gelu_f(s0)) |
                    ((unsigned)(unsigned short)f2b(gelu_f(s1)) << 16);
    ((unsigned*)(gg + (size_t)n * D))[tid] = pack;
}

// out = trans*alpha + h*(1-alpha); layernorm; write fp32 h + bf16 h.
__global__ __launch_bounds__(128) void blend_ln(
    const float* __restrict__ trans, const float* __restrict__ hin,
    const float* __restrict__ skip, const float* __restrict__ g,
    const float* __restrict__ b, float* __restrict__ hout,
    short* __restrict__ hb16) {
    int n = blockIdx.x;
    int tid = threadIdx.x;  // 0..127
    float alpha = 1.0f / (1.0f + expf(-skip[0]));
    size_t base = (size_t)n * D + tid * 4;
    float4 t4 = *(const float4*)(trans + base);
    float4 h4 = *(const float4*)(hin + base);
    float o[4];
    o[0] = t4.x * alpha + h4.x * (1.0f - alpha);
    o[1] = t4.y * alpha + h4.y * (1.0f - alpha);
    o[2] = t4.z * alpha + h4.z * (1.0f - alpha);
    o[3] = t4.w * alpha + h4.w * (1.0f - alpha);
    float s = o[0] + o[1] + o[2] + o[3];
    float ss = o[0] * o[0] + o[1] * o[1] + o[2] * o[2] + o[3] * o[3];
    for (int off = 32; off; off >>= 1) {
        s += __shfl_down(s, off);
        ss += __shfl_down(ss, off);
    }
    __shared__ float red[4];
    if ((tid & 63) == 0) { red[tid >> 6] = s; red[2 + (tid >> 6)] = ss; }
    __syncthreads();
    float S = red[0] + red[1];
    float SS = red[2] + red[3];
    float mu = S * (1.0f / 512.0f);
    float var = SS * (1.0f / 512.0f) - mu * mu;
    float inv = rsqrtf(var + 1e-5f);
    int c = tid * 4;
    float4 o4;
    o4.x = (o[0] - mu) * inv * g[c + 0] + b[c + 0];
    o4.y = (o[1] - mu) * inv * g[c + 1] + b[c + 1];
    o4.z = (o[2] - mu) * inv * g[c + 2] + b[c + 2];
    o4.w = (o[3] - mu) * inv * g[c + 3] + b[c + 3];
    *(float4*)(hout + base) = o4;
    short4v hb;
    hb[0] = f2b(o4.x); hb[1] = f2b(o4.y); hb[2] = f2b(o4.z); hb[3] = f2b(o4.w);
    *(short4v*)(hb16 + base) = hb;
}

// embs16 = bf16(embeddings * attn_kernels), 8 elems/thread
__global__ void scale_emb_b16(const float* __restrict__ e, const float* __restrict__ ak,
                              short* __restrict__ o, int n8) {
    int i = blockIdx.x * 256 + threadIdx.x;
    if (i >= n8) return;
    float4 a = ((const float4*)e)[i * 2];
    float4 b = ((const float4*)e)[i * 2 + 1];
    int d0 = (i * 8) & (D - 1);
    short8 v;
    v[0] = f2b(a.x * ak[d0 + 0]); v[1] = f2b(a.y * ak[d0 + 1]);
    v[2] = f2b(a.z * ak[d0 + 2]); v[3] = f2b(a.w * ak[d0 + 3]);
    v[4] = f2b(b.x * ak[d0 + 4]); v[5] = f2b(b.y * ak[d0 + 5]);
    v[6] = f2b(b.z * ak[d0 + 6]); v[7] = f2b(b.w * ak[d0 + 7]);
    *(short8*)(o + (size_t)i * 8) = v;
}

extern "C" void kernel_launch(void* const* d_in, const int* in_sizes, int n_in,
                              void* d_out, int out_size, void* d_ws, size_t ws_size,
                              hipStream_t stream) {
    const float* embeddings = (const float*)d_in[0];
    const float* node_emb   = (const float*)d_in[1];
    const float* adapt_w    = (const float*)d_in[2];
    const float* adapt_b    = (const float*)d_in[3];
    const float* kw   = (const float*)d_in[4];
    const float* kb   = (const float*)d_in[5];
    const float* qw   = (const float*)d_in[6];
    const float* qb   = (const float*)d_in[7];
    const float* vw   = (const float*)d_in[8];
    const float* vb   = (const float*)d_in[9];
    const float* aw   = (const float*)d_in[10];
    const float* ab   = (const float*)d_in[11];
    const float* pri  = (const float*)d_in[12];
    const float* att_r = (const float*)d_in[13];
    const float* msg_r = (const float*)d_in[14];
    const float* skip  = (const float*)d_in[15];
    const float* ln_g  = (const float*)d_in[16];
    const float* ln_b  = (const float*)d_in[17];
    const float* out_w = (const float*)d_in[18];
    const float* out_b = (const float*)d_in[19];
    const float* attn_k = (const float*)d_in[20];
    const int* src = (const int*)d_in[21];
    const int* dst = (const int*)d_in[22];

    const int E  = in_sizes[21];
    const int NB = in_sizes[0] / D;   // 8192
    const int NN = in_sizes[1] / D;   // 20000
    const int NC = out_size / NB;     // 10000

    size_t big = (size_t)NN * D;
    float* hbuf = (float*)d_ws;                  // fp32 h (residual/LN)
    float* fb32 = hbuf + big;                    // trans out; aliased as scores t
    short* hb16 = (short*)(fb32 + big);          // bf16 h (GEMM A operand)
    short* kb16 = hb16 + big;
    short* qb16 = kb16 + big;
    short* vb16 = qb16 + big;
    short* gg16 = vb16 + big;                    // node_emb bf16 pre-loop; gelu(agg) in loop
    short* w16a = gg16 + big;                    // adapt_w bf16
    short* w16q = w16a + (size_t)D * D;          // qw[l]
    short* w16w = w16q + (size_t)D * D;          // aw[l]
    short* w16o = w16w + (size_t)D * D;          // out_w
    short* fwk16 = w16o + (size_t)D * D;         // fused kw
    short* fwv16 = fwk16 + (size_t)D * D;        // fused vw
    float* fbk = (float*)(fwv16 + (size_t)D * D);
    float* fbv = fbk + D;
    float* tbuf = fb32;                          // scores alias (E*8 <= big*2)
    int* offs   = (int*)(fbv + D);               // NN+1
    int* cursor = offs + NN + 1;                 // NN
    int* srcs   = cursor + NN;                   // E (CSR order)
    int* dsts   = srcs + E;                      // E (CSR order)
    short* cls16 = kb16;                         // reuse after layers
    short* embs16 = qb16;

    auto ggrid = [](int M, int N) { return dim3((N + 127) / 128, (M + 127) / 128); };
    const int WB = D * D / 8;

    // ---- CSR by dst (src/dst are layer-invariant) ----
    zero_int<<<(NN + 255) / 256, 256, 0, stream>>>(cursor, NN);
    hist_dst<<<(E + 255) / 256, 256, 0, stream>>>(dst, cursor, E);
    scan_counts<<<1, 1024, 0, stream>>>(cursor, offs, cursor, NN, E);
    scatter_edges<<<(E + 255) / 256, 256, 0, stream>>>(src, dst, cursor, srcs, dsts, E);

    // ---- one-shot bf16 conversions ----
    cvt_b16<<<((int)(big / 8) + 255) / 256, 256, 0, stream>>>(node_emb, gg16, (int)(big / 8));
    cvt_b16<<<(WB + 255) / 256, 256, 0, stream>>>(adapt_w, w16a, WB);
    cvt_b16<<<(WB + 255) / 256, 256, 0, stream>>>(out_w, w16o, WB);

    // h = gelu(node_emb @ adapt_w^T + adapt_b)  -> fp32 + bf16
    gemm_bf<1, 2><<<ggrid(NN, D), 256, 0, stream>>>(gg16, w16a, adapt_b, hbuf, hb16, NN, D, D);

    for (int l = 0; l < NLAYER; ++l) {
        const size_t wo = (size_t)l * D * D;
        cvt_b16<<<(WB + 255) / 256, 256, 0, stream>>>(qw + wo, w16q, WB);
        cvt_b16<<<(WB + 255) / 256, 256, 0, stream>>>(aw + wo, w16w, WB);
        fuse_w<<<dim3(8, 8), 256, 0, stream>>>(kw + wo, kb + l * D, att_r + (size_t)l * H * 64 * 64, fwk16, fbk);
        fuse_w<<<dim3(8, 8), 256, 0, stream>>>(vw + wo, vb + l * D, msg_r + (size_t)l * H * 64 * 64, fwv16, fbv);

        gemm_bf<0, 1><<<ggrid(NN, D), 256, 0, stream>>>(hb16, fwk16, fbk, nullptr, kb16, NN, D, D);
        gemm_bf<0, 1><<<ggrid(NN, D), 256, 0, stream>>>(hb16, w16q, qb + l * D, nullptr, qb16, NN, D, D);
        gemm_bf<0, 1><<<ggrid(NN, D), 256, 0, stream>>>(hb16, fwv16, fbv, nullptr, vb16, NN, D, D);

        edge_qk<<<(E + 3) / 4, 256, 0, stream>>>(kb16, qb16, srcs, dsts, pri + l * H, tbuf, E);
        node_attn_agg<<<NN, 256, 0, stream>>>(vb16, srcs, tbuf, offs, gg16);

        // trans = gelu(agg) @ aw^T + ab  (gelu pre-applied in gg16) -> fp32
        gemm_bf<0, 0><<<ggrid(NN, D), 256, 0, stream>>>(gg16, w16w, ab + l * D, fb32, nullptr, NN, D, D);
        blend_ln<<<NN, 128, 0, stream>>>(fb32, hbuf, skip + l, ln_g + l * D, ln_b + l * D, hbuf, hb16);
    }

    // cls_emb = h[:NC] @ out_w^T + out_b  -> bf16
    gemm_bf<0, 1><<<ggrid(NC, D), 256, 0, stream>>>(hb16, w16o, out_b, nullptr, cls16, NC, D, D);
    // embs = bf16(embeddings * attn_kernels)
    scale_emb_b16<<<((NB * D / 8) + 255) / 256, 256, 0, stream>>>(embeddings, attn_k, embs16, NB * D / 8);
    // logits = embs @ cls_emb^T  -> fp32 d_out
    gemm_bf<0, 0><<<ggrid(NB, NC), 256, 0, stream>>>(embs16, cls16, nullptr, (float*)d_out, nullptr, NB, NC, D);
}

// Round 6
// 880.861 us; speedup vs baseline: 13.6198x; 1.0933x over previous
//
#include <hip/hip_runtime.h>
#include <hip/hip_bf16.h>

#define D 512
#define H 8
#define NLAYER 2

typedef __attribute__((ext_vector_type(8))) short short8;
typedef __attribute__((ext_vector_type(4))) short short4v;
typedef __attribute__((ext_vector_type(4))) float f32x4;

__device__ __forceinline__ float gelu_f(float x) {
    float x3 = x * x * x;
    return 0.5f * x * (1.0f + tanhf(0.7978845608028654f * (x + 0.044715f * x3)));
}

// fp32 -> bf16 bits, round-to-nearest-even
__device__ __forceinline__ unsigned short f2b(float x) {
    unsigned u = __float_as_uint(x);
    u += 0x7FFF + ((u >> 16) & 1);
    return (unsigned short)(u >> 16);
}
__device__ __forceinline__ float b2f(unsigned short u) {
    return __uint_as_float(((unsigned)u) << 16);
}

// ---------------------------------------------------------------------------
// C[M,N] = postact( A[M,K] @ B[N,K]^T + bias ), A/B bf16-resident, fp32 accum.
// 128x128 tile, BK=32, 256 threads = 4 waves (2x2 of 64x64), 4x4 16x16x32.
// OUTMODE: 0 = f32 out, 1 = bf16 out, 2 = both.
// Tile order: bijective XCD split + 8-row chunks iterated bn-major per XCD.
// ---------------------------------------------------------------------------
template <int POSTG, int OUTMODE>
__global__ __launch_bounds__(256) void gemm_bf(
    const short* __restrict__ A, const short* __restrict__ B,
    const float* __restrict__ bias, float* __restrict__ Cf,
    short* __restrict__ Cb, int M, int N, int K) {
    __shared__ __align__(16) short As[128 * 40];
    __shared__ __align__(16) short Bs[128 * 40];
    const unsigned gx = gridDim.x, gy = gridDim.y;
    const unsigned nwg = gx * gy;
    const unsigned orig = blockIdx.y * gx + blockIdx.x;
    const unsigned q = nwg >> 3, r = nwg & 7;
    const unsigned xcd = orig & 7, sidx = orig >> 3;
    const unsigned swz = (xcd < r ? xcd * (q + 1) : r * (q + 1) + (xcd - r) * q) + sidx;
    const unsigned CH = 8;
    const unsigned chunk = swz / (CH * gx);
    const unsigned rem = swz - chunk * (CH * gx);
    const unsigned nr = min(CH, gy - chunk * CH);
    const unsigned col = rem / nr;
    const unsigned rowin = rem - col * nr;
    const int bm = (int)(chunk * CH + rowin) * 128;
    const int bn = (int)col * 128;

    const int tid = threadIdx.x;
    const int lane = tid & 63;
    const int wave = tid >> 6;
    const int wm = (wave >> 1) * 64, wn = (wave & 1) * 64;
    const int lr16 = lane & 15;
    const int lk8 = (lane >> 4) * 8;

    const int srow = tid >> 1;
    const int skb = (tid & 1) * 16;
    const int arow = min(bm + srow, M - 1);
    const int brow = min(bn + srow, N - 1);
    const short* Ap = A + (size_t)arow * K + skb;
    const short* Bp = B + (size_t)brow * K + skb;

    f32x4 acc[4][4];
#pragma unroll
    for (int i = 0; i < 4; ++i)
#pragma unroll
        for (int j = 0; j < 4; ++j) acc[i][j] = (f32x4){0.f, 0.f, 0.f, 0.f};

    short8 ra0, ra1, rb0, rb1;
    auto load_ab = [&](int k0) {
        ra0 = *(const short8*)(Ap + k0);
        ra1 = *(const short8*)(Ap + k0 + 8);
        rb0 = *(const short8*)(Bp + k0);
        rb1 = *(const short8*)(Bp + k0 + 8);
    };

    load_ab(0);
    for (int k0 = 0; k0 < K; k0 += 32) {
        __syncthreads();
        *(short8*)&As[srow * 40 + skb]     = ra0;
        *(short8*)&As[srow * 40 + skb + 8] = ra1;
        *(short8*)&Bs[srow * 40 + skb]     = rb0;
        *(short8*)&Bs[srow * 40 + skb + 8] = rb1;
        __syncthreads();
        if (k0 + 32 < K) load_ab(k0 + 32);

        short8 af[4], bfr[4];
#pragma unroll
        for (int mi = 0; mi < 4; ++mi)
            af[mi] = *(const short8*)&As[(wm + mi * 16 + lr16) * 40 + lk8];
#pragma unroll
        for (int ni = 0; ni < 4; ++ni)
            bfr[ni] = *(const short8*)&Bs[(wn + ni * 16 + lr16) * 40 + lk8];
#pragma unroll
        for (int mi = 0; mi < 4; ++mi)
#pragma unroll
            for (int ni = 0; ni < 4; ++ni)
                acc[mi][ni] = __builtin_amdgcn_mfma_f32_16x16x32_bf16(
                    af[mi], bfr[ni], acc[mi][ni], 0, 0, 0);
    }

#pragma unroll
    for (int mi = 0; mi < 4; ++mi) {
        int row0 = bm + wm + mi * 16 + (lane >> 4) * 4;
#pragma unroll
        for (int ni = 0; ni < 4; ++ni) {
            int col2 = bn + wn + ni * 16 + lr16;
            if (col2 < N) {
                float bsv = bias ? bias[col2] : 0.0f;
#pragma unroll
                for (int rr2 = 0; rr2 < 4; ++rr2) {
                    int row = row0 + rr2;
                    if (row < M) {
                        float v = acc[mi][ni][rr2] + bsv;
                        if (POSTG) v = gelu_f(v);
                        if (OUTMODE != 1) Cf[(size_t)row * N + col2] = v;
                        if (OUTMODE != 0) Cb[(size_t)row * N + col2] = (short)f2b(v);
                    }
                }
            }
        }
    }
}

// fp32 -> bf16 bulk convert, 8 elems/thread
__global__ void cvt_b16(const float* __restrict__ in, short* __restrict__ out, int n8) {
    int i = blockIdx.x * 256 + threadIdx.x;
    if (i >= n8) return;
    float4 a = ((const float4*)in)[i * 2];
    float4 b = ((const float4*)in)[i * 2 + 1];
    short8 o;
    o[0] = f2b(a.x); o[1] = f2b(a.y); o[2] = f2b(a.z); o[3] = f2b(a.w);
    o[4] = f2b(b.x); o[5] = f2b(b.y); o[6] = f2b(b.z); o[7] = f2b(b.w);
    *(short8*)(out + (size_t)i * 8) = o;
}

__global__ void cp_f32(const float* __restrict__ in, float* __restrict__ out, int n) {
    int i = blockIdx.x * 256 + threadIdx.x;
    if (i < n) out[i] = in[i];
}

// ---------------------------------------------------------------------------
// fold att_r/msg_r into the K/V projection weight; bf16 weight out.
// ---------------------------------------------------------------------------
__global__ __launch_bounds__(256) void fuse_w(
    const float* __restrict__ w, const float* __restrict__ bsrc,
    const float* __restrict__ r, short* __restrict__ fw, float* __restrict__ fb) {
    int h = blockIdx.y;
    int dc = blockIdx.x * 64;
    __shared__ float rs[64][64];
    int tid = threadIdx.x;
    for (int i = tid; i < 4096; i += 256) rs[i >> 6][i & 63] = r[h * 4096 + i];
    __syncthreads();
    for (int rep = 0; rep < 16; ++rep) {
        int o = rep * 256 + tid;
        int j = o >> 6;
        int dd = o & 63;
        float s = 0.0f;
#pragma unroll 8
        for (int i = 0; i < 64; ++i)
            s = fmaf(rs[i][j], w[(size_t)(h * 64 + i) * D + dc + dd], s);
        fw[(size_t)(h * 64 + j) * D + dc + dd] = (short)f2b(s);
    }
    if (blockIdx.x == 0 && tid < 64) {
        float s = 0.0f;
        for (int i = 0; i < 64; ++i) s += bsrc[h * 64 + i] * rs[i][tid];
        fb[h * 64 + tid] = s;
    }
}

// ---------------------------------------------------------------------------
// CSR build by dst:  hist -> scan -> scatter (CSR-ordered src list)
// ---------------------------------------------------------------------------
__global__ void zero_int(int* __restrict__ p, int n) {
    int i = blockIdx.x * 256 + threadIdx.x;
    if (i < n) p[i] = 0;
}

__global__ void hist_dst(const int* __restrict__ dst, int* __restrict__ cnt, int E) {
    int i = blockIdx.x * 256 + threadIdx.x;
    if (i < E) atomicAdd(&cnt[dst[i]], 1);
}

__global__ __launch_bounds__(1024) void scan_counts(
    const int* __restrict__ cnt, int* __restrict__ offs, int* __restrict__ cursor,
    int n, int E) {
    __shared__ int part[1024];
    int t = threadIdx.x;
    int chunk = (n + 1023) >> 10;
    int lo = t * chunk;
    int hi = min(lo + chunk, n);
    int s = 0;
    for (int i = lo; i < hi; ++i) s += cnt[i];
    part[t] = s;
    __syncthreads();
    for (int off = 1; off < 1024; off <<= 1) {
        int v = (t >= off) ? part[t - off] : 0;
        __syncthreads();
        part[t] += v;
        __syncthreads();
    }
    int base = (t == 0) ? 0 : part[t - 1];
    for (int i = lo; i < hi; ++i) {
        offs[i] = base;
        cursor[i] = base;
        base += cnt[i];
    }
    if (t == 1023) offs[n] = E;
}

__global__ void scatter_edges(const int* __restrict__ src, const int* __restrict__ dst,
                              int* __restrict__ cursor, int* __restrict__ srcs, int E) {
    int i = blockIdx.x * 256 + threadIdx.x;
    if (i < E) {
        int pos = atomicAdd(&cursor[dst[i]], 1);
        srcs[pos] = src[i];
    }
}

// ---------------------------------------------------------------------------
// Fused per-node edge attention: QK dots + online softmax + V aggregation.
// One 256-thread block per dst node; edges in chunks of 64 via LDS t-tile.
// kqv row layout: [0,512)=k', [512,1024)=q, [1024,1536)=v'. Writes bf16
// gelu(agg). No global t buffer, q loaded once per node.
// ---------------------------------------------------------------------------
__global__ __launch_bounds__(256) void edge_attn(
    const short* __restrict__ kqv, const int* __restrict__ srcs,
    const int* __restrict__ offs, const float* __restrict__ pri,
    short* __restrict__ gg) {
    int n = blockIdx.x;
    int tid = threadIdx.x;
    int lane = tid & 63, wave = tid >> 6;
    int start = offs[n], end = offs[n + 1];

    __shared__ float t_lds[64][8];
    __shared__ float red[32][8];
    __shared__ float rm[8], rden[8], sc[8];
    __shared__ float part[4][512];

    // q slice into regs (same slice for all 4 waves; L1-served)
    const short8 qv = *(const short8*)(kqv + (size_t)n * 1536 + 512 + lane * 8);
    float qf[8];
#pragma unroll
    for (int j = 0; j < 8; ++j) qf[j] = b2f((unsigned short)qv[j]);
    const float prih = pri[lane >> 3] * 0.125f;

    if (tid < 8) { rm[tid] = -INFINITY; rden[tid] = 0.0f; }

    const int hh = lane >> 3;          // head owning cols lane*8..+7
    const int hr = tid & 7, sb = tid >> 3;  // reduction mapping
    float vacc[8];
#pragma unroll
    for (int j = 0; j < 8; ++j) vacc[j] = 0.0f;

    for (int base = start; base < end; base += 64) {
        int csz = min(64, end - base);
        __syncthreads();  // protect t_lds/red from previous chunk's readers
        // ---- dot phase: wave w handles slots w, w+4, ...
        for (int s = wave; s < csz; s += 4) {
            int sn = srcs[base + s];
            short8 kv = *(const short8*)(kqv + (size_t)sn * 1536 + lane * 8);
            float sum = 0.0f;
#pragma unroll
            for (int j = 0; j < 8; ++j)
                sum = fmaf(b2f((unsigned short)kv[j]), qf[j], sum);
            sum += __shfl_xor(sum, 1);
            sum += __shfl_xor(sum, 2);
            sum += __shfl_xor(sum, 4);
            if ((lane & 7) == 0) t_lds[s][hh] = sum * prih;
        }
        __syncthreads();
        // ---- chunk max per head
        float m = -INFINITY;
        if (sb < csz) m = t_lds[sb][hr];
        if (sb + 32 < csz) m = fmaxf(m, t_lds[sb + 32][hr]);
        red[sb][hr] = m;
        __syncthreads();
        if (tid < 8) {
            float mm = -INFINITY;
#pragma unroll
            for (int s2 = 0; s2 < 32; ++s2) mm = fmaxf(mm, red[s2][tid]);
            float nm = fmaxf(rm[tid], mm);
            sc[tid] = expf(rm[tid] - nm);   // 0 when rm was -inf
            rm[tid] = nm;
        }
        __syncthreads();
        // ---- rescale running acc; chunk exp-sum; den update
        float m2 = rm[hh], scl = sc[hh];
#pragma unroll
        for (int j = 0; j < 8; ++j) vacc[j] *= scl;
        float mr = rm[hr];
        float se = 0.0f;
        if (sb < csz) se = expf(t_lds[sb][hr] - mr);
        if (sb + 32 < csz) se += expf(t_lds[sb + 32][hr] - mr);
        red[sb][hr] = se;
        __syncthreads();
        if (tid < 8) {
            float ssum = 0.0f;
#pragma unroll
            for (int s2 = 0; s2 < 32; ++s2) ssum += red[s2][tid];
            rden[tid] = rden[tid] * sc[tid] + ssum;
        }
        // ---- accumulate: group (=wave) handles slots w, w+4, ...
        for (int s = wave; s < csz; s += 4) {
            int sn = srcs[base + s];
            float a = expf(t_lds[s][hh] - m2);
            short8 v = *(const short8*)(kqv + (size_t)sn * 1536 + 1024 + lane * 8);
#pragma unroll
            for (int j = 0; j < 8; ++j)
                vacc[j] = fmaf(b2f((unsigned short)v[j]), a, vacc[j]);
        }
    }
    // ---- cross-group reduce + normalize + gelu + pack
#pragma unroll
    for (int j = 0; j < 8; ++j) part[wave][lane * 8 + j] = vacc[j];
    __syncthreads();
    int c0 = tid * 2;
    float inv = 1.0f / fmaxf(rden[tid >> 5], 1e-9f);
    float s0 = (part[0][c0] + part[1][c0] + part[2][c0] + part[3][c0]) * inv;
    float s1 = (part[0][c0 + 1] + part[1][c0 + 1] + part[2][c0 + 1] + part[3][c0 + 1]) * inv;
    unsigned pack = (unsigned)(unsigned short)f2b(gelu_f(s0)) |
                    ((unsigned)(unsigned short)f2b(gelu_f(s1)) << 16);
    ((unsigned*)(gg + (size_t)n * D))[tid] = pack;
}

// out = trans*alpha + h*(1-alpha); layernorm; write fp32 h + bf16 h.
__global__ __launch_bounds__(128) void blend_ln(
    const float* __restrict__ trans, const float* __restrict__ hin,
    const float* __restrict__ skip, const float* __restrict__ g,
    const float* __restrict__ b, float* __restrict__ hout,
    short* __restrict__ hb16) {
    int n = blockIdx.x;
    int tid = threadIdx.x;  // 0..127
    float alpha = 1.0f / (1.0f + expf(-skip[0]));
    size_t base = (size_t)n * D + tid * 4;
    float4 t4 = *(const float4*)(trans + base);
    float4 h4 = *(const float4*)(hin + base);
    float o[4];
    o[0] = t4.x * alpha + h4.x * (1.0f - alpha);
    o[1] = t4.y * alpha + h4.y * (1.0f - alpha);
    o[2] = t4.z * alpha + h4.z * (1.0f - alpha);
    o[3] = t4.w * alpha + h4.w * (1.0f - alpha);
    float s = o[0] + o[1] + o[2] + o[3];
    float ss = o[0] * o[0] + o[1] * o[1] + o[2] * o[2] + o[3] * o[3];
    for (int off = 32; off; off >>= 1) {
        s += __shfl_down(s, off);
        ss += __shfl_down(ss, off);
    }
    __shared__ float red[4];
    if ((tid & 63) == 0) { red[tid >> 6] = s; red[2 + (tid >> 6)] = ss; }
    __syncthreads();
    float S = red[0] + red[1];
    float SS = red[2] + red[3];
    float mu = S * (1.0f / 512.0f);
    float var = SS * (1.0f / 512.0f) - mu * mu;
    float inv = rsqrtf(var + 1e-5f);
    int c = tid * 4;
    float4 o4;
    o4.x = (o[0] - mu) * inv * g[c + 0] + b[c + 0];
    o4.y = (o[1] - mu) * inv * g[c + 1] + b[c + 1];
    o4.z = (o[2] - mu) * inv * g[c + 2] + b[c + 2];
    o4.w = (o[3] - mu) * inv * g[c + 3] + b[c + 3];
    *(float4*)(hout + base) = o4;
    short4v hb;
    hb[0] = f2b(o4.x); hb[1] = f2b(o4.y); hb[2] = f2b(o4.z); hb[3] = f2b(o4.w);
    *(short4v*)(hb16 + base) = hb;
}

// embs16 = bf16(embeddings * attn_kernels), 8 elems/thread
__global__ void scale_emb_b16(const float* __restrict__ e, const float* __restrict__ ak,
                              short* __restrict__ o, int n8) {
    int i = blockIdx.x * 256 + threadIdx.x;
    if (i >= n8) return;
    float4 a = ((const float4*)e)[i * 2];
    float4 b = ((const float4*)e)[i * 2 + 1];
    int d0 = (i * 8) & (D - 1);
    short8 v;
    v[0] = f2b(a.x * ak[d0 + 0]); v[1] = f2b(a.y * ak[d0 + 1]);
    v[2] = f2b(a.z * ak[d0 + 2]); v[3] = f2b(a.w * ak[d0 + 3]);
    v[4] = f2b(b.x * ak[d0 + 4]); v[5] = f2b(b.y * ak[d0 + 5]);
    v[6] = f2b(b.z * ak[d0 + 6]); v[7] = f2b(b.w * ak[d0 + 7]);
    *(short8*)(o + (size_t)i * 8) = v;
}

extern "C" void kernel_launch(void* const* d_in, const int* in_sizes, int n_in,
                              void* d_out, int out_size, void* d_ws, size_t ws_size,
                              hipStream_t stream) {
    const float* embeddings = (const float*)d_in[0];
    const float* node_emb   = (const float*)d_in[1];
    const float* adapt_w    = (const float*)d_in[2];
    const float* adapt_b    = (const float*)d_in[3];
    const float* kw   = (const float*)d_in[4];
    const float* kb   = (const float*)d_in[5];
    const float* qw   = (const float*)d_in[6];
    const float* qb   = (const float*)d_in[7];
    const float* vw   = (const float*)d_in[8];
    const float* vb   = (const float*)d_in[9];
    const float* aw   = (const float*)d_in[10];
    const float* ab   = (const float*)d_in[11];
    const float* pri  = (const float*)d_in[12];
    const float* att_r = (const float*)d_in[13];
    const float* msg_r = (const float*)d_in[14];
    const float* skip  = (const float*)d_in[15];
    const float* ln_g  = (const float*)d_in[16];
    const float* ln_b  = (const float*)d_in[17];
    const float* out_w = (const float*)d_in[18];
    const float* out_b = (const float*)d_in[19];
    const float* attn_k = (const float*)d_in[20];
    const int* src = (const int*)d_in[21];
    const int* dst = (const int*)d_in[22];

    const int E  = in_sizes[21];
    const int NB = in_sizes[0] / D;   // 8192
    const int NN = in_sizes[1] / D;   // 20000
    const int NC = out_size / NB;     // 10000

    size_t big = (size_t)NN * D;
    float* hbuf = (float*)d_ws;                  // fp32 h (residual/LN)
    float* fb32 = hbuf + big;                    // trans out
    short* hb16 = (short*)(fb32 + big);          // bf16 h (GEMM A operand)
    short* gg16 = hb16 + big;                    // node_emb bf16 / gelu(agg)
    short* kqv16 = gg16 + big;                   // [NN][1536] k'|q|v'
    short* w16a = kqv16 + (size_t)NN * 1536;     // adapt_w
    short* w16o = w16a + (size_t)D * D;          // out_w
    short* w16w = w16o + (size_t)D * D;          // aw[l]
    short* wcat = w16w + (size_t)D * D;          // [1536][512] k'|q|v' weights
    float* bcat = (float*)(wcat + (size_t)1536 * D);  // [1536]
    int* offs   = (int*)(bcat + 1536);           // NN+1
    int* cursor = offs + NN + 1;                 // NN
    int* srcs   = cursor + NN;                   // E (CSR order)
    short* cls16 = kqv16;                        // reuse after layers
    short* embs16 = kqv16 + (size_t)NC * D;

    auto ggrid = [](int M, int N) { return dim3((N + 127) / 128, (M + 127) / 128); };
    const int WB = D * D / 8;

    // ---- CSR by dst (src/dst are layer-invariant) ----
    zero_int<<<(NN + 255) / 256, 256, 0, stream>>>(cursor, NN);
    hist_dst<<<(E + 255) / 256, 256, 0, stream>>>(dst, cursor, E);
    scan_counts<<<1, 1024, 0, stream>>>(cursor, offs, cursor, NN, E);
    scatter_edges<<<(E + 255) / 256, 256, 0, stream>>>(src, dst, cursor, srcs, E);

    // ---- one-shot bf16 conversions ----
    cvt_b16<<<((int)(big / 8) + 255) / 256, 256, 0, stream>>>(node_emb, gg16, (int)(big / 8));
    cvt_b16<<<(WB + 255) / 256, 256, 0, stream>>>(adapt_w, w16a, WB);
    cvt_b16<<<(WB + 255) / 256, 256, 0, stream>>>(out_w, w16o, WB);

    // h = gelu(node_emb @ adapt_w^T + adapt_b)  -> fp32 + bf16
    gemm_bf<1, 2><<<ggrid(NN, D), 256, 0, stream>>>(gg16, w16a, adapt_b, hbuf, hb16, NN, D, D);

    for (int l = 0; l < NLAYER; ++l) {
        const size_t wo = (size_t)l * D * D;
        // wcat rows: [0,512) fused-K, [512,1024) Q, [1024,1536) fused-V
        fuse_w<<<dim3(8, 8), 256, 0, stream>>>(kw + wo, kb + l * D, att_r + (size_t)l * H * 64 * 64, wcat, bcat);
        cvt_b16<<<(WB + 255) / 256, 256, 0, stream>>>(qw + wo, wcat + (size_t)512 * D, WB);
        cp_f32<<<2, 256, 0, stream>>>(qb + l * D, bcat + 512, D);
        fuse_w<<<dim3(8, 8), 256, 0, stream>>>(vw + wo, vb + l * D, msg_r + (size_t)l * H * 64 * 64, wcat + (size_t)1024 * D, bcat + 1024);

        // kqv = h @ wcat^T + bcat   (one GEMM, N=1536)
        gemm_bf<0, 1><<<ggrid(NN, 1536), 256, 0, stream>>>(hb16, wcat, bcat, nullptr, kqv16, NN, 1536, D);

        // fused edge attention -> gelu(agg) bf16
        edge_attn<<<NN, 256, 0, stream>>>(kqv16, srcs, offs, pri + l * H, gg16);

        // trans = gelu(agg) @ aw^T + ab -> fp32
        cvt_b16<<<(WB + 255) / 256, 256, 0, stream>>>(aw + wo, w16w, WB);
        gemm_bf<0, 0><<<ggrid(NN, D), 256, 0, stream>>>(gg16, w16w, ab + l * D, fb32, nullptr, NN, D, D);
        blend_ln<<<NN, 128, 0, stream>>>(fb32, hbuf, skip + l, ln_g + l * D, ln_b + l * D, hbuf, hb16);
    }

    // cls_emb = h[:NC] @ out_w^T + out_b  -> bf16
    gemm_bf<0, 1><<<ggrid(NC, D), 256, 0, stream>>>(hb16, w16o, out_b, nullptr, cls16, NC, D, D);
    // embs = bf16(embeddings * attn_kernels)
    scale_emb_b16<<<((NB * D / 8) + 255) / 256, 256, 0, stream>>>(embeddings, attn_k, embs16, NB * D / 8);
    // logits = embs @ cls_emb^T  -> fp32 d_out
    gemm_bf<0, 0><<<ggrid(NB, NC), 256, 0, stream>>>(embs16, cls16, nullptr, (float*)d_out, nullptr, NB, NC, D);
}

// Round 7
// 875.060 us; speedup vs baseline: 13.7100x; 1.0066x over previous
//
#include <hip/hip_runtime.h>
#include <hip/hip_bf16.h>

#define D 512
#define H 8
#define NLAYER 2

typedef __attribute__((ext_vector_type(8))) short short8;
typedef __attribute__((ext_vector_type(4))) short short4v;
typedef __attribute__((ext_vector_type(4))) float f32x4;

__device__ __forceinline__ float gelu_f(float x) {
    float x3 = x * x * x;
    return 0.5f * x * (1.0f + tanhf(0.7978845608028654f * (x + 0.044715f * x3)));
}

// fp32 -> bf16 bits, round-to-nearest-even
__device__ __forceinline__ unsigned short f2b(float x) {
    unsigned u = __float_as_uint(x);
    u += 0x7FFF + ((u >> 16) & 1);
    return (unsigned short)(u >> 16);
}
__device__ __forceinline__ float b2f(unsigned short u) {
    return __uint_as_float(((unsigned)u) << 16);
}

// ---------------------------------------------------------------------------
// C[M,N] = postact( A[M,K] @ B[N,K]^T + bias ), A/B bf16-resident, fp32 accum.
// 128x128 tile, BK=64 (8 stage/barrier rounds at K=512, 32 MFMA per round),
// 256 threads = 4 waves (2x2 of 64x64), 4x4 16x16x32 frags.
// OUTMODE: 0 = f32 out, 1 = bf16 out, 2 = both.
// Tile order: bijective XCD split + 8-row chunks iterated bn-major per XCD.
// LDS row stride 72 shorts (144 B): bank = 4*row mod 32 -> 2-way only (free).
// ---------------------------------------------------------------------------
template <int POSTG, int OUTMODE>
__global__ __launch_bounds__(256) void gemm_bf(
    const short* __restrict__ A, const short* __restrict__ B,
    const float* __restrict__ bias, float* __restrict__ Cf,
    short* __restrict__ Cb, int M, int N, int K) {
    __shared__ __align__(16) short As[128 * 72];
    __shared__ __align__(16) short Bs[128 * 72];
    const unsigned gx = gridDim.x, gy = gridDim.y;
    const unsigned nwg = gx * gy;
    const unsigned orig = blockIdx.y * gx + blockIdx.x;
    const unsigned q = nwg >> 3, r = nwg & 7;
    const unsigned xcd = orig & 7, sidx = orig >> 3;
    const unsigned swz = (xcd < r ? xcd * (q + 1) : r * (q + 1) + (xcd - r) * q) + sidx;
    const unsigned CH = 8;
    const unsigned chunk = swz / (CH * gx);
    const unsigned rem = swz - chunk * (CH * gx);
    const unsigned nr = min(CH, gy - chunk * CH);
    const unsigned col = rem / nr;
    const unsigned rowin = rem - col * nr;
    const int bm = (int)(chunk * CH + rowin) * 128;
    const int bn = (int)col * 128;

    const int tid = threadIdx.x;
    const int lane = tid & 63;
    const int wave = tid >> 6;
    const int wm = (wave >> 1) * 64, wn = (wave & 1) * 64;
    const int lr16 = lane & 15;
    const int lk8 = (lane >> 4) * 8;

    // staging: thread t -> row t>>1, 32-short k-chunk (t&1)*32 (64 B)
    const int srow = tid >> 1;
    const int skb = (tid & 1) * 32;
    const int arow = min(bm + srow, M - 1);
    const int brow = min(bn + srow, N - 1);
    const short* Ap = A + (size_t)arow * K + skb;
    const short* Bp = B + (size_t)brow * K + skb;

    f32x4 acc[4][4];
#pragma unroll
    for (int i = 0; i < 4; ++i)
#pragma unroll
        for (int j = 0; j < 4; ++j) acc[i][j] = (f32x4){0.f, 0.f, 0.f, 0.f};

    short8 ra[4], rb[4];
    auto load_ab = [&](int k0) {
#pragma unroll
        for (int u = 0; u < 4; ++u) {
            ra[u] = *(const short8*)(Ap + k0 + u * 8);
            rb[u] = *(const short8*)(Bp + k0 + u * 8);
        }
    };

    load_ab(0);
    for (int k0 = 0; k0 < K; k0 += 64) {
        __syncthreads();
#pragma unroll
        for (int u = 0; u < 4; ++u) {
            *(short8*)&As[srow * 72 + skb + u * 8] = ra[u];
            *(short8*)&Bs[srow * 72 + skb + u * 8] = rb[u];
        }
        __syncthreads();
        if (k0 + 64 < K) load_ab(k0 + 64);  // prefetch next tile under MFMA

#pragma unroll
        for (int kk = 0; kk < 2; ++kk) {
            short8 af[4], bfr[4];
#pragma unroll
            for (int mi = 0; mi < 4; ++mi)
                af[mi] = *(const short8*)&As[(wm + mi * 16 + lr16) * 72 + kk * 32 + lk8];
#pragma unroll
            for (int ni = 0; ni < 4; ++ni)
                bfr[ni] = *(const short8*)&Bs[(wn + ni * 16 + lr16) * 72 + kk * 32 + lk8];
#pragma unroll
            for (int mi = 0; mi < 4; ++mi)
#pragma unroll
                for (int ni = 0; ni < 4; ++ni)
                    acc[mi][ni] = __builtin_amdgcn_mfma_f32_16x16x32_bf16(
                        af[mi], bfr[ni], acc[mi][ni], 0, 0, 0);
        }
    }

    // epilogue: C/D layout col=lane&15, row=(lane>>4)*4+reg  [m89 verified]
#pragma unroll
    for (int mi = 0; mi < 4; ++mi) {
        int row0 = bm + wm + mi * 16 + (lane >> 4) * 4;
#pragma unroll
        for (int ni = 0; ni < 4; ++ni) {
            int col2 = bn + wn + ni * 16 + lr16;
            if (col2 < N) {
                float bsv = bias ? bias[col2] : 0.0f;
#pragma unroll
                for (int rr2 = 0; rr2 < 4; ++rr2) {
                    int row = row0 + rr2;
                    if (row < M) {
                        float v = acc[mi][ni][rr2] + bsv;
                        if (POSTG) v = gelu_f(v);
                        if (OUTMODE != 1) Cf[(size_t)row * N + col2] = v;
                        if (OUTMODE != 0) Cb[(size_t)row * N + col2] = (short)f2b(v);
                    }
                }
            }
        }
    }
}

// fp32 -> bf16 bulk convert, 8 elems/thread
__global__ void cvt_b16(const float* __restrict__ in, short* __restrict__ out, int n8) {
    int i = blockIdx.x * 256 + threadIdx.x;
    if (i >= n8) return;
    float4 a = ((const float4*)in)[i * 2];
    float4 b = ((const float4*)in)[i * 2 + 1];
    short8 o;
    o[0] = f2b(a.x); o[1] = f2b(a.y); o[2] = f2b(a.z); o[3] = f2b(a.w);
    o[4] = f2b(b.x); o[5] = f2b(b.y); o[6] = f2b(b.z); o[7] = f2b(b.w);
    *(short8*)(out + (size_t)i * 8) = o;
}

__global__ void cp_f32(const float* __restrict__ in, float* __restrict__ out, int n) {
    int i = blockIdx.x * 256 + threadIdx.x;
    if (i < n) out[i] = in[i];
}

// ---------------------------------------------------------------------------
// fold att_r/msg_r into the K/V projection weight; bf16 weight out.
// ---------------------------------------------------------------------------
__global__ __launch_bounds__(256) void fuse_w(
    const float* __restrict__ w, const float* __restrict__ bsrc,
    const float* __restrict__ r, short* __restrict__ fw, float* __restrict__ fb) {
    int h = blockIdx.y;
    int dc = blockIdx.x * 64;
    __shared__ float rs[64][64];
    int tid = threadIdx.x;
    for (int i = tid; i < 4096; i += 256) rs[i >> 6][i & 63] = r[h * 4096 + i];
    __syncthreads();
    for (int rep = 0; rep < 16; ++rep) {
        int o = rep * 256 + tid;
        int j = o >> 6;
        int dd = o & 63;
        float s = 0.0f;
#pragma unroll 8
        for (int i = 0; i < 64; ++i)
            s = fmaf(rs[i][j], w[(size_t)(h * 64 + i) * D + dc + dd], s);
        fw[(size_t)(h * 64 + j) * D + dc + dd] = (short)f2b(s);
    }
    if (blockIdx.x == 0 && tid < 64) {
        float s = 0.0f;
        for (int i = 0; i < 64; ++i) s += bsrc[h * 64 + i] * rs[i][tid];
        fb[h * 64 + tid] = s;
    }
}

// ---------------------------------------------------------------------------
// CSR build by dst:  hist -> scan -> scatter (CSR-ordered src list)
// ---------------------------------------------------------------------------
__global__ void zero_int(int* __restrict__ p, int n) {
    int i = blockIdx.x * 256 + threadIdx.x;
    if (i < n) p[i] = 0;
}

__global__ void hist_dst(const int* __restrict__ dst, int* __restrict__ cnt, int E) {
    int i = blockIdx.x * 256 + threadIdx.x;
    if (i < E) atomicAdd(&cnt[dst[i]], 1);
}

__global__ __launch_bounds__(1024) void scan_counts(
    const int* __restrict__ cnt, int* __restrict__ offs, int* __restrict__ cursor,
    int n, int E) {
    __shared__ int part[1024];
    int t = threadIdx.x;
    int chunk = (n + 1023) >> 10;
    int lo = t * chunk;
    int hi = min(lo + chunk, n);
    int s = 0;
    for (int i = lo; i < hi; ++i) s += cnt[i];
    part[t] = s;
    __syncthreads();
    for (int off = 1; off < 1024; off <<= 1) {
        int v = (t >= off) ? part[t - off] : 0;
        __syncthreads();
        part[t] += v;
        __syncthreads();
    }
    int base = (t == 0) ? 0 : part[t - 1];
    for (int i = lo; i < hi; ++i) {
        offs[i] = base;
        cursor[i] = base;
        base += cnt[i];
    }
    if (t == 1023) offs[n] = E;
}

__global__ void scatter_edges(const int* __restrict__ src, const int* __restrict__ dst,
                              int* __restrict__ cursor, int* __restrict__ srcs, int E) {
    int i = blockIdx.x * 256 + threadIdx.x;
    if (i < E) {
        int pos = atomicAdd(&cursor[dst[i]], 1);
        srcs[pos] = src[i];
    }
}

// ---------------------------------------------------------------------------
// Fused per-node edge attention, one WAVE per dst node (4 nodes / block).
// Zero LDS, zero barriers: per-lane flash-softmax state replicated across
// each 8-lane head group; per edge = k-gather + dot + 3 shfl + rescale +
// v-gather. kqv row: [0,512)=k', [512,1024)=q, [1024,1536)=v'.
// ---------------------------------------------------------------------------
__global__ __launch_bounds__(256) void edge_attn(
    const short* __restrict__ kqv, const int* __restrict__ srcs,
    const int* __restrict__ offs, const float* __restrict__ pri,
    short* __restrict__ gg, int NNodes) {
    int n = blockIdx.x * 4 + (threadIdx.x >> 6);
    if (n >= NNodes) return;
    int lane = threadIdx.x & 63;
    int start = offs[n], end = offs[n + 1];

    const short8 qv = *(const short8*)(kqv + (size_t)n * 1536 + 512 + lane * 8);
    float qf[8];
#pragma unroll
    for (int j = 0; j < 8; ++j) qf[j] = b2f((unsigned short)qv[j]);
    const float prih = pri[lane >> 3] * 0.125f;

    float rm = -INFINITY, rden = 0.0f;
    float vacc[8];
#pragma unroll
    for (int j = 0; j < 8; ++j) vacc[j] = 0.0f;

    for (int i = start; i < end; ++i) {
        int sn = srcs[i];
        const short* row = kqv + (size_t)sn * 1536;
        short8 kv = *(const short8*)(row + lane * 8);
        short8 vv = *(const short8*)(row + 1024 + lane * 8);
        float sum = 0.0f;
#pragma unroll
        for (int j = 0; j < 8; ++j)
            sum = fmaf(b2f((unsigned short)kv[j]), qf[j], sum);
        sum += __shfl_xor(sum, 1);
        sum += __shfl_xor(sum, 2);
        sum += __shfl_xor(sum, 4);   // all 8 lanes of head group hold head dot
        float tt = sum * prih;
        float nm = fmaxf(rm, tt);
        float scl = expf(rm - nm);   // 0 on first edge (rm = -inf)
        float e = expf(tt - nm);
        rden = rden * scl + e;
        rm = nm;
#pragma unroll
        for (int j = 0; j < 8; ++j)
            vacc[j] = fmaf(vacc[j], scl, b2f((unsigned short)vv[j]) * e);
    }

    float inv = 1.0f / fmaxf(rden, 1e-9f);
    unsigned o[4];
#pragma unroll
    for (int p = 0; p < 4; ++p) {
        float s0 = gelu_f(vacc[2 * p] * inv);
        float s1 = gelu_f(vacc[2 * p + 1] * inv);
        o[p] = (unsigned)(unsigned short)f2b(s0) |
               ((unsigned)(unsigned short)f2b(s1) << 16);
    }
    uint4 pack = make_uint4(o[0], o[1], o[2], o[3]);
    *(uint4*)(gg + (size_t)n * D + lane * 8) = pack;
}

// out = trans*alpha + h*(1-alpha); layernorm; write fp32 h + bf16 h.
__global__ __launch_bounds__(128) void blend_ln(
    const float* __restrict__ trans, const float* __restrict__ hin,
    const float* __restrict__ skip, const float* __restrict__ g,
    const float* __restrict__ b, float* __restrict__ hout,
    short* __restrict__ hb16) {
    int n = blockIdx.x;
    int tid = threadIdx.x;  // 0..127
    float alpha = 1.0f / (1.0f + expf(-skip[0]));
    size_t base = (size_t)n * D + tid * 4;
    float4 t4 = *(const float4*)(trans + base);
    float4 h4 = *(const float4*)(hin + base);
    float o[4];
    o[0] = t4.x * alpha + h4.x * (1.0f - alpha);
    o[1] = t4.y * alpha + h4.y * (1.0f - alpha);
    o[2] = t4.z * alpha + h4.z * (1.0f - alpha);
    o[3] = t4.w * alpha + h4.w * (1.0f - alpha);
    float s = o[0] + o[1] + o[2] + o[3];
    float ss = o[0] * o[0] + o[1] * o[1] + o[2] * o[2] + o[3] * o[3];
    for (int off = 32; off; off >>= 1) {
        s += __shfl_down(s, off);
        ss += __shfl_down(ss, off);
    }
    __shared__ float red[4];
    if ((tid & 63) == 0) { red[tid >> 6] = s; red[2 + (tid >> 6)] = ss; }
    __syncthreads();
    float S = red[0] + red[1];
    float SS = red[2] + red[3];
    float mu = S * (1.0f / 512.0f);
    float var = SS * (1.0f / 512.0f) - mu * mu;
    float inv = rsqrtf(var + 1e-5f);
    int c = tid * 4;
    float4 o4;
    o4.x = (o[0] - mu) * inv * g[c + 0] + b[c + 0];
    o4.y = (o[1] - mu) * inv * g[c + 1] + b[c + 1];
    o4.z = (o[2] - mu) * inv * g[c + 2] + b[c + 2];
    o4.w = (o[3] - mu) * inv * g[c + 3] + b[c + 3];
    *(float4*)(hout + base) = o4;
    short4v hb;
    hb[0] = f2b(o4.x); hb[1] = f2b(o4.y); hb[2] = f2b(o4.z); hb[3] = f2b(o4.w);
    *(short4v*)(hb16 + base) = hb;
}

// embs16 = bf16(embeddings * attn_kernels), 8 elems/thread
__global__ void scale_emb_b16(const float* __restrict__ e, const float* __restrict__ ak,
                              short* __restrict__ o, int n8) {
    int i = blockIdx.x * 256 + threadIdx.x;
    if (i >= n8) return;
    float4 a = ((const float4*)e)[i * 2];
    float4 b = ((const float4*)e)[i * 2 + 1];
    int d0 = (i * 8) & (D - 1);
    short8 v;
    v[0] = f2b(a.x * ak[d0 + 0]); v[1] = f2b(a.y * ak[d0 + 1]);
    v[2] = f2b(a.z * ak[d0 + 2]); v[3] = f2b(a.w * ak[d0 + 3]);
    v[4] = f2b(b.x * ak[d0 + 4]); v[5] = f2b(b.y * ak[d0 + 5]);
    v[6] = f2b(b.z * ak[d0 + 6]); v[7] = f2b(b.w * ak[d0 + 7]);
    *(short8*)(o + (size_t)i * 8) = v;
}

extern "C" void kernel_launch(void* const* d_in, const int* in_sizes, int n_in,
                              void* d_out, int out_size, void* d_ws, size_t ws_size,
                              hipStream_t stream) {
    const float* embeddings = (const float*)d_in[0];
    const float* node_emb   = (const float*)d_in[1];
    const float* adapt_w    = (const float*)d_in[2];
    const float* adapt_b    = (const float*)d_in[3];
    const float* kw   = (const float*)d_in[4];
    const float* kb   = (const float*)d_in[5];
    const float* qw   = (const float*)d_in[6];
    const float* qb   = (const float*)d_in[7];
    const float* vw   = (const float*)d_in[8];
    const float* vb   = (const float*)d_in[9];
    const float* aw   = (const float*)d_in[10];
    const float* ab   = (const float*)d_in[11];
    const float* pri  = (const float*)d_in[12];
    const float* att_r = (const float*)d_in[13];
    const float* msg_r = (const float*)d_in[14];
    const float* skip  = (const float*)d_in[15];
    const float* ln_g  = (const float*)d_in[16];
    const float* ln_b  = (const float*)d_in[17];
    const float* out_w = (const float*)d_in[18];
    const float* out_b = (const float*)d_in[19];
    const float* attn_k = (const float*)d_in[20];
    const int* src = (const int*)d_in[21];
    const int* dst = (const int*)d_in[22];

    const int E  = in_sizes[21];
    const int NB = in_sizes[0] / D;   // 8192
    const int NN = in_sizes[1] / D;   // 20000
    const int NC = out_size / NB;     // 10000

    size_t big = (size_t)NN * D;
    float* hbuf = (float*)d_ws;                  // fp32 h (residual/LN)
    float* fb32 = hbuf + big;                    // trans out
    short* hb16 = (short*)(fb32 + big);          // bf16 h (GEMM A operand)
    short* gg16 = hb16 + big;                    // node_emb bf16 / gelu(agg)
    short* kqv16 = gg16 + big;                   // [NN][1536] k'|q|v'
    short* w16a = kqv16 + (size_t)NN * 1536;     // adapt_w
    short* w16o = w16a + (size_t)D * D;          // out_w
    short* w16w = w16o + (size_t)D * D;          // aw[l]
    short* wcat = w16w + (size_t)D * D;          // [1536][512] k'|q|v' weights
    float* bcat = (float*)(wcat + (size_t)1536 * D);  // [1536]
    int* offs   = (int*)(bcat + 1536);           // NN+1
    int* cursor = offs + NN + 1;                 // NN
    int* srcs   = cursor + NN;                   // E (CSR order)
    short* cls16 = kqv16;                        // reuse after layers
    short* embs16 = kqv16 + (size_t)NC * D;

    auto ggrid = [](int M, int N) { return dim3((N + 127) / 128, (M + 127) / 128); };
    const int WB = D * D / 8;

    // ---- CSR by dst (src/dst are layer-invariant) ----
    zero_int<<<(NN + 255) / 256, 256, 0, stream>>>(cursor, NN);
    hist_dst<<<(E + 255) / 256, 256, 0, stream>>>(dst, cursor, E);
    scan_counts<<<1, 1024, 0, stream>>>(cursor, offs, cursor, NN, E);
    scatter_edges<<<(E + 255) / 256, 256, 0, stream>>>(src, dst, cursor, srcs, E);

    // ---- one-shot bf16 conversions ----
    cvt_b16<<<((int)(big / 8) + 255) / 256, 256, 0, stream>>>(node_emb, gg16, (int)(big / 8));
    cvt_b16<<<(WB + 255) / 256, 256, 0, stream>>>(adapt_w, w16a, WB);
    cvt_b16<<<(WB + 255) / 256, 256, 0, stream>>>(out_w, w16o, WB);

    // h = gelu(node_emb @ adapt_w^T + adapt_b)  -> fp32 + bf16
    gemm_bf<1, 2><<<ggrid(NN, D), 256, 0, stream>>>(gg16, w16a, adapt_b, hbuf, hb16, NN, D, D);

    for (int l = 0; l < NLAYER; ++l) {
        const size_t wo = (size_t)l * D * D;
        // wcat rows: [0,512) fused-K, [512,1024) Q, [1024,1536) fused-V
        fuse_w<<<dim3(8, 8), 256, 0, stream>>>(kw + wo, kb + l * D, att_r + (size_t)l * H * 64 * 64, wcat, bcat);
        cvt_b16<<<(WB + 255) / 256, 256, 0, stream>>>(qw + wo, wcat + (size_t)512 * D, WB);
        cp_f32<<<2, 256, 0, stream>>>(qb + l * D, bcat + 512, D);
        fuse_w<<<dim3(8, 8), 256, 0, stream>>>(vw + wo, vb + l * D, msg_r + (size_t)l * H * 64 * 64, wcat + (size_t)1024 * D, bcat + 1024);

        // kqv = h @ wcat^T + bcat   (one GEMM, N=1536)
        gemm_bf<0, 1><<<ggrid(NN, 1536), 256, 0, stream>>>(hb16, wcat, bcat, nullptr, kqv16, NN, 1536, D);

        // fused edge attention -> gelu(agg) bf16 (wave per node)
        edge_attn<<<(NN + 3) / 4, 256, 0, stream>>>(kqv16, srcs, offs, pri + l * H, gg16, NN);

        // trans = gelu(agg) @ aw^T + ab -> fp32
        cvt_b16<<<(WB + 255) / 256, 256, 0, stream>>>(aw + wo, w16w, WB);
        gemm_bf<0, 0><<<ggrid(NN, D), 256, 0, stream>>>(gg16, w16w, ab + l * D, fb32, nullptr, NN, D, D);
        blend_ln<<<NN, 128, 0, stream>>>(fb32, hbuf, skip + l, ln_g + l * D, ln_b + l * D, hbuf, hb16);
    }

    // cls_emb = h[:NC] @ out_w^T + out_b  -> bf16
    gemm_bf<0, 1><<<ggrid(NC, D), 256, 0, stream>>>(hb16, w16o, out_b, nullptr, cls16, NC, D, D);
    // embs = bf16(embeddings * attn_kernels)
    scale_emb_b16<<<((NB * D / 8) + 255) / 256, 256, 0, stream>>>(embeddings, attn_k, embs16, NB * D / 8);
    // logits = embs @ cls_emb^T  -> fp32 d_out
    gemm_bf<0, 0><<<ggrid(NB, NC), 256, 0, stream>>>(embs16, cls16, nullptr, (float*)d_out, nullptr, NB, NC, D);
}

// Round 8
// 861.834 us; speedup vs baseline: 13.9204x; 1.0153x over previous
//
#include <hip/hip_runtime.h>
#include <hip/hip_bf16.h>

#define D 512
#define H 8
#define NLAYER 2

typedef __attribute__((ext_vector_type(8))) short short8;
typedef __attribute__((ext_vector_type(4))) short short4v;
typedef __attribute__((ext_vector_type(4))) float f32x4;

__device__ __forceinline__ float gelu_f(float x) {
    float x3 = x * x * x;
    return 0.5f * x * (1.0f + tanhf(0.7978845608028654f * (x + 0.044715f * x3)));
}

// fp32 -> bf16 bits, round-to-nearest-even
__device__ __forceinline__ unsigned short f2b(float x) {
    unsigned u = __float_as_uint(x);
    u += 0x7FFF + ((u >> 16) & 1);
    return (unsigned short)(u >> 16);
}
__device__ __forceinline__ float b2f(unsigned short u) {
    return __uint_as_float(((unsigned)u) << 16);
}

// HBM -> LDS direct 16B async copy (dest must be wave-uniform base + lane*16)
__device__ __forceinline__ void gld16(const short* g, short* l) {
    __builtin_amdgcn_global_load_lds(
        (const __attribute__((address_space(1))) void*)g,
        (__attribute__((address_space(3))) void*)l, 16, 0, 0);
}

// ---------------------------------------------------------------------------
// C[M,N] = postact( A[M,K] @ B[N,K]^T + bias ), A/B bf16-resident, fp32 accum.
// m97-family: 128x128 tile, BK=32, linear LDS [128][32] shorts, staging via
// global_load_lds (16B), double-buffered 2-phase schedule (stage next tile
// right after the single per-step barrier, overlap with ds_read+MFMA).
// 256 threads = 4 waves (2x2 of 64x64), 4x4 16x16x32 frags.
// OUTMODE: 0 = f32 out, 1 = bf16 out, 2 = both.
// Tile order: bijective XCD split + 8-row chunks iterated bn-major per XCD.
// ---------------------------------------------------------------------------
template <int POSTG, int OUTMODE>
__global__ __launch_bounds__(256) void gemm_bf(
    const short* __restrict__ A, const short* __restrict__ B,
    const float* __restrict__ bias, float* __restrict__ Cf,
    short* __restrict__ Cb, int M, int N, int K) {
    __shared__ __align__(16) short As[2][4096];  // [buf][128 rows x 32 shorts]
    __shared__ __align__(16) short Bs[2][4096];
    const unsigned gx = gridDim.x, gy = gridDim.y;
    const unsigned nwg = gx * gy;
    const unsigned orig = blockIdx.y * gx + blockIdx.x;
    const unsigned q = nwg >> 3, r = nwg & 7;
    const unsigned xcd = orig & 7, sidx = orig >> 3;
    const unsigned swz = (xcd < r ? xcd * (q + 1) : r * (q + 1) + (xcd - r) * q) + sidx;
    const unsigned CH = 8;
    const unsigned chunk = swz / (CH * gx);
    const unsigned rem = swz - chunk * (CH * gx);
    const unsigned nr = min(CH, gy - chunk * CH);
    const unsigned col = rem / nr;
    const unsigned rowin = rem - col * nr;
    const int bm = (int)(chunk * CH + rowin) * 128;
    const int bn = (int)col * 128;

    const int tid = threadIdx.x;
    const int lane = tid & 63;
    const int wave = tid >> 6;
    const int wm = (wave >> 1) * 64, wn = (wave & 1) * 64;
    const int lr16 = lane & 15;
    const int lk8 = (lane >> 4) * 8;

    // staging geometry: thread t covers 16B chunk (t&3) of row (t>>2); two
    // issues per matrix cover rows 0-63 and 64-127. LDS dest = base + t*16B.
    const int trow = tid >> 2;
    const int tchk = (tid & 3) * 8;
    const short* a0 = A + (size_t)min(bm + trow, M - 1) * K + tchk;
    const short* a1 = A + (size_t)min(bm + 64 + trow, M - 1) * K + tchk;
    const short* b0 = B + (size_t)min(bn + trow, N - 1) * K + tchk;
    const short* b1 = B + (size_t)min(bn + 64 + trow, N - 1) * K + tchk;

    auto stage = [&](int buf, int k0) {
        gld16(a0 + k0, &As[buf][tid * 8]);
        gld16(a1 + k0, &As[buf][2048 + tid * 8]);
        gld16(b0 + k0, &Bs[buf][tid * 8]);
        gld16(b1 + k0, &Bs[buf][2048 + tid * 8]);
    };

    f32x4 acc[4][4];
#pragma unroll
    for (int i = 0; i < 4; ++i)
#pragma unroll
        for (int j = 0; j < 4; ++j) acc[i][j] = (f32x4){0.f, 0.f, 0.f, 0.f};

    stage(0, 0);
    int cur = 0;
    for (int k0 = 0; k0 < K; k0 += 32) {
        __syncthreads();  // drains vmcnt -> buf[cur] ready; prev reads done
        if (k0 + 32 < K) stage(cur ^ 1, k0 + 32);  // overlaps with compute

        short8 af[4], bfr[4];
#pragma unroll
        for (int mi = 0; mi < 4; ++mi)
            af[mi] = *(const short8*)&As[cur][(wm + mi * 16 + lr16) * 32 + lk8];
#pragma unroll
        for (int ni = 0; ni < 4; ++ni)
            bfr[ni] = *(const short8*)&Bs[cur][(wn + ni * 16 + lr16) * 32 + lk8];
#pragma unroll
        for (int mi = 0; mi < 4; ++mi)
#pragma unroll
            for (int ni = 0; ni < 4; ++ni)
                acc[mi][ni] = __builtin_amdgcn_mfma_f32_16x16x32_bf16(
                    af[mi], bfr[ni], acc[mi][ni], 0, 0, 0);
        cur ^= 1;
    }

    // epilogue: C/D layout col=lane&15, row=(lane>>4)*4+reg  [m89 verified]
#pragma unroll
    for (int mi = 0; mi < 4; ++mi) {
        int row0 = bm + wm + mi * 16 + (lane >> 4) * 4;
#pragma unroll
        for (int ni = 0; ni < 4; ++ni) {
            int col2 = bn + wn + ni * 16 + lr16;
            if (col2 < N) {
                float bsv = bias ? bias[col2] : 0.0f;
#pragma unroll
                for (int rr2 = 0; rr2 < 4; ++rr2) {
                    int row = row0 + rr2;
                    if (row < M) {
                        float v = acc[mi][ni][rr2] + bsv;
                        if (POSTG) v = gelu_f(v);
                        if (OUTMODE != 1) Cf[(size_t)row * N + col2] = v;
                        if (OUTMODE != 0) Cb[(size_t)row * N + col2] = (short)f2b(v);
                    }
                }
            }
        }
    }
}

// fp32 -> bf16 bulk convert, 8 elems/thread
__global__ void cvt_b16(const float* __restrict__ in, short* __restrict__ out, int n8) {
    int i = blockIdx.x * 256 + threadIdx.x;
    if (i >= n8) return;
    float4 a = ((const float4*)in)[i * 2];
    float4 b = ((const float4*)in)[i * 2 + 1];
    short8 o;
    o[0] = f2b(a.x); o[1] = f2b(a.y); o[2] = f2b(a.z); o[3] = f2b(a.w);
    o[4] = f2b(b.x); o[5] = f2b(b.y); o[6] = f2b(b.z); o[7] = f2b(b.w);
    *(short8*)(out + (size_t)i * 8) = o;
}

__global__ void cp_f32(const float* __restrict__ in, float* __restrict__ out, int n) {
    int i = blockIdx.x * 256 + threadIdx.x;
    if (i < n) out[i] = in[i];
}

// ---------------------------------------------------------------------------
// fold att_r/msg_r into the K/V projection weight; bf16 weight out.
// ---------------------------------------------------------------------------
__global__ __launch_bounds__(256) void fuse_w(
    const float* __restrict__ w, const float* __restrict__ bsrc,
    const float* __restrict__ r, short* __restrict__ fw, float* __restrict__ fb) {
    int h = blockIdx.y;
    int dc = blockIdx.x * 64;
    __shared__ float rs[64][64];
    int tid = threadIdx.x;
    for (int i = tid; i < 4096; i += 256) rs[i >> 6][i & 63] = r[h * 4096 + i];
    __syncthreads();
    for (int rep = 0; rep < 16; ++rep) {
        int o = rep * 256 + tid;
        int j = o >> 6;
        int dd = o & 63;
        float s = 0.0f;
#pragma unroll 8
        for (int i = 0; i < 64; ++i)
            s = fmaf(rs[i][j], w[(size_t)(h * 64 + i) * D + dc + dd], s);
        fw[(size_t)(h * 64 + j) * D + dc + dd] = (short)f2b(s);
    }
    if (blockIdx.x == 0 && tid < 64) {
        float s = 0.0f;
        for (int i = 0; i < 64; ++i) s += bsrc[h * 64 + i] * rs[i][tid];
        fb[h * 64 + tid] = s;
    }
}

// ---------------------------------------------------------------------------
// CSR build by dst:  hist -> scan -> scatter (CSR-ordered src list)
// ---------------------------------------------------------------------------
__global__ void zero_int(int* __restrict__ p, int n) {
    int i = blockIdx.x * 256 + threadIdx.x;
    if (i < n) p[i] = 0;
}

__global__ void hist_dst(const int* __restrict__ dst, int* __restrict__ cnt, int E) {
    int i = blockIdx.x * 256 + threadIdx.x;
    if (i < E) atomicAdd(&cnt[dst[i]], 1);
}

__global__ __launch_bounds__(1024) void scan_counts(
    const int* __restrict__ cnt, int* __restrict__ offs, int* __restrict__ cursor,
    int n, int E) {
    __shared__ int part[1024];
    int t = threadIdx.x;
    int chunk = (n + 1023) >> 10;
    int lo = t * chunk;
    int hi = min(lo + chunk, n);
    int s = 0;
    for (int i = lo; i < hi; ++i) s += cnt[i];
    part[t] = s;
    __syncthreads();
    for (int off = 1; off < 1024; off <<= 1) {
        int v = (t >= off) ? part[t - off] : 0;
        __syncthreads();
        part[t] += v;
        __syncthreads();
    }
    int base = (t == 0) ? 0 : part[t - 1];
    for (int i = lo; i < hi; ++i) {
        offs[i] = base;
        cursor[i] = base;
        base += cnt[i];
    }
    if (t == 1023) offs[n] = E;
}

__global__ void scatter_edges(const int* __restrict__ src, const int* __restrict__ dst,
                              int* __restrict__ cursor, int* __restrict__ srcs, int E) {
    int i = blockIdx.x * 256 + threadIdx.x;
    if (i < E) {
        int pos = atomicAdd(&cursor[dst[i]], 1);
        srcs[pos] = src[i];
    }
}

// ---------------------------------------------------------------------------
// Fused per-node edge attention, one WAVE per dst node (4 nodes / block).
// Unroll-2: two independent flash-softmax states (even/odd slots) merged at
// the end -> half the serial load->dot->shfl->rescale chain length.
// kqv row: [0,512)=k', [512,1024)=q, [1024,1536)=v'.
// ---------------------------------------------------------------------------
__global__ __launch_bounds__(256) void edge_attn(
    const short* __restrict__ kqv, const int* __restrict__ srcs,
    const int* __restrict__ offs, const float* __restrict__ pri,
    short* __restrict__ gg, int NNodes) {
    int n = blockIdx.x * 4 + (threadIdx.x >> 6);
    if (n >= NNodes) return;
    int lane = threadIdx.x & 63;
    int start = offs[n], end = offs[n + 1];

    const short8 qv = *(const short8*)(kqv + (size_t)n * 1536 + 512 + lane * 8);
    float qf[8];
#pragma unroll
    for (int j = 0; j < 8; ++j) qf[j] = b2f((unsigned short)qv[j]);
    const float prih = pri[lane >> 3] * 0.125f;

    float rm0 = -INFINITY, rd0 = 0.0f, rm1 = -INFINITY, rd1 = 0.0f;
    float va0[8], va1[8];
#pragma unroll
    for (int j = 0; j < 8; ++j) { va0[j] = 0.0f; va1[j] = 0.0f; }

    int i = start;
    for (; i + 1 < end; i += 2) {
        int s0 = srcs[i], s1 = srcs[i + 1];
        const short* r0 = kqv + (size_t)s0 * 1536;
        const short* r1 = kqv + (size_t)s1 * 1536;
        short8 k0 = *(const short8*)(r0 + lane * 8);
        short8 v0 = *(const short8*)(r0 + 1024 + lane * 8);
        short8 k1 = *(const short8*)(r1 + lane * 8);
        short8 v1 = *(const short8*)(r1 + 1024 + lane * 8);
        float d0 = 0.0f, d1 = 0.0f;
#pragma unroll
        for (int j = 0; j < 8; ++j) {
            d0 = fmaf(b2f((unsigned short)k0[j]), qf[j], d0);
            d1 = fmaf(b2f((unsigned short)k1[j]), qf[j], d1);
        }
        d0 += __shfl_xor(d0, 1); d1 += __shfl_xor(d1, 1);
        d0 += __shfl_xor(d0, 2); d1 += __shfl_xor(d1, 2);
        d0 += __shfl_xor(d0, 4); d1 += __shfl_xor(d1, 4);
        float t0 = d0 * prih, t1 = d1 * prih;
        float nm0 = fmaxf(rm0, t0), nm1 = fmaxf(rm1, t1);
        float sc0 = expf(rm0 - nm0), sc1 = expf(rm1 - nm1);
        float e0 = expf(t0 - nm0), e1 = expf(t1 - nm1);
        rd0 = rd0 * sc0 + e0; rm0 = nm0;
        rd1 = rd1 * sc1 + e1; rm1 = nm1;
#pragma unroll
        for (int j = 0; j < 8; ++j) {
            va0[j] = fmaf(va0[j], sc0, b2f((unsigned short)v0[j]) * e0);
            va1[j] = fmaf(va1[j], sc1, b2f((unsigned short)v1[j]) * e1);
        }
    }
    if (i < end) {  // tail edge -> state 0
        int s0 = srcs[i];
        const short* r0 = kqv + (size_t)s0 * 1536;
        short8 k0 = *(const short8*)(r0 + lane * 8);
        short8 v0 = *(const short8*)(r0 + 1024 + lane * 8);
        float d0 = 0.0f;
#pragma unroll
        for (int j = 0; j < 8; ++j) d0 = fmaf(b2f((unsigned short)k0[j]), qf[j], d0);
        d0 += __shfl_xor(d0, 1);
        d0 += __shfl_xor(d0, 2);
        d0 += __shfl_xor(d0, 4);
        float t0 = d0 * prih;
        float nm0 = fmaxf(rm0, t0);
        float sc0 = expf(rm0 - nm0);
        float e0 = expf(t0 - nm0);
        rd0 = rd0 * sc0 + e0; rm0 = nm0;
#pragma unroll
        for (int j = 0; j < 8; ++j)
            va0[j] = fmaf(va0[j], sc0, b2f((unsigned short)v0[j]) * e0);
    }

    // merge the two states (clamp avoids exp(-inf - -inf) NaN on deg-0 nodes)
    float m = fmaxf(fmaxf(rm0, rm1), -3.0e38f);
    float s0 = expf(rm0 - m), s1 = expf(rm1 - m);
    float rden = rd0 * s0 + rd1 * s1;
    float inv = 1.0f / fmaxf(rden, 1e-9f);
    unsigned o[4];
#pragma unroll
    for (int p = 0; p < 4; ++p) {
        float x0 = gelu_f((va0[2 * p] * s0 + va1[2 * p] * s1) * inv);
        float x1 = gelu_f((va0[2 * p + 1] * s0 + va1[2 * p + 1] * s1) * inv);
        o[p] = (unsigned)(unsigned short)f2b(x0) |
               ((unsigned)(unsigned short)f2b(x1) << 16);
    }
    uint4 pack = make_uint4(o[0], o[1], o[2], o[3]);
    *(uint4*)(gg + (size_t)n * D + lane * 8) = pack;
}

// out = trans*alpha + h*(1-alpha); layernorm; write fp32 h + bf16 h.
__global__ __launch_bounds__(128) void blend_ln(
    const float* __restrict__ trans, const float* __restrict__ hin,
    const float* __restrict__ skip, const float* __restrict__ g,
    const float* __restrict__ b, float* __restrict__ hout,
    short* __restrict__ hb16) {
    int n = blockIdx.x;
    int tid = threadIdx.x;  // 0..127
    float alpha = 1.0f / (1.0f + expf(-skip[0]));
    size_t base = (size_t)n * D + tid * 4;
    float4 t4 = *(const float4*)(trans + base);
    float4 h4 = *(const float4*)(hin + base);
    float o[4];
    o[0] = t4.x * alpha + h4.x * (1.0f - alpha);
    o[1] = t4.y * alpha + h4.y * (1.0f - alpha);
    o[2] = t4.z * alpha + h4.z * (1.0f - alpha);
    o[3] = t4.w * alpha + h4.w * (1.0f - alpha);
    float s = o[0] + o[1] + o[2] + o[3];
    float ss = o[0] * o[0] + o[1] * o[1] + o[2] * o[2] + o[3] * o[3];
    for (int off = 32; off; off >>= 1) {
        s += __shfl_down(s, off);
        ss += __shfl_down(ss, off);
    }
    __shared__ float red[4];
    if ((tid & 63) == 0) { red[tid >> 6] = s; red[2 + (tid >> 6)] = ss; }
    __syncthreads();
    float S = red[0] + red[1];
    float SS = red[2] + red[3];
    float mu = S * (1.0f / 512.0f);
    float var = SS * (1.0f / 512.0f) - mu * mu;
    float inv = rsqrtf(var + 1e-5f);
    int c = tid * 4;
    float4 o4;
    o4.x = (o[0] - mu) * inv * g[c + 0] + b[c + 0];
    o4.y = (o[1] - mu) * inv * g[c + 1] + b[c + 1];
    o4.z = (o[2] - mu) * inv * g[c + 2] + b[c + 2];
    o4.w = (o[3] - mu) * inv * g[c + 3] + b[c + 3];
    *(float4*)(hout + base) = o4;
    short4v hb;
    hb[0] = f2b(o4.x); hb[1] = f2b(o4.y); hb[2] = f2b(o4.z); hb[3] = f2b(o4.w);
    *(short4v*)(hb16 + base) = hb;
}

// embs16 = bf16(embeddings * attn_kernels), 8 elems/thread
__global__ void scale_emb_b16(const float* __restrict__ e, const float* __restrict__ ak,
                              short* __restrict__ o, int n8) {
    int i = blockIdx.x * 256 + threadIdx.x;
    if (i >= n8) return;
    float4 a = ((const float4*)e)[i * 2];
    float4 b = ((const float4*)e)[i * 2 + 1];
    int d0 = (i * 8) & (D - 1);
    short8 v;
    v[0] = f2b(a.x * ak[d0 + 0]); v[1] = f2b(a.y * ak[d0 + 1]);
    v[2] = f2b(a.z * ak[d0 + 2]); v[3] = f2b(a.w * ak[d0 + 3]);
    v[4] = f2b(b.x * ak[d0 + 4]); v[5] = f2b(b.y * ak[d0 + 5]);
    v[6] = f2b(b.z * ak[d0 + 6]); v[7] = f2b(b.w * ak[d0 + 7]);
    *(short8*)(o + (size_t)i * 8) = v;
}

extern "C" void kernel_launch(void* const* d_in, const int* in_sizes, int n_in,
                              void* d_out, int out_size, void* d_ws, size_t ws_size,
                              hipStream_t stream) {
    const float* embeddings = (const float*)d_in[0];
    const float* node_emb   = (const float*)d_in[1];
    const float* adapt_w    = (const float*)d_in[2];
    const float* adapt_b    = (const float*)d_in[3];
    const float* kw   = (const float*)d_in[4];
    const float* kb   = (const float*)d_in[5];
    const float* qw   = (const float*)d_in[6];
    const float* qb   = (const float*)d_in[7];
    const float* vw   = (const float*)d_in[8];
    const float* vb   = (const float*)d_in[9];
    const float* aw   = (const float*)d_in[10];
    const float* ab   = (const float*)d_in[11];
    const float* pri  = (const float*)d_in[12];
    const float* att_r = (const float*)d_in[13];
    const float* msg_r = (const float*)d_in[14];
    const float* skip  = (const float*)d_in[15];
    const float* ln_g  = (const float*)d_in[16];
    const float* ln_b  = (const float*)d_in[17];
    const float* out_w = (const float*)d_in[18];
    const float* out_b = (const float*)d_in[19];
    const float* attn_k = (const float*)d_in[20];
    const int* src = (const int*)d_in[21];
    const int* dst = (const int*)d_in[22];

    const int E  = in_sizes[21];
    const int NB = in_sizes[0] / D;   // 8192
    const int NN = in_sizes[1] / D;   // 20000
    const int NC = out_size / NB;     // 10000

    size_t big = (size_t)NN * D;
    float* hbuf = (float*)d_ws;                  // fp32 h (residual/LN)
    float* fb32 = hbuf + big;                    // trans out
    short* hb16 = (short*)(fb32 + big);          // bf16 h (GEMM A operand)
    short* gg16 = hb16 + big;                    // node_emb bf16 / gelu(agg)
    short* kqv16 = gg16 + big;                   // [NN][1536] k'|q|v'
    short* w16a = kqv16 + (size_t)NN * 1536;     // adapt_w
    short* w16o = w16a + (size_t)D * D;          // out_w
    short* w16w = w16o + (size_t)D * D;          // aw[l]
    short* wcat = w16w + (size_t)D * D;          // [1536][512] k'|q|v' weights
    float* bcat = (float*)(wcat + (size_t)1536 * D);  // [1536]
    int* offs   = (int*)(bcat + 1536);           // NN+1
    int* cursor = offs + NN + 1;                 // NN
    int* srcs   = cursor + NN;                   // E (CSR order)
    short* cls16 = kqv16;                        // reuse after layers
    short* embs16 = kqv16 + (size_t)NC * D;

    auto ggrid = [](int M, int N) { return dim3((N + 127) / 128, (M + 127) / 128); };
    const int WB = D * D / 8;

    // ---- CSR by dst (src/dst are layer-invariant) ----
    zero_int<<<(NN + 255) / 256, 256, 0, stream>>>(cursor, NN);
    hist_dst<<<(E + 255) / 256, 256, 0, stream>>>(dst, cursor, E);
    scan_counts<<<1, 1024, 0, stream>>>(cursor, offs, cursor, NN, E);
    scatter_edges<<<(E + 255) / 256, 256, 0, stream>>>(src, dst, cursor, srcs, E);

    // ---- one-shot bf16 conversions ----
    cvt_b16<<<((int)(big / 8) + 255) / 256, 256, 0, stream>>>(node_emb, gg16, (int)(big / 8));
    cvt_b16<<<(WB + 255) / 256, 256, 0, stream>>>(adapt_w, w16a, WB);
    cvt_b16<<<(WB + 255) / 256, 256, 0, stream>>>(out_w, w16o, WB);

    // h = gelu(node_emb @ adapt_w^T + adapt_b)  -> fp32 + bf16
    gemm_bf<1, 2><<<ggrid(NN, D), 256, 0, stream>>>(gg16, w16a, adapt_b, hbuf, hb16, NN, D, D);

    for (int l = 0; l < NLAYER; ++l) {
        const size_t wo = (size_t)l * D * D;
        // wcat rows: [0,512) fused-K, [512,1024) Q, [1024,1536) fused-V
        fuse_w<<<dim3(8, 8), 256, 0, stream>>>(kw + wo, kb + l * D, att_r + (size_t)l * H * 64 * 64, wcat, bcat);
        cvt_b16<<<(WB + 255) / 256, 256, 0, stream>>>(qw + wo, wcat + (size_t)512 * D, WB);
        cp_f32<<<2, 256, 0, stream>>>(qb + l * D, bcat + 512, D);
        fuse_w<<<dim3(8, 8), 256, 0, stream>>>(vw + wo, vb + l * D, msg_r + (size_t)l * H * 64 * 64, wcat + (size_t)1024 * D, bcat + 1024);

        // kqv = h @ wcat^T + bcat   (one GEMM, N=1536)
        gemm_bf<0, 1><<<ggrid(NN, 1536), 256, 0, stream>>>(hb16, wcat, bcat, nullptr, kqv16, NN, 1536, D);

        // fused edge attention -> gelu(agg) bf16 (wave per node, unroll-2)
        edge_attn<<<(NN + 3) / 4, 256, 0, stream>>>(kqv16, srcs, offs, pri + l * H, gg16, NN);

        // trans = gelu(agg) @ aw^T + ab -> fp32
        cvt_b16<<<(WB + 255) / 256, 256, 0, stream>>>(aw + wo, w16w, WB);
        gemm_bf<0, 0><<<ggrid(NN, D), 256, 0, stream>>>(gg16, w16w, ab + l * D, fb32, nullptr, NN, D, D);
        blend_ln<<<NN, 128, 0, stream>>>(fb32, hbuf, skip + l, ln_g + l * D, ln_b + l * D, hbuf, hb16);
    }

    // cls_emb = h[:NC] @ out_w^T + out_b  -> bf16
    gemm_bf<0, 1><<<ggrid(NC, D), 256, 0, stream>>>(hb16, w16o, out_b, nullptr, cls16, NC, D, D);
    // embs = bf16(embeddings * attn_kernels)
    scale_emb_b16<<<((NB * D / 8) + 255) / 256, 256, 0, stream>>>(embeddings, attn_k, embs16, NB * D / 8);
    // logits = embs @ cls_emb^T  -> fp32 d_out
    gemm_bf<0, 0><<<ggrid(NB, NC), 256, 0, stream>>>(embs16, cls16, nullptr, (float*)d_out, nullptr, NB, NC, D);
}

// Round 9
// 782.885 us; speedup vs baseline: 15.3242x; 1.1008x over previous
//
#include <hip/hip_runtime.h>
#include <hip/hip_bf16.h>

#define D 512
#define H 8
#define NLAYER 2

typedef __attribute__((ext_vector_type(8))) short short8;
typedef __attribute__((ext_vector_type(4))) short short4v;
typedef __attribute__((ext_vector_type(4))) float f32x4;

__device__ __forceinline__ float gelu_f(float x) {
    float x3 = x * x * x;
    return 0.5f * x * (1.0f + tanhf(0.7978845608028654f * (x + 0.044715f * x3)));
}

// fp32 -> bf16 bits, round-to-nearest-even
__device__ __forceinline__ unsigned short f2b(float x) {
    unsigned u = __float_as_uint(x);
    u += 0x7FFF + ((u >> 16) & 1);
    return (unsigned short)(u >> 16);
}
__device__ __forceinline__ float b2f(unsigned short u) {
    return __uint_as_float(((unsigned)u) << 16);
}

// HBM -> LDS direct 16B async copy (dest must be wave-uniform base + lane*16)
__device__ __forceinline__ void gld16(const short* g, short* l) {
    __builtin_amdgcn_global_load_lds(
        (const __attribute__((address_space(1))) void*)g,
        (__attribute__((address_space(3))) void*)l, 16, 0, 0);
}

// ---------------------------------------------------------------------------
// C[M,N] = postact( A[M,K] @ B[N,K]^T + bias ), A/B bf16-resident, fp32 accum.
// 128x128 tile, BK=32, linear LDS, global_load_lds staging, 2-DEEP prefetch
// with counted vmcnt (T4): raw s_barrier, steady-state s_waitcnt vmcnt(4) --
// the newest tile's 4 loads stay in flight across the barrier; each tile gets
// ~2 compute phases of latency cover. lgkmcnt(0)+sched_barrier(0) fence per
// rule #18 before the LDS-reuse barrier.
// 256 threads = 4 waves (2x2 of 64x64), 4x4 16x16x32 frags.
// OUTMODE: 0 = f32 out, 1 = bf16 out, 2 = both.
// Tile order: bijective XCD split + 8-row chunks iterated bn-major per XCD.
// ---------------------------------------------------------------------------
template <int POSTG, int OUTMODE>
__global__ __launch_bounds__(256) void gemm_bf(
    const short* __restrict__ A, const short* __restrict__ B,
    const float* __restrict__ bias, float* __restrict__ Cf,
    short* __restrict__ Cb, int M, int N, int K) {
    __shared__ __align__(16) short As[2][4096];  // [buf][128 rows x 32 shorts]
    __shared__ __align__(16) short Bs[2][4096];
    const unsigned gx = gridDim.x, gy = gridDim.y;
    const unsigned nwg = gx * gy;
    const unsigned orig = blockIdx.y * gx + blockIdx.x;
    const unsigned q = nwg >> 3, r = nwg & 7;
    const unsigned xcd = orig & 7, sidx = orig >> 3;
    const unsigned swz = (xcd < r ? xcd * (q + 1) : r * (q + 1) + (xcd - r) * q) + sidx;
    const unsigned CH = 8;
    const unsigned chunk = swz / (CH * gx);
    const unsigned rem = swz - chunk * (CH * gx);
    const unsigned nr = min(CH, gy - chunk * CH);
    const unsigned col = rem / nr;
    const unsigned rowin = rem - col * nr;
    const int bm = (int)(chunk * CH + rowin) * 128;
    const int bn = (int)col * 128;

    const int tid = threadIdx.x;
    const int lane = tid & 63;
    const int wave = tid >> 6;
    const int wm = (wave >> 1) * 64, wn = (wave & 1) * 64;
    const int lr16 = lane & 15;
    const int lk8 = (lane >> 4) * 8;

    // staging: thread t covers 16B chunk (t&3) of row (t>>2); 2 issues/matrix
    const int trow = tid >> 2;
    const int tchk = (tid & 3) * 8;
    const short* a0 = A + (size_t)min(bm + trow, M - 1) * K + tchk;
    const short* a1 = A + (size_t)min(bm + 64 + trow, M - 1) * K + tchk;
    const short* b0 = B + (size_t)min(bn + trow, N - 1) * K + tchk;
    const short* b1 = B + (size_t)min(bn + 64 + trow, N - 1) * K + tchk;

    auto stage = [&](int buf, int k0) {
        gld16(a0 + k0, &As[buf][tid * 8]);
        gld16(a1 + k0, &As[buf][2048 + tid * 8]);
        gld16(b0 + k0, &Bs[buf][tid * 8]);
        gld16(b1 + k0, &Bs[buf][2048 + tid * 8]);
    };

    f32x4 acc[4][4];
#pragma unroll
    for (int i = 0; i < 4; ++i)
#pragma unroll
        for (int j = 0; j < 4; ++j) acc[i][j] = (f32x4){0.f, 0.f, 0.f, 0.f};

    stage(0, 0);
    stage(1, 32);          // K >= 64 always here (K = 512)
    int cur = 0;
    for (int k0 = 0; k0 < K; k0 += 32) {
        // oldest in-flight tile (buf cur) complete; newest 4 loads stay queued
        if (k0 + 32 < K) {
            asm volatile("s_waitcnt vmcnt(4)" ::: "memory");
        } else {
            asm volatile("s_waitcnt vmcnt(0)" ::: "memory");
        }
        __builtin_amdgcn_s_barrier();   // buf[cur] visible to all waves

        short8 af[4], bfr[4];
#pragma unroll
        for (int mi = 0; mi < 4; ++mi)
            af[mi] = *(const short8*)&As[cur][(wm + mi * 16 + lr16) * 32 + lk8];
#pragma unroll
        for (int ni = 0; ni < 4; ++ni)
            bfr[ni] = *(const short8*)&Bs[cur][(wn + ni * 16 + lr16) * 32 + lk8];
        asm volatile("s_waitcnt lgkmcnt(0)" ::: "memory");
        __builtin_amdgcn_sched_barrier(0);   // rule #18: pin MFMA after reads
        __builtin_amdgcn_s_barrier();        // all waves done reading buf[cur]

        if (k0 + 64 < K) stage(cur, k0 + 64);  // overwrite cur with tile k+2

#pragma unroll
        for (int mi = 0; mi < 4; ++mi)
#pragma unroll
            for (int ni = 0; ni < 4; ++ni)
                acc[mi][ni] = __builtin_amdgcn_mfma_f32_16x16x32_bf16(
                    af[mi], bfr[ni], acc[mi][ni], 0, 0, 0);
        cur ^= 1;
    }

    // epilogue: C/D layout col=lane&15, row=(lane>>4)*4+reg  [m89 verified]
#pragma unroll
    for (int mi = 0; mi < 4; ++mi) {
        int row0 = bm + wm + mi * 16 + (lane >> 4) * 4;
#pragma unroll
        for (int ni = 0; ni < 4; ++ni) {
            int col2 = bn + wn + ni * 16 + lr16;
            if (col2 < N) {
                float bsv = bias ? bias[col2] : 0.0f;
#pragma unroll
                for (int rr2 = 0; rr2 < 4; ++rr2) {
                    int row = row0 + rr2;
                    if (row < M) {
                        float v = acc[mi][ni][rr2] + bsv;
                        if (POSTG) v = gelu_f(v);
                        if (OUTMODE != 1) Cf[(size_t)row * N + col2] = v;
                        if (OUTMODE != 0) Cb[(size_t)row * N + col2] = (short)f2b(v);
                    }
                }
            }
        }
    }
}

// fp32 -> bf16 bulk convert, 8 elems/thread
__global__ void cvt_b16(const float* __restrict__ in, short* __restrict__ out, int n8) {
    int i = blockIdx.x * 256 + threadIdx.x;
    if (i >= n8) return;
    float4 a = ((const float4*)in)[i * 2];
    float4 b = ((const float4*)in)[i * 2 + 1];
    short8 o;
    o[0] = f2b(a.x); o[1] = f2b(a.y); o[2] = f2b(a.z); o[3] = f2b(a.w);
    o[4] = f2b(b.x); o[5] = f2b(b.y); o[6] = f2b(b.z); o[7] = f2b(b.w);
    *(short8*)(out + (size_t)i * 8) = o;
}

// ---------------------------------------------------------------------------
// One launch per layer: fold att_r/msg_r into K/V weights (bf16 -> wcat rows
// 0..511 / 1024..1535 + biases), convert qw -> wcat rows 512..1023, convert
// aw -> w16w, copy qb -> bcat+512.
// blocks: [0,128) fuse (bit6 = which), [128,256) cvt qw, [256,384) cvt aw,
// 384 = bias copy. 256 threads.
// ---------------------------------------------------------------------------
__global__ __launch_bounds__(256) void prep_layer(
    const float* __restrict__ kw, const float* __restrict__ kb,
    const float* __restrict__ qw, const float* __restrict__ qb,
    const float* __restrict__ vw, const float* __restrict__ vb,
    const float* __restrict__ aw,
    const float* __restrict__ att_r, const float* __restrict__ msg_r,
    short* __restrict__ wcat, float* __restrict__ bcat,
    short* __restrict__ w16w) {
    __shared__ float rs[64][64];
    int bid = blockIdx.x;
    int tid = threadIdx.x;
    if (bid < 128) {
        int which = bid >> 6;            // 0 = K, 1 = V
        int sub = bid & 63;
        int h = sub >> 3, dc = (sub & 7) * 64;
        const float* w = which ? vw : kw;
        const float* bsrc = which ? vb : kb;
        const float* rr = (which ? msg_r : att_r) + h * 4096;
        short* fw = wcat + (which ? (size_t)1024 * D : 0);
        float* fb = bcat + (which ? 1024 : 0);
        for (int i = tid; i < 4096; i += 256) rs[i >> 6][i & 63] = rr[i];
        __syncthreads();
        for (int rep = 0; rep < 16; ++rep) {
            int o = rep * 256 + tid;
            int j = o >> 6;
            int dd = o & 63;
            float s = 0.0f;
#pragma unroll 8
            for (int i = 0; i < 64; ++i)
                s = fmaf(rs[i][j], w[(size_t)(h * 64 + i) * D + dc + dd], s);
            fw[(size_t)(h * 64 + j) * D + dc + dd] = (short)f2b(s);
        }
        if ((sub & 7) == 0 && tid < 64) {
            float s = 0.0f;
            for (int i = 0; i < 64; ++i) s += bsrc[h * 64 + i] * rs[i][tid];
            fb[h * 64 + tid] = s;
        }
    } else if (bid < 384) {
        int cb = bid - 128;
        const float* in = qw;
        short* out = wcat + (size_t)512 * D;
        if (cb >= 128) { in = aw; out = w16w; cb -= 128; }
        int i = cb * 256 + tid;  // < 32768 = D*D/8
        float4 a = ((const float4*)in)[i * 2];
        float4 b = ((const float4*)in)[i * 2 + 1];
        short8 o;
        o[0] = f2b(a.x); o[1] = f2b(a.y); o[2] = f2b(a.z); o[3] = f2b(a.w);
        o[4] = f2b(b.x); o[5] = f2b(b.y); o[6] = f2b(b.z); o[7] = f2b(b.w);
        *(short8*)(out + (size_t)i * 8) = o;
    } else {
        bcat[512 + tid * 2] = qb[tid * 2];
        bcat[512 + tid * 2 + 1] = qb[tid * 2 + 1];
    }
}

// ---------------------------------------------------------------------------
// CSR build by dst:  hist -> scan -> scatter (CSR-ordered src list)
// ---------------------------------------------------------------------------
__global__ void zero_int(int* __restrict__ p, int n) {
    int i = blockIdx.x * 256 + threadIdx.x;
    if (i < n) p[i] = 0;
}

__global__ void hist_dst(const int* __restrict__ dst, int* __restrict__ cnt, int E) {
    int i = blockIdx.x * 256 + threadIdx.x;
    if (i < E) atomicAdd(&cnt[dst[i]], 1);
}

__global__ __launch_bounds__(1024) void scan_counts(
    const int* __restrict__ cnt, int* __restrict__ offs, int* __restrict__ cursor,
    int n, int E) {
    __shared__ int part[1024];
    int t = threadIdx.x;
    int chunk = (n + 1023) >> 10;
    int lo = t * chunk;
    int hi = min(lo + chunk, n);
    int s = 0;
    for (int i = lo; i < hi; ++i) s += cnt[i];
    part[t] = s;
    __syncthreads();
    for (int off = 1; off < 1024; off <<= 1) {
        int v = (t >= off) ? part[t - off] : 0;
        __syncthreads();
        part[t] += v;
        __syncthreads();
    }
    int base = (t == 0) ? 0 : part[t - 1];
    for (int i = lo; i < hi; ++i) {
        offs[i] = base;
        cursor[i] = base;
        base += cnt[i];
    }
    if (t == 1023) offs[n] = E;
}

__global__ void scatter_edges(const int* __restrict__ src, const int* __restrict__ dst,
                              int* __restrict__ cursor, int* __restrict__ srcs, int E) {
    int i = blockIdx.x * 256 + threadIdx.x;
    if (i < E) {
        int pos = atomicAdd(&cursor[dst[i]], 1);
        srcs[pos] = src[i];
    }
}

// ---------------------------------------------------------------------------
// Fused per-node edge attention, one WAVE per dst node (4 nodes / block).
// Unroll-2 flash softmax, states merged at end. kqv row: k'|q|v'.
// ---------------------------------------------------------------------------
__global__ __launch_bounds__(256) void edge_attn(
    const short* __restrict__ kqv, const int* __restrict__ srcs,
    const int* __restrict__ offs, const float* __restrict__ pri,
    short* __restrict__ gg, int NNodes) {
    int n = blockIdx.x * 4 + (threadIdx.x >> 6);
    if (n >= NNodes) return;
    int lane = threadIdx.x & 63;
    int start = offs[n], end = offs[n + 1];

    const short8 qv = *(const short8*)(kqv + (size_t)n * 1536 + 512 + lane * 8);
    float qf[8];
#pragma unroll
    for (int j = 0; j < 8; ++j) qf[j] = b2f((unsigned short)qv[j]);
    const float prih = pri[lane >> 3] * 0.125f;

    float rm0 = -INFINITY, rd0 = 0.0f, rm1 = -INFINITY, rd1 = 0.0f;
    float va0[8], va1[8];
#pragma unroll
    for (int j = 0; j < 8; ++j) { va0[j] = 0.0f; va1[j] = 0.0f; }

    int i = start;
    for (; i + 1 < end; i += 2) {
        int s0 = srcs[i], s1 = srcs[i + 1];
        const short* r0 = kqv + (size_t)s0 * 1536;
        const short* r1 = kqv + (size_t)s1 * 1536;
        short8 k0 = *(const short8*)(r0 + lane * 8);
        short8 v0 = *(const short8*)(r0 + 1024 + lane * 8);
        short8 k1 = *(const short8*)(r1 + lane * 8);
        short8 v1 = *(const short8*)(r1 + 1024 + lane * 8);
        float d0 = 0.0f, d1 = 0.0f;
#pragma unroll
        for (int j = 0; j < 8; ++j) {
            d0 = fmaf(b2f((unsigned short)k0[j]), qf[j], d0);
            d1 = fmaf(b2f((unsigned short)k1[j]), qf[j], d1);
        }
        d0 += __shfl_xor(d0, 1); d1 += __shfl_xor(d1, 1);
        d0 += __shfl_xor(d0, 2); d1 += __shfl_xor(d1, 2);
        d0 += __shfl_xor(d0, 4); d1 += __shfl_xor(d1, 4);
        float t0 = d0 * prih, t1 = d1 * prih;
        float nm0 = fmaxf(rm0, t0), nm1 = fmaxf(rm1, t1);
        float sc0 = expf(rm0 - nm0), sc1 = expf(rm1 - nm1);
        float e0 = expf(t0 - nm0), e1 = expf(t1 - nm1);
        rd0 = rd0 * sc0 + e0; rm0 = nm0;
        rd1 = rd1 * sc1 + e1; rm1 = nm1;
#pragma unroll
        for (int j = 0; j < 8; ++j) {
            va0[j] = fmaf(va0[j], sc0, b2f((unsigned short)v0[j]) * e0);
            va1[j] = fmaf(va1[j], sc1, b2f((unsigned short)v1[j]) * e1);
        }
    }
    if (i < end) {  // tail edge -> state 0
        int s0 = srcs[i];
        const short* r0 = kqv + (size_t)s0 * 1536;
        short8 k0 = *(const short8*)(r0 + lane * 8);
        short8 v0 = *(const short8*)(r0 + 1024 + lane * 8);
        float d0 = 0.0f;
#pragma unroll
        for (int j = 0; j < 8; ++j) d0 = fmaf(b2f((unsigned short)k0[j]), qf[j], d0);
        d0 += __shfl_xor(d0, 1);
        d0 += __shfl_xor(d0, 2);
        d0 += __shfl_xor(d0, 4);
        float t0 = d0 * prih;
        float nm0 = fmaxf(rm0, t0);
        float sc0 = expf(rm0 - nm0);
        float e0 = expf(t0 - nm0);
        rd0 = rd0 * sc0 + e0; rm0 = nm0;
#pragma unroll
        for (int j = 0; j < 8; ++j)
            va0[j] = fmaf(va0[j], sc0, b2f((unsigned short)v0[j]) * e0);
    }

    // merge the two states (clamp avoids exp(-inf - -inf) NaN on deg-0 nodes)
    float m = fmaxf(fmaxf(rm0, rm1), -3.0e38f);
    float s0 = expf(rm0 - m), s1 = expf(rm1 - m);
    float rden = rd0 * s0 + rd1 * s1;
    float inv = 1.0f / fmaxf(rden, 1e-9f);
    unsigned o[4];
#pragma unroll
    for (int p = 0; p < 4; ++p) {
        float x0 = gelu_f((va0[2 * p] * s0 + va1[2 * p] * s1) * inv);
        float x1 = gelu_f((va0[2 * p + 1] * s0 + va1[2 * p + 1] * s1) * inv);
        o[p] = (unsigned)(unsigned short)f2b(x0) |
               ((unsigned)(unsigned short)f2b(x1) << 16);
    }
    uint4 pack = make_uint4(o[0], o[1], o[2], o[3]);
    *(uint4*)(gg + (size_t)n * D + lane * 8) = pack;
}

// out = trans*alpha + h*(1-alpha); layernorm; write fp32 h + bf16 h.
__global__ __launch_bounds__(128) void blend_ln(
    const float* __restrict__ trans, const float* __restrict__ hin,
    const float* __restrict__ skip, const float* __restrict__ g,
    const float* __restrict__ b, float* __restrict__ hout,
    short* __restrict__ hb16) {
    int n = blockIdx.x;
    int tid = threadIdx.x;  // 0..127
    float alpha = 1.0f / (1.0f + expf(-skip[0]));
    size_t base = (size_t)n * D + tid * 4;
    float4 t4 = *(const float4*)(trans + base);
    float4 h4 = *(const float4*)(hin + base);
    float o[4];
    o[0] = t4.x * alpha + h4.x * (1.0f - alpha);
    o[1] = t4.y * alpha + h4.y * (1.0f - alpha);
    o[2] = t4.z * alpha + h4.z * (1.0f - alpha);
    o[3] = t4.w * alpha + h4.w * (1.0f - alpha);
    float s = o[0] + o[1] + o[2] + o[3];
    float ss = o[0] * o[0] + o[1] * o[1] + o[2] * o[2] + o[3] * o[3];
    for (int off = 32; off; off >>= 1) {
        s += __shfl_down(s, off);
        ss += __shfl_down(ss, off);
    }
    __shared__ float red[4];
    if ((tid & 63) == 0) { red[tid >> 6] = s; red[2 + (tid >> 6)] = ss; }
    __syncthreads();
    float S = red[0] + red[1];
    float SS = red[2] + red[3];
    float mu = S * (1.0f / 512.0f);
    float var = SS * (1.0f / 512.0f) - mu * mu;
    float inv = rsqrtf(var + 1e-5f);
    int c = tid * 4;
    float4 o4;
    o4.x = (o[0] - mu) * inv * g[c + 0] + b[c + 0];
    o4.y = (o[1] - mu) * inv * g[c + 1] + b[c + 1];
    o4.z = (o[2] - mu) * inv * g[c + 2] + b[c + 2];
    o4.w = (o[3] - mu) * inv * g[c + 3] + b[c + 3];
    *(float4*)(hout + base) = o4;
    short4v hb;
    hb[0] = f2b(o4.x); hb[1] = f2b(o4.y); hb[2] = f2b(o4.z); hb[3] = f2b(o4.w);
    *(short4v*)(hb16 + base) = hb;
}

// embs16 = bf16(embeddings * attn_kernels), 8 elems/thread
__global__ void scale_emb_b16(const float* __restrict__ e, const float* __restrict__ ak,
                              short* __restrict__ o, int n8) {
    int i = blockIdx.x * 256 + threadIdx.x;
    if (i >= n8) return;
    float4 a = ((const float4*)e)[i * 2];
    float4 b = ((const float4*)e)[i * 2 + 1];
    int d0 = (i * 8) & (D - 1);
    short8 v;
    v[0] = f2b(a.x * ak[d0 + 0]); v[1] = f2b(a.y * ak[d0 + 1]);
    v[2] = f2b(a.z * ak[d0 + 2]); v[3] = f2b(a.w * ak[d0 + 3]);
    v[4] = f2b(b.x * ak[d0 + 4]); v[5] = f2b(b.y * ak[d0 + 5]);
    v[6] = f2b(b.z * ak[d0 + 6]); v[7] = f2b(b.w * ak[d0 + 7]);
    *(short8*)(o + (size_t)i * 8) = v;
}

extern "C" void kernel_launch(void* const* d_in, const int* in_sizes, int n_in,
                              void* d_out, int out_size, void* d_ws, size_t ws_size,
                              hipStream_t stream) {
    const float* embeddings = (const float*)d_in[0];
    const float* node_emb   = (const float*)d_in[1];
    const float* adapt_w    = (const float*)d_in[2];
    const float* adapt_b    = (const float*)d_in[3];
    const float* kw   = (const float*)d_in[4];
    const float* kb   = (const float*)d_in[5];
    const float* qw   = (const float*)d_in[6];
    const float* qb   = (const float*)d_in[7];
    const float* vw   = (const float*)d_in[8];
    const float* vb   = (const float*)d_in[9];
    const float* aw   = (const float*)d_in[10];
    const float* ab   = (const float*)d_in[11];
    const float* pri  = (const float*)d_in[12];
    const float* att_r = (const float*)d_in[13];
    const float* msg_r = (const float*)d_in[14];
    const float* skip  = (const float*)d_in[15];
    const float* ln_g  = (const float*)d_in[16];
    const float* ln_b  = (const float*)d_in[17];
    const float* out_w = (const float*)d_in[18];
    const float* out_b = (const float*)d_in[19];
    const float* attn_k = (const float*)d_in[20];
    const int* src = (const int*)d_in[21];
    const int* dst = (const int*)d_in[22];

    const int E  = in_sizes[21];
    const int NB = in_sizes[0] / D;   // 8192
    const int NN = in_sizes[1] / D;   // 20000
    const int NC = out_size / NB;     // 10000

    size_t big = (size_t)NN * D;
    float* hbuf = (float*)d_ws;                  // fp32 h (residual/LN)
    float* fb32 = hbuf + big;                    // trans out
    short* hb16 = (short*)(fb32 + big);          // bf16 h (GEMM A operand)
    short* gg16 = hb16 + big;                    // node_emb bf16 / gelu(agg)
    short* kqv16 = gg16 + big;                   // [NN][1536] k'|q|v'
    short* w16a = kqv16 + (size_t)NN * 1536;     // adapt_w
    short* w16o = w16a + (size_t)D * D;          // out_w
    short* w16w = w16o + (size_t)D * D;          // aw[l]
    short* wcat = w16w + (size_t)D * D;          // [1536][512] k'|q|v' weights
    float* bcat = (float*)(wcat + (size_t)1536 * D);  // [1536]
    int* offs   = (int*)(bcat + 1536);           // NN+1
    int* cursor = offs + NN + 1;                 // NN
    int* srcs   = cursor + NN;                   // E (CSR order)
    short* cls16 = kqv16;                        // reuse after layers
    short* embs16 = kqv16 + (size_t)NC * D;

    auto ggrid = [](int M, int N) { return dim3((N + 127) / 128, (M + 127) / 128); };
    const int WB = D * D / 8;

    // ---- CSR by dst (src/dst are layer-invariant) ----
    zero_int<<<(NN + 255) / 256, 256, 0, stream>>>(cursor, NN);
    hist_dst<<<(E + 255) / 256, 256, 0, stream>>>(dst, cursor, E);
    scan_counts<<<1, 1024, 0, stream>>>(cursor, offs, cursor, NN, E);
    scatter_edges<<<(E + 255) / 256, 256, 0, stream>>>(src, dst, cursor, srcs, E);

    // ---- one-shot bf16 conversions ----
    cvt_b16<<<((int)(big / 8) + 255) / 256, 256, 0, stream>>>(node_emb, gg16, (int)(big / 8));
    cvt_b16<<<(WB + 255) / 256, 256, 0, stream>>>(adapt_w, w16a, WB);
    cvt_b16<<<(WB + 255) / 256, 256, 0, stream>>>(out_w, w16o, WB);

    // h = gelu(node_emb @ adapt_w^T + adapt_b)  -> fp32 + bf16
    gemm_bf<1, 2><<<ggrid(NN, D), 256, 0, stream>>>(gg16, w16a, adapt_b, hbuf, hb16, NN, D, D);

    for (int l = 0; l < NLAYER; ++l) {
        const size_t wo = (size_t)l * D * D;
        // all layer weight prep in one launch
        prep_layer<<<385, 256, 0, stream>>>(
            kw + wo, kb + l * D, qw + wo, qb + l * D, vw + wo, vb + l * D,
            aw + wo, att_r + (size_t)l * H * 64 * 64, msg_r + (size_t)l * H * 64 * 64,
            wcat, bcat, w16w);

        // kqv = h @ wcat^T + bcat   (one GEMM, N=1536)
        gemm_bf<0, 1><<<ggrid(NN, 1536), 256, 0, stream>>>(hb16, wcat, bcat, nullptr, kqv16, NN, 1536, D);

        // fused edge attention -> gelu(agg) bf16 (wave per node, unroll-2)
        edge_attn<<<(NN + 3) / 4, 256, 0, stream>>>(kqv16, srcs, offs, pri + l * H, gg16, NN);

        // trans = gelu(agg) @ aw^T + ab -> fp32
        gemm_bf<0, 0><<<ggrid(NN, D), 256, 0, stream>>>(gg16, w16w, ab + l * D, fb32, nullptr, NN, D, D);
        blend_ln<<<NN, 128, 0, stream>>>(fb32, hbuf, skip + l, ln_g + l * D, ln_b + l * D, hbuf, hb16);
    }

    // cls_emb = h[:NC] @ out_w^T + out_b  -> bf16
    gemm_bf<0, 1><<<ggrid(NC, D), 256, 0, stream>>>(hb16, w16o, out_b, nullptr, cls16, NC, D, D);
    // embs = bf16(embeddings * attn_kernels)
    scale_emb_b16<<<((NB * D / 8) + 255) / 256, 256, 0, stream>>>(embeddings, attn_k, embs16, NB * D / 8);
    // logits = embs @ cls_emb^T  -> fp32 d_out
    gemm_bf<0, 0><<<ggrid(NB, NC), 256, 0, stream>>>(embs16, cls16, nullptr, (float*)d_out, nullptr, NB, NC, D);
}